// Round 1
// baseline (752.545 us; speedup 1.0000x reference)
//
#include <hip/hip_runtime.h>
#include <math.h>

#define B_ 32
#define K_ 8192
#define TOPK_ 1000
#define F_ 1024
#define E_ 1153
#define H1_ 512
#define H2_ 256
#define PH_ 768
#define ADIM_ 4672

// output layout (floats): logits | board_vals | value | wact | wres
#define OFF_BV   149504
#define OFF_VAL  149536
#define OFF_WACT 149568
#define OFF_WRES 153664

__device__ __forceinline__ float gelu_f(float x) {
  return 0.5f * x * (1.0f + erff(x * 0.70710678118654752440f));
}

// ---------- phase 1: q1b = features@W1s[:F] + b1s ; q2b = features@W1e[:F] + b1e ----------
__global__ __launch_bounds__(256) void k_q1q2(
    const float* __restrict__ features, const float* __restrict__ W1s,
    const float* __restrict__ W1e, const float* __restrict__ b1s,
    const float* __restrict__ b1e, float* __restrict__ q1b,
    float* __restrict__ q2b) {
  const int j = blockIdx.x * 256 + threadIdx.x;  // 0..767
  const int b = blockIdx.y;
  const float* A = features + b * F_;
  float acc = 0.f;
  if (j < H1_) {
    const float* W = W1s + j;
    for (int h = 0; h < F_; ++h) acc += A[h] * W[(size_t)h * H1_];
    q1b[b * H1_ + j] = acc + b1s[j];
  } else {
    const int j2 = j - H1_;
    const float* W = W1e + j2;
    for (int h = 0; h < F_; ++h) acc += A[h] * W[(size_t)h * H2_];
    q2b[b * H2_ + j2] = acc + b1e[j2];
  }
}

// ---------- phase 2: fused [k1|k2] GEMM; k2 -> global, k1 -> fused relu-dot scores ----------
// block: 512 thr (8 waves). 32 memory rows per block, 768 cols (512 k1 + 256 k2).
// thread (tc=tid&63, tg=tid>>6): rows tg*4..+3, cols tc+64*i (i<12). acc[4][12].
__global__ __launch_bounds__(512) void k_gemm_scores(
    const float* __restrict__ memory, const float* __restrict__ W1s,
    const float* __restrict__ W1e, const float* __restrict__ q1b,
    const float* __restrict__ W2s, const float* __restrict__ b2s,
    float* __restrict__ scores, float* __restrict__ k2_all) {
  __shared__ float lds_A[32 * 32];
  const int tid = threadIdx.x;
  const int tc = tid & 63, tg = tid >> 6;
  const int k0 = blockIdx.x * 32;

  float acc[4][12];
#pragma unroll
  for (int r = 0; r < 4; ++r)
#pragma unroll
    for (int i = 0; i < 12; ++i) acc[r][i] = 0.f;

  const int sr = tid >> 4;        // 0..31
  const int sh = (tid & 15) * 2;  // 0..30

  for (int h0 = 0; h0 < F_; h0 += 32) {
    const float* mrow = memory + (size_t)(k0 + sr) * E_ + h0 + sh;
    const float a0 = mrow[0];
    const float a1 = mrow[1];
    __syncthreads();
    lds_A[sr * 32 + sh] = a0;
    lds_A[sr * 32 + sh + 1] = a1;
    __syncthreads();
    const float* w1base = W1s + (size_t)(F_ + h0) * H1_ + tc;
    const float* w2base = W1e + (size_t)(F_ + h0) * H2_ + tc;
#pragma unroll 4
    for (int hh = 0; hh < 32; ++hh) {
      float w[12];
#pragma unroll
      for (int i = 0; i < 8; ++i) w[i] = w1base[(size_t)hh * H1_ + 64 * i];
#pragma unroll
      for (int i = 0; i < 4; ++i) w[8 + i] = w2base[(size_t)hh * H2_ + 64 * i];
#pragma unroll
      for (int r = 0; r < 4; ++r) {
        const float a = lds_A[(tg * 4 + r) * 32 + hh];
#pragma unroll
        for (int i = 0; i < 12; ++i) acc[r][i] += a * w[i];
      }
    }
  }

  // epilogue 1: k2 cols -> global
#pragma unroll
  for (int r = 0; r < 4; ++r) {
    const int k = k0 + tg * 4 + r;
#pragma unroll
    for (int i = 0; i < 4; ++i)
      k2_all[(size_t)k * H2_ + tc + 64 * i] = acc[r][8 + i];
  }

  // epilogue 2: scores[b][k] = b2s + sum_j relu(q1b[b][j] + k1[k][j]) * W2s[j]
  float w2v[8], qv[8];
#pragma unroll
  for (int i = 0; i < 8; ++i) w2v[i] = W2s[tc + 64 * i];
  const float b2 = b2s[0];
  for (int b = 0; b < B_; ++b) {
    const float* q = q1b + b * H1_ + tc;
#pragma unroll
    for (int i = 0; i < 8; ++i) qv[i] = q[64 * i];
#pragma unroll
    for (int r = 0; r < 4; ++r) {
      float s = 0.f;
#pragma unroll
      for (int i = 0; i < 8; ++i)
        s += fmaxf(qv[i] + acc[r][i], 0.f) * w2v[i];
#pragma unroll
      for (int off = 32; off > 0; off >>= 1) s += __shfl_xor(s, off);
      if (tc == 0) scores[(size_t)b * K_ + k0 + tg * 4 + r] = s + b2;
    }
  }
}

// ---------- phase 3: exact top-1000 per row via 8-bit radix select ----------
__global__ __launch_bounds__(256) void k_topk(
    const float* __restrict__ scores, int* __restrict__ topk_idx) {
  __shared__ unsigned key[K_];
  __shared__ unsigned hist[256];
  __shared__ unsigned scan[256];
  __shared__ unsigned bc[2];
  __shared__ unsigned n_gt, run_eq;
  const int tid = threadIdx.x;
  const int b = blockIdx.x;
  const float* row = scores + (size_t)b * K_;
  for (int i = tid; i < K_; i += 256) {
    const unsigned u = __float_as_uint(row[i]);
    key[i] = (u & 0x80000000u) ? ~u : (u | 0x80000000u);  // order-preserving
  }
  __syncthreads();
  unsigned prefix = 0;
  int r = TOPK_;
  for (int p = 0; p < 4; ++p) {
    const int shift = 24 - 8 * p;
    hist[tid] = 0;
    __syncthreads();
    const unsigned pmask = (p == 0) ? 0u : (0xFFFFFFFFu << (shift + 8));
    for (int i = tid; i < K_; i += 256) {
      const unsigned k = key[i];
      if ((k & pmask) == prefix) atomicAdd(&hist[(k >> shift) & 255u], 1u);
    }
    __syncthreads();
    if (tid == 0) {
      int rr = r;
      int d = 255;
      while (d > 0 && (int)hist[d] < rr) { rr -= (int)hist[d]; --d; }
      bc[0] = (unsigned)d;
      bc[1] = (unsigned)rr;
    }
    __syncthreads();
    prefix |= bc[0] << shift;
    r = (int)bc[1];
    __syncthreads();
  }
  const unsigned T = prefix;
  const int take_eq = r;
  const int cnt_gt = TOPK_ - take_eq;
  if (tid == 0) { n_gt = 0; run_eq = 0; }
  __syncthreads();
  int* outp = topk_idx + b * TOPK_;
  for (int base = 0; base < K_; base += 256) {
    const int i = base + tid;
    const unsigned k = key[i];
    if (k > T) { const unsigned pos = atomicAdd(&n_gt, 1u); outp[pos] = i; }
    const unsigned feq = (k == T) ? 1u : 0u;
    scan[tid] = feq;
    __syncthreads();
    for (int off = 1; off < 256; off <<= 1) {
      const unsigned v = scan[tid];
      const unsigned add = (tid >= off) ? scan[tid - off] : 0u;
      __syncthreads();
      scan[tid] = v + add;
      __syncthreads();
    }
    if (feq) {
      const unsigned pos = run_eq + scan[tid] - 1u;  // stable: index order
      if ((int)pos < take_eq) outp[cnt_gt + (int)pos] = i;
    }
    __syncthreads();
    if (tid == 0) run_eq += scan[255];
    __syncthreads();
  }
}

// ---------- phase 4: s2[b,t] = b2e + sum_j gelu(q2b[b][j] + k2_all[idx][j]) * W2e[j] ----------
__global__ __launch_bounds__(256) void k_s2(
    const float* __restrict__ k2_all, const float* __restrict__ q2b,
    const int* __restrict__ topk_idx, const float* __restrict__ W2e,
    const float* __restrict__ b2e, float* __restrict__ s2) {
  const int tid = threadIdx.x;
  const int ln = tid & 63;
  const int e = blockIdx.x * 4 + (tid >> 6);  // 0..31999
  const int b = e / TOPK_;
  const int idx = topk_idx[e];
  const float* kr = k2_all + (size_t)idx * H2_;
  const float* qr = q2b + b * H2_;
  float s = 0.f;
#pragma unroll
  for (int i = 0; i < 4; ++i) {
    const int j = ln + 64 * i;
    s += gelu_f(qr[j] + kr[j]) * W2e[j];
  }
#pragma unroll
  for (int off = 32; off > 0; off >>= 1) s += __shfl_down(s, off);
  if (ln == 0) s2[e] = s + b2e[0];
}

// ---------- phase 5: w2 = softmax(s2); weighted actions/results ----------
__global__ __launch_bounds__(512) void k_soft_weighted(
    const float* __restrict__ s2, const int* __restrict__ topk_idx,
    const float* __restrict__ memory, float* __restrict__ ws_wact,
    float* __restrict__ ws_wres, float* __restrict__ out) {
  __shared__ float w2[TOPK_];
  __shared__ int idxs[TOPK_];
  __shared__ float red[512];
  const int tid = threadIdx.x;
  const int b = blockIdx.x;
  for (int t = tid; t < TOPK_; t += 512) {
    w2[t] = s2[b * TOPK_ + t];
    idxs[t] = topk_idx[b * TOPK_ + t];
  }
  __syncthreads();
  float m = -3.4e38f;
  for (int t = tid; t < TOPK_; t += 512) m = fmaxf(m, w2[t]);
  red[tid] = m;
  __syncthreads();
  for (int s = 256; s > 0; s >>= 1) {
    if (tid < s) red[tid] = fmaxf(red[tid], red[tid + s]);
    __syncthreads();
  }
  m = red[0];
  __syncthreads();
  float psum = 0.f;
  for (int t = tid; t < TOPK_; t += 512) {
    const float ev = expf(w2[t] - m);
    w2[t] = ev;
    psum += ev;
  }
  red[tid] = psum;
  __syncthreads();
  for (int s = 256; s > 0; s >>= 1) {
    if (tid < s) red[tid] += red[tid + s];
    __syncthreads();
  }
  const float inv = 1.f / red[0];
  __syncthreads();
  for (int t = tid; t < TOPK_; t += 512) w2[t] *= inv;
  __syncthreads();
  // weighted_results
  float wr = 0.f;
  for (int t = tid; t < TOPK_; t += 512)
    wr += w2[t] * memory[(size_t)idxs[t] * E_ + (E_ - 1)];
  red[tid] = wr;
  __syncthreads();
  for (int s = 256; s > 0; s >>= 1) {
    if (tid < s) red[tid] += red[tid + s];
    __syncthreads();
  }
  if (tid == 0) {
    ws_wres[b] = red[0];
    out[OFF_WRES + b] = red[0];
  }
  __syncthreads();
  // weighted_actions: 4 t-groups x 128 action dims
  const int g = tid >> 7, a = tid & 127;
  float acc = 0.f;
  for (int t = g; t < TOPK_; t += 4)
    acc += truncf(memory[(size_t)idxs[t] * E_ + F_ + a]) * w2[t];
  red[tid] = acc;
  __syncthreads();
  if (tid < 128) {
    const float v = red[tid] + red[128 + tid] + red[256 + tid] + red[384 + tid];
    ws_wact[b * 128 + tid] = v;
    out[OFF_WACT + b * 128 + tid] = v;
  }
}

// ---------- phase 6a: hp = gelu([features|wact] @ Wp1 + bp1) ----------
__global__ __launch_bounds__(256) void k_hp(
    const float* __restrict__ features, const float* __restrict__ ws_wact,
    const float* __restrict__ Wp1, const float* __restrict__ bp1,
    float* __restrict__ hp) {
  const int j = blockIdx.x * 256 + threadIdx.x;  // 0..767
  const int b = blockIdx.y;
  const float* A = features + b * F_;
  const float* wa = ws_wact + b * 128;
  float acc = bp1[j];
  for (int h = 0; h < F_; ++h) acc += A[h] * Wp1[(size_t)h * PH_ + j];
  for (int h = 0; h < 128; ++h) acc += wa[h] * Wp1[(size_t)(F_ + h) * PH_ + j];
  hp[b * PH_ + j] = gelu_f(acc);
}

// ---------- phase 6b: logits = hp @ Wp2 + bp2 (init + atomic h-split accumulate) ----------
__global__ __launch_bounds__(256) void k_logits_init(
    const float* __restrict__ bp2, float* __restrict__ out) {
  const int i = blockIdx.x * 256 + threadIdx.x;
  if (i < B_ * ADIM_) out[i] = bp2[i % ADIM_];
}

__global__ __launch_bounds__(256) void k_logits(
    const float* __restrict__ hp, const float* __restrict__ Wp2,
    float* __restrict__ out) {
  __shared__ float lhp[32 * 192];
  const int tid = threadIdx.x;
  const int h0 = blockIdx.y * 192;
  const int col = blockIdx.x * 64 + (tid & 63);
  const int tg = tid >> 6;
  for (int i2 = tid; i2 < 32 * 192; i2 += 256) {
    const int bb = i2 / 192, h = i2 - bb * 192;
    lhp[i2] = hp[bb * PH_ + h0 + h];
  }
  __syncthreads();
  float acc[8] = {0.f, 0.f, 0.f, 0.f, 0.f, 0.f, 0.f, 0.f};
  for (int h = 0; h < 192; ++h) {
    const float w = Wp2[(size_t)(h0 + h) * ADIM_ + col];
#pragma unroll
    for (int bb = 0; bb < 8; ++bb) acc[bb] += lhp[(tg * 8 + bb) * 192 + h] * w;
  }
#pragma unroll
  for (int bb = 0; bb < 8; ++bb)
    atomicAdd(&out[(size_t)(tg * 8 + bb) * ADIM_ + col], acc[bb]);
}

// ---------- phase 6c: board_vals (tanh) and adaptive weight (sigmoid) ----------
__global__ __launch_bounds__(512) void k_value_nets(
    const float* __restrict__ features, const float* __restrict__ Wv1,
    const float* __restrict__ bv1, const float* __restrict__ Wv2,
    const float* __restrict__ bv2, const float* __restrict__ Wm1,
    const float* __restrict__ bm1, const float* __restrict__ Wm2,
    const float* __restrict__ bm2, float* __restrict__ ws_aw,
    float* __restrict__ out) {
  __shared__ float red[512];
  const int tid = threadIdx.x;
  const int b = blockIdx.x;
  const int net = blockIdx.y;
  const float* W1 = net ? Wm1 : Wv1;
  const float* bb1 = net ? bm1 : bv1;
  const float* W2 = net ? Wm2 : Wv2;
  const float* bb2 = net ? bm2 : bv2;
  const float* A = features + b * F_;
  float acc = bb1[tid];
  for (int h = 0; h < F_; ++h) acc += A[h] * W1[(size_t)h * 512 + tid];
  red[tid] = gelu_f(acc) * W2[tid];
  __syncthreads();
  for (int s = 256; s > 0; s >>= 1) {
    if (tid < s) red[tid] += red[tid + s];
    __syncthreads();
  }
  if (tid == 0) {
    const float v = red[0] + bb2[0];
    if (net == 0) out[OFF_BV + b] = tanhf(v);
    else ws_aw[b] = 1.f / (1.f + expf(-v));
  }
}

// ---------- phase 6d: value_output ----------
__global__ void k_value_out(const float* __restrict__ ws_aw,
                            const float* __restrict__ ws_wres,
                            float* __restrict__ out) {
  const int b = threadIdx.x;
  if (b < B_) {
    const float aw = ws_aw[b];
    const float bv = out[OFF_BV + b];
    out[OFF_VAL + b] = aw * ws_wres[b] + (1.f - aw) * bv;
  }
}

extern "C" void kernel_launch(void* const* d_in, const int* in_sizes, int n_in,
                              void* d_out, int out_size, void* d_ws,
                              size_t ws_size, hipStream_t stream) {
  (void)in_sizes; (void)n_in; (void)out_size; (void)ws_size;
  const float* features = (const float*)d_in[0];
  const float* memory   = (const float*)d_in[1];
  const float* W1s = (const float*)d_in[2];
  const float* b1s = (const float*)d_in[3];
  const float* W2s = (const float*)d_in[4];
  const float* b2s = (const float*)d_in[5];
  const float* W1e = (const float*)d_in[6];
  const float* b1e = (const float*)d_in[7];
  const float* W2e = (const float*)d_in[8];
  const float* b2e = (const float*)d_in[9];
  const float* Wp1 = (const float*)d_in[10];
  const float* bp1 = (const float*)d_in[11];
  const float* Wp2 = (const float*)d_in[12];
  const float* bp2 = (const float*)d_in[13];
  const float* Wv1 = (const float*)d_in[14];
  const float* bv1 = (const float*)d_in[15];
  const float* Wv2 = (const float*)d_in[16];
  const float* bv2 = (const float*)d_in[17];
  const float* Wm1 = (const float*)d_in[18];
  const float* bm1 = (const float*)d_in[19];
  const float* Wm2 = (const float*)d_in[20];
  const float* bm2 = (const float*)d_in[21];
  float* out = (float*)d_out;

  // workspace layout (floats)
  float* ws = (float*)d_ws;
  float* q1b    = ws;                    // 32*512
  float* q2b    = q1b + 32 * 512;        // 32*256
  float* k2_all = q2b + 32 * 256;        // 8192*256
  float* scores = k2_all + 8192 * 256;   // 32*8192
  float* s2     = scores + 32 * 8192;    // 32*1000
  int*   topk   = (int*)(s2 + 32 * 1000);// 32*1000 ints
  float* wact   = (float*)(topk + 32 * 1000); // 32*128
  float* wres   = wact + 32 * 128;       // 32
  float* aw     = wres + 32;             // 32
  float* hp     = aw + 32;               // 32*768

  k_q1q2<<<dim3(3, 32), 256, 0, stream>>>(features, W1s, W1e, b1s, b1e, q1b, q2b);
  k_gemm_scores<<<256, 512, 0, stream>>>(memory, W1s, W1e, q1b, W2s, b2s, scores, k2_all);
  k_topk<<<32, 256, 0, stream>>>(scores, topk);
  k_s2<<<8000, 256, 0, stream>>>(k2_all, q2b, topk, W2e, b2e, s2);
  k_soft_weighted<<<32, 512, 0, stream>>>(s2, topk, memory, wact, wres, out);
  k_hp<<<dim3(3, 32), 256, 0, stream>>>(features, wact, Wp1, bp1, hp);
  k_logits_init<<<584, 256, 0, stream>>>(bp2, out);
  k_logits<<<dim3(73, 4), 256, 0, stream>>>(hp, Wp2, out);
  k_value_nets<<<dim3(32, 2), 512, 0, stream>>>(features, Wv1, bv1, Wv2, bv2,
                                                Wm1, bm1, Wm2, bm2, aw, out);
  k_value_out<<<1, 64, 0, stream>>>(aw, wres, out);
}

// Round 2
// 606.789 us; speedup vs baseline: 1.2402x; 1.2402x over previous
//
#include <hip/hip_runtime.h>
#include <math.h>

#define B_ 32
#define K_ 8192
#define TOPK_ 1000
#define F_ 1024
#define E_ 1153
#define H1_ 512
#define H2_ 256
#define PH_ 768
#define ADIM_ 4672

// output layout (floats): logits | board_vals | value | wact | wres
#define OFF_BV   149504
#define OFF_VAL  149536
#define OFF_WACT 149568
#define OFF_WRES 153664

typedef __attribute__((ext_vector_type(8))) short v8s;
typedef __attribute__((ext_vector_type(4))) float v4f;
typedef __attribute__((ext_vector_type(4))) unsigned short v4u16;

#define GLD16(gp, lp) __builtin_amdgcn_global_load_lds( \
    (const __attribute__((address_space(1))) void*)(gp), \
    (__attribute__((address_space(3))) void*)(lp), 16, 0, 0)

__device__ __forceinline__ float gelu_f(float x) {
  return 0.5f * x * (1.0f + erff(x * 0.70710678118654752440f));
}
__device__ __forceinline__ unsigned short f2bf(float x) {
  union { float f; unsigned u; } v; v.f = x;
  unsigned r = v.u + 0x7fffu + ((v.u >> 16) & 1u);
  return (unsigned short)(r >> 16);
}
__device__ __forceinline__ float bf2f(unsigned short h) {
  union { unsigned u; float f; } v; v.u = ((unsigned)h) << 16; return v.f;
}

// ---------- split/convert memory[:, :F] -> Ahi, Alo (bf16, [8192][1024]) ----------
__global__ __launch_bounds__(256) void k_split_mem(
    const float* __restrict__ memory, unsigned short* __restrict__ Ahi,
    unsigned short* __restrict__ Alo) {
  const int r = blockIdx.x;
  const int tid = threadIdx.x;
  const float* src = memory + (size_t)r * E_;
#pragma unroll
  for (int i = 0; i < 4; ++i) {
    const float x = src[tid + 256 * i];
    const unsigned short h = f2bf(x);
    Ahi[(size_t)r * 1024 + tid + 256 * i] = h;
    Alo[(size_t)r * 1024 + tid + 256 * i] = f2bf(x - bf2f(h));
  }
}

// ---------- transpose+split weights: B1hi/lo [512][1024], B2hi [256][1024] ----------
__global__ __launch_bounds__(256) void k_split_w(
    const float* __restrict__ W1s, const float* __restrict__ W1e,
    unsigned short* __restrict__ B1hi, unsigned short* __restrict__ B1lo,
    unsigned short* __restrict__ B2hi) {
  __shared__ float t[32][33];
  const int x = threadIdx.x, y = threadIdx.y;  // 32 x 8
  const int j0 = blockIdx.x * 32, k0 = blockIdx.y * 32;
#pragma unroll
  for (int i = 0; i < 4; ++i) {
    const int k = k0 + y + 8 * i;
    const int j = j0 + x;
    t[y + 8 * i][x] = (j < 512) ? W1s[(size_t)(F_ + k) * H1_ + j]
                                : W1e[(size_t)(F_ + k) * H2_ + (j - 512)];
  }
  __syncthreads();
#pragma unroll
  for (int i = 0; i < 4; ++i) {
    const int j = j0 + y + 8 * i;
    const int k = k0 + x;
    const float v = t[x][y + 8 * i];
    const unsigned short h = f2bf(v);
    if (j < 512) {
      B1hi[(size_t)j * 1024 + k] = h;
      B1lo[(size_t)j * 1024 + k] = f2bf(v - bf2f(h));
    } else {
      B2hi[(size_t)(j - 512) * 1024 + k] = h;
    }
  }
}

// ---------- q1b = features@W1s[:F]+b1s ; q2b = features@W1e[:F]+b1e (fp32) ----------
__global__ __launch_bounds__(256) void k_q1q2(
    const float* __restrict__ features, const float* __restrict__ W1s,
    const float* __restrict__ W1e, const float* __restrict__ b1s,
    const float* __restrict__ b1e, float* __restrict__ q1b,
    float* __restrict__ q2b) {
  const int j = blockIdx.x * 256 + threadIdx.x;
  const int b = blockIdx.y;
  const float* A = features + b * F_;
  float acc = 0.f;
  if (j < H1_) {
    const float* W = W1s + j;
    for (int h = 0; h < F_; ++h) acc += A[h] * W[(size_t)h * H1_];
    q1b[b * H1_ + j] = acc + b1s[j];
  } else {
    const int j2 = j - H1_;
    const float* W = W1e + j2;
    for (int h = 0; h < F_; ++h) acc += A[h] * W[(size_t)h * H2_];
    q2b[b * H2_ + j2] = acc + b1e[j2];
  }
}

// ---------- staging helper: 16B chunks into pad-80 LDS rows (5 chunks/row) ----------
// LDS row stride 80B (40 shorts): fragment ds_read_b128 spreads over 8 banks -> no conflict.
__device__ __forceinline__ void stage80(
    const unsigned short* __restrict__ src, int row_base, int k0,
    char* lds, int lds_off, int nchunks, int tid) {
  for (int i = 0; i * 256 < nchunks; ++i) {
    const int c = i * 256 + tid;
    if (c < nchunks) {
      const int row = c / 5, sub = c % 5;
      const int s = (sub == 4) ? 0 : sub;  // pad chunk loads row start (unused)
      const unsigned short* g = src + (size_t)(row_base + row) * 1024 + k0 + s * 8;
      GLD16(g, lds + lds_off + i * 4096 + ((tid >> 6) * 1024));
    }
  }
}

// ---------- GEMM1 (selection): C1 fp32 [8192][512] = A(hi+lo) @ B1(hi+lo)^T, 3-term ----------
__global__ __launch_bounds__(256) void k_gemm1(
    const unsigned short* __restrict__ Ahi, const unsigned short* __restrict__ Alo,
    const unsigned short* __restrict__ B1hi, const unsigned short* __restrict__ B1lo,
    float* __restrict__ C1) {
  __shared__ unsigned short lds[15360];  // 30720B: Ahi@0 Alo@10240 Bhi@20480 Blo@25600
  char* L = (char*)lds;
  const int tid = threadIdx.x;
  const int lane = tid & 63, w = tid >> 6;
  const int m0 = blockIdx.x * 128;
  const int n0 = blockIdx.y * 64;
  const int wr = w >> 1, wc = w & 1;
  v4f acc[4][2];
#pragma unroll
  for (int mi = 0; mi < 4; ++mi)
#pragma unroll
    for (int ni = 0; ni < 2; ++ni) acc[mi][ni] = (v4f)(0.f);

  for (int k0 = 0; k0 < 1024; k0 += 32) {
    __syncthreads();
    stage80(Ahi, m0, k0, L, 0, 640, tid);
    stage80(Alo, m0, k0, L, 10240, 640, tid);
    stage80(B1hi, n0, k0, L, 20480, 320, tid);
    stage80(B1lo, n0, k0, L, 25600, 320, tid);
    asm volatile("s_waitcnt vmcnt(0)" ::: "memory");
    __syncthreads();
    v8s ah[4], al[4], bh[2], bl[2];
    const int fo = (lane >> 4) * 16;
#pragma unroll
    for (int mi = 0; mi < 4; ++mi) {
      const int ro = (wr * 64 + mi * 16 + (lane & 15)) * 80 + fo;
      ah[mi] = *(const v8s*)(L + ro);
      al[mi] = *(const v8s*)(L + 10240 + ro);
    }
#pragma unroll
    for (int ni = 0; ni < 2; ++ni) {
      const int ro = (wc * 32 + ni * 16 + (lane & 15)) * 80 + fo;
      bh[ni] = *(const v8s*)(L + 20480 + ro);
      bl[ni] = *(const v8s*)(L + 25600 + ro);
    }
#pragma unroll
    for (int mi = 0; mi < 4; ++mi)
#pragma unroll
      for (int ni = 0; ni < 2; ++ni) {
        acc[mi][ni] = __builtin_amdgcn_mfma_f32_16x16x32_bf16(ah[mi], bh[ni], acc[mi][ni], 0, 0, 0);
        acc[mi][ni] = __builtin_amdgcn_mfma_f32_16x16x32_bf16(ah[mi], bl[ni], acc[mi][ni], 0, 0, 0);
        acc[mi][ni] = __builtin_amdgcn_mfma_f32_16x16x32_bf16(al[mi], bh[ni], acc[mi][ni], 0, 0, 0);
      }
  }
#pragma unroll
  for (int mi = 0; mi < 4; ++mi)
#pragma unroll
    for (int ni = 0; ni < 2; ++ni)
#pragma unroll
      for (int j = 0; j < 4; ++j) {
        const int mrow = m0 + wr * 64 + mi * 16 + (lane >> 4) * 4 + j;
        const int ncol = n0 + wc * 32 + ni * 16 + (lane & 15);
        C1[(size_t)mrow * 512 + ncol] = acc[mi][ni][j];
      }
}

// ---------- GEMM2 (evidence): C2 bf16 [8192][256] = Ahi @ B2hi^T, 1-term ----------
__global__ __launch_bounds__(256) void k_gemm2(
    const unsigned short* __restrict__ Ahi, const unsigned short* __restrict__ B2hi,
    unsigned short* __restrict__ C2) {
  __shared__ unsigned short lds[7680];  // 15360B: A@0 B@10240
  char* L = (char*)lds;
  const int tid = threadIdx.x;
  const int lane = tid & 63, w = tid >> 6;
  const int m0 = blockIdx.x * 128;
  const int n0 = blockIdx.y * 64;
  const int wr = w >> 1, wc = w & 1;
  v4f acc[4][2];
#pragma unroll
  for (int mi = 0; mi < 4; ++mi)
#pragma unroll
    for (int ni = 0; ni < 2; ++ni) acc[mi][ni] = (v4f)(0.f);

  for (int k0 = 0; k0 < 1024; k0 += 32) {
    __syncthreads();
    stage80(Ahi, m0, k0, L, 0, 640, tid);
    stage80(B2hi, n0, k0, L, 10240, 320, tid);
    asm volatile("s_waitcnt vmcnt(0)" ::: "memory");
    __syncthreads();
    v8s ah[4], bh[2];
    const int fo = (lane >> 4) * 16;
#pragma unroll
    for (int mi = 0; mi < 4; ++mi)
      ah[mi] = *(const v8s*)(L + (wr * 64 + mi * 16 + (lane & 15)) * 80 + fo);
#pragma unroll
    for (int ni = 0; ni < 2; ++ni)
      bh[ni] = *(const v8s*)(L + 10240 + (wc * 32 + ni * 16 + (lane & 15)) * 80 + fo);
#pragma unroll
    for (int mi = 0; mi < 4; ++mi)
#pragma unroll
      for (int ni = 0; ni < 2; ++ni)
        acc[mi][ni] = __builtin_amdgcn_mfma_f32_16x16x32_bf16(ah[mi], bh[ni], acc[mi][ni], 0, 0, 0);
  }
#pragma unroll
  for (int mi = 0; mi < 4; ++mi)
#pragma unroll
    for (int ni = 0; ni < 2; ++ni)
#pragma unroll
      for (int j = 0; j < 4; ++j) {
        const int mrow = m0 + wr * 64 + mi * 16 + (lane >> 4) * 4 + j;
        const int ncol = n0 + wc * 32 + ni * 16 + (lane & 15);
        C2[(size_t)mrow * 256 + ncol] = f2bf(acc[mi][ni][j]);
      }
}

// ---------- scores[b][k] = b2s + sum_j relu(q1b[b][j] + C1[k][j]) * W2s[j] ----------
__global__ __launch_bounds__(256) void k_scores(
    const float* __restrict__ C1, const float* __restrict__ q1b,
    const float* __restrict__ W2s, const float* __restrict__ b2s,
    float* __restrict__ scores) {
  const int tid = threadIdx.x, lane = tid & 63, w = tid >> 6;
  const int kbase = blockIdx.x * 64 + w * 16;
  const float b2 = b2s[0];
  float wv[8];
#pragma unroll
  for (int i = 0; i < 8; ++i) wv[i] = W2s[lane * 8 + i];
  for (int rc = 0; rc < 4; ++rc) {
    float c[4][8];
#pragma unroll
    for (int rr = 0; rr < 4; ++rr) {
      const float4 c0 = *(const float4*)&C1[(size_t)(kbase + rc * 4 + rr) * 512 + lane * 8];
      const float4 c1 = *(const float4*)&C1[(size_t)(kbase + rc * 4 + rr) * 512 + lane * 8 + 4];
      c[rr][0] = c0.x; c[rr][1] = c0.y; c[rr][2] = c0.z; c[rr][3] = c0.w;
      c[rr][4] = c1.x; c[rr][5] = c1.y; c[rr][6] = c1.z; c[rr][7] = c1.w;
    }
    for (int b = 0; b < B_; ++b) {
      const float4 q0 = *(const float4*)&q1b[b * H1_ + lane * 8];
      const float4 q1v = *(const float4*)&q1b[b * H1_ + lane * 8 + 4];
      float q[8] = {q0.x, q0.y, q0.z, q0.w, q1v.x, q1v.y, q1v.z, q1v.w};
#pragma unroll
      for (int rr = 0; rr < 4; ++rr) {
        float s = 0.f;
#pragma unroll
        for (int i = 0; i < 8; ++i) s += fmaxf(q[i] + c[rr][i], 0.f) * wv[i];
#pragma unroll
        for (int off = 32; off > 0; off >>= 1) s += __shfl_xor(s, off);
        if (lane == 0) scores[(size_t)b * K_ + kbase + rc * 4 + rr] = s + b2;
      }
    }
  }
}

// ---------- exact top-1000 (set semantics; ties by lowest index) ----------
__global__ __launch_bounds__(1024) void k_topk(
    const float* __restrict__ scores, int* __restrict__ topk_idx) {
  __shared__ unsigned key[K_];        // 32 KB (reused as reduce scratch at end)
  __shared__ unsigned whist[16][256]; // 16 KB per-wave hists
  __shared__ unsigned sfx[256];
  __shared__ int eqlist[1024];
  __shared__ unsigned ctl[4];  // d, r, n_out, eq_cnt
  const int tid = threadIdx.x;
  const int wid = tid >> 6;
  const int b = blockIdx.x;
  const float* row = scores + (size_t)b * K_;
  for (int i = tid; i < K_; i += 1024) {
    const unsigned u = __float_as_uint(row[i]);
    key[i] = (u & 0x80000000u) ? ~u : (u | 0x80000000u);
  }
  unsigned prefix = 0;
  int r = TOPK_;
  for (int p = 0; p < 4; ++p) {
    const int shift = 24 - 8 * p;
    for (int i = tid; i < 16 * 256; i += 1024) ((unsigned*)whist)[i] = 0;
    __syncthreads();
    const unsigned pmask = (p == 0) ? 0u : (0xFFFFFFFFu << (shift + 8));
    for (int i = tid; i < K_; i += 1024) {
      const unsigned k = key[i];
      if ((k & pmask) == prefix) atomicAdd(&whist[wid][(k >> shift) & 255u], 1u);
    }
    __syncthreads();
    if (tid < 256) {
      unsigned s = 0;
#pragma unroll
      for (int ww = 0; ww < 16; ++ww) s += whist[ww][tid];
      sfx[tid] = s;
    }
    __syncthreads();
    // suffix-inclusive sums: sfx[d] = #keys with bucket >= d
    for (int off = 1; off < 256; off <<= 1) {
      unsigned v = 0;
      if (tid < 256) { v = sfx[tid]; if (tid + off < 256) v += sfx[tid + off]; }
      __syncthreads();
      if (tid < 256) sfx[tid] = v;
      __syncthreads();
    }
    if (tid < 256) {
      const int Sge = (int)sfx[tid];
      const int Sgt = (tid < 255) ? (int)sfx[tid + 1] : 0;
      if (Sgt < r && r <= Sge) { ctl[0] = (unsigned)tid; ctl[1] = (unsigned)(r - Sgt); }
    }
    __syncthreads();
    prefix |= ctl[0] << shift;
    r = (int)ctl[1];
    __syncthreads();
  }
  const unsigned T = prefix;
  const int take_eq = r;
  if (tid == 0) { ctl[2] = 0; ctl[3] = 0; }
  __syncthreads();
  int* outp = topk_idx + b * TOPK_;
  for (int i = tid; i < K_; i += 1024) {
    const unsigned k = key[i];
    if (k > T) outp[atomicAdd(&ctl[2], 1u)] = i;
    else if (k == T) { const unsigned e = atomicAdd(&ctl[3], 1u); if (e < 1024) eqlist[e] = i; }
  }
  __syncthreads();
  const int m = (ctl[3] < 1024u) ? (int)ctl[3] : 1024;
  const int ngt = TOPK_ - take_eq;
  for (int sel = 0; sel < take_eq; ++sel) {
    key[tid] = (tid < m) ? (unsigned)eqlist[tid] : 0xFFFFFFFFu;
    __syncthreads();
    for (int s = 512; s > 0; s >>= 1) {
      if (tid < s) key[tid] = min(key[tid], key[tid + s]);
      __syncthreads();
    }
    const unsigned mn = key[0];
    if (tid < m && (unsigned)eqlist[tid] == mn) eqlist[tid] = 0x7FFFFFFF;
    if (tid == 0) outp[ngt + sel] = (int)mn;
    __syncthreads();
  }
}

// ---------- s2[e] = b2e + sum_j gelu(q2b[b][j] + C2[idx][j]) * W2e[j] ----------
__global__ __launch_bounds__(256) void k_s2(
    const unsigned short* __restrict__ C2, const float* __restrict__ q2b,
    const int* __restrict__ topk_idx, const float* __restrict__ W2e,
    const float* __restrict__ b2e, float* __restrict__ s2) {
  const int tid = threadIdx.x;
  const int ln = tid & 63;
  const int e = blockIdx.x * 4 + (tid >> 6);
  const int b = e / TOPK_;
  const int idx = topk_idx[e];
  const v4u16 kv = *(const v4u16*)(C2 + (size_t)idx * H2_ + ln * 4);
  const float4 qv = *(const float4*)(q2b + b * H2_ + ln * 4);
  float s = gelu_f(qv.x + bf2f(kv[0])) * W2e[ln * 4 + 0]
          + gelu_f(qv.y + bf2f(kv[1])) * W2e[ln * 4 + 1]
          + gelu_f(qv.z + bf2f(kv[2])) * W2e[ln * 4 + 2]
          + gelu_f(qv.w + bf2f(kv[3])) * W2e[ln * 4 + 3];
#pragma unroll
  for (int off = 32; off > 0; off >>= 1) s += __shfl_down(s, off);
  if (ln == 0) s2[e] = s + b2e[0];
}

// ---------- w2 = softmax(s2) per row ----------
__global__ __launch_bounds__(256) void k_soft(
    const float* __restrict__ s2, float* __restrict__ w2) {
  __shared__ float red[256];
  const int tid = threadIdx.x, b = blockIdx.x;
  float m = -3.4e38f;
  for (int t = tid; t < TOPK_; t += 256) m = fmaxf(m, s2[b * TOPK_ + t]);
  red[tid] = m;
  __syncthreads();
  for (int s = 128; s > 0; s >>= 1) {
    if (tid < s) red[tid] = fmaxf(red[tid], red[tid + s]);
    __syncthreads();
  }
  m = red[0];
  __syncthreads();
  float ps = 0.f;
  for (int t = tid; t < TOPK_; t += 256) {
    const float ev = expf(s2[b * TOPK_ + t] - m);
    w2[b * TOPK_ + t] = ev;
    ps += ev;
  }
  red[tid] = ps;
  __syncthreads();
  for (int s = 128; s > 0; s >>= 1) {
    if (tid < s) red[tid] += red[tid + s];
    __syncthreads();
  }
  const float inv = 1.f / red[0];
  for (int t = tid; t < TOPK_; t += 256) w2[b * TOPK_ + t] *= inv;
}

// ---------- zero accumulators ----------
__global__ void k_zero(float* __restrict__ p, int n) {
  const int i = blockIdx.x * 256 + threadIdx.x;
  if (i < n) p[i] = 0.f;
}

// ---------- weighted actions/results (gather-reduce, 8 chunks per b) ----------
__global__ __launch_bounds__(256) void k_weighted(
    const int* __restrict__ topk_idx, const float* __restrict__ w2,
    const float* __restrict__ memory, float* __restrict__ wact_acc,
    float* __restrict__ wres_acc) {
  const int blk = blockIdx.x;  // 32b x 8 chunks
  const int b = blk >> 3, c = blk & 7;
  const int tid = threadIdx.x;
  const int g = tid >> 7, a = tid & 127;
  float acc = 0.f, accr = 0.f;
  for (int t = c * 125 + g; t < (c + 1) * 125; t += 2) {
    const int idx = topk_idx[b * TOPK_ + t];
    const float wv = w2[b * TOPK_ + t];
    acc += truncf(memory[(size_t)idx * E_ + F_ + a]) * wv;
    if (a == 0) accr += wv * memory[(size_t)idx * E_ + (E_ - 1)];
  }
  atomicAdd(&wact_acc[b * 128 + a], acc);
  if (a == 0) atomicAdd(&wres_acc[b], accr);
}

// ---------- hp = gelu([features|wact] @ Wp1 + bp1) ----------
__global__ __launch_bounds__(256) void k_hp(
    const float* __restrict__ features, const float* __restrict__ ws_wact,
    const float* __restrict__ Wp1, const float* __restrict__ bp1,
    float* __restrict__ hp) {
  const int j = blockIdx.x * 256 + threadIdx.x;
  const int b = blockIdx.y;
  const float* A = features + b * F_;
  const float* wa = ws_wact + b * 128;
  float acc = bp1[j];
  for (int h = 0; h < F_; ++h) acc += A[h] * Wp1[(size_t)h * PH_ + j];
  for (int h = 0; h < 128; ++h) acc += wa[h] * Wp1[(size_t)(F_ + h) * PH_ + j];
  hp[b * PH_ + j] = gelu_f(acc);
}

// ---------- logits ----------
__global__ __launch_bounds__(256) void k_logits_init(
    const float* __restrict__ bp2, float* __restrict__ out) {
  const int i = blockIdx.x * 256 + threadIdx.x;
  if (i < B_ * ADIM_) out[i] = bp2[i % ADIM_];
}

__global__ __launch_bounds__(256) void k_logits(
    const float* __restrict__ hp, const float* __restrict__ Wp2,
    float* __restrict__ out) {
  __shared__ float lhp[32 * 192];
  const int tid = threadIdx.x;
  const int h0 = blockIdx.y * 192;
  const int col = blockIdx.x * 64 + (tid & 63);
  const int tg = tid >> 6;
  for (int i2 = tid; i2 < 32 * 192; i2 += 256) {
    const int bb = i2 / 192, h = i2 - bb * 192;
    lhp[i2] = hp[bb * PH_ + h0 + h];
  }
  __syncthreads();
  float acc[8] = {0.f, 0.f, 0.f, 0.f, 0.f, 0.f, 0.f, 0.f};
  for (int h = 0; h < 192; ++h) {
    const float w = Wp2[(size_t)(h0 + h) * ADIM_ + col];
#pragma unroll
    for (int bb = 0; bb < 8; ++bb) acc[bb] += lhp[(tg * 8 + bb) * 192 + h] * w;
  }
#pragma unroll
  for (int bb = 0; bb < 8; ++bb)
    atomicAdd(&out[(size_t)(tg * 8 + bb) * ADIM_ + col], acc[bb]);
}

// ---------- board_vals (tanh) and adaptive weight (sigmoid) ----------
__global__ __launch_bounds__(512) void k_value_nets(
    const float* __restrict__ features, const float* __restrict__ Wv1,
    const float* __restrict__ bv1, const float* __restrict__ Wv2,
    const float* __restrict__ bv2, const float* __restrict__ Wm1,
    const float* __restrict__ bm1, const float* __restrict__ Wm2,
    const float* __restrict__ bm2, float* __restrict__ ws_aw,
    float* __restrict__ out) {
  __shared__ float red[512];
  const int tid = threadIdx.x;
  const int b = blockIdx.x;
  const int net = blockIdx.y;
  const float* W1 = net ? Wm1 : Wv1;
  const float* bb1 = net ? bm1 : bv1;
  const float* W2 = net ? Wm2 : Wv2;
  const float* bb2 = net ? bm2 : bv2;
  const float* A = features + b * F_;
  float acc = bb1[tid];
  for (int h = 0; h < F_; ++h) acc += A[h] * W1[(size_t)h * 512 + tid];
  red[tid] = gelu_f(acc) * W2[tid];
  __syncthreads();
  for (int s = 256; s > 0; s >>= 1) {
    if (tid < s) red[tid] += red[tid + s];
    __syncthreads();
  }
  if (tid == 0) {
    const float v = red[0] + bb2[0];
    if (net == 0) out[OFF_BV + b] = tanhf(v);
    else ws_aw[b] = 1.f / (1.f + expf(-v));
  }
}

// ---------- finalize: copy wact/wres to out; value_output ----------
__global__ __launch_bounds__(256) void k_finalize(
    const float* __restrict__ wact, const float* __restrict__ wres,
    const float* __restrict__ aw, float* __restrict__ out) {
  const int i = blockIdx.x * 256 + threadIdx.x;
  if (i < 4096) {
    out[OFF_WACT + i] = wact[i];
  } else if (i < 4128) {
    const int b = i - 4096;
    out[OFF_WRES + b] = wres[b];
    const float A = aw[b];
    out[OFF_VAL + b] = A * wres[b] + (1.f - A) * out[OFF_BV + b];
  }
}

extern "C" void kernel_launch(void* const* d_in, const int* in_sizes, int n_in,
                              void* d_out, int out_size, void* d_ws,
                              size_t ws_size, hipStream_t stream) {
  (void)in_sizes; (void)n_in; (void)out_size; (void)ws_size;
  const float* features = (const float*)d_in[0];
  const float* memory   = (const float*)d_in[1];
  const float* W1s = (const float*)d_in[2];
  const float* b1s = (const float*)d_in[3];
  const float* W2s = (const float*)d_in[4];
  const float* b2s = (const float*)d_in[5];
  const float* W1e = (const float*)d_in[6];
  const float* b1e = (const float*)d_in[7];
  const float* W2e = (const float*)d_in[8];
  const float* b2e = (const float*)d_in[9];
  const float* Wp1 = (const float*)d_in[10];
  const float* bp1 = (const float*)d_in[11];
  const float* Wp2 = (const float*)d_in[12];
  const float* bp2 = (const float*)d_in[13];
  const float* Wv1 = (const float*)d_in[14];
  const float* bv1 = (const float*)d_in[15];
  const float* Wv2 = (const float*)d_in[16];
  const float* bv2 = (const float*)d_in[17];
  const float* Wm1 = (const float*)d_in[18];
  const float* bm1 = (const float*)d_in[19];
  const float* Wm2 = (const float*)d_in[20];
  const float* bm2 = (const float*)d_in[21];
  float* out = (float*)d_out;

  // workspace layout (bytes)
  char* W = (char*)d_ws;
  unsigned short* Ahi  = (unsigned short*)(W);                      // 16 MB
  unsigned short* Alo  = (unsigned short*)(W + (16u << 20));        // 16 MB
  unsigned short* B1hi = (unsigned short*)(W + (32u << 20));        // 1 MB
  unsigned short* B1lo = (unsigned short*)(W + (33u << 20));        // 1 MB
  unsigned short* B2hi = (unsigned short*)(W + (34u << 20));        // 0.5 MB
  float*          C1   = (float*)(W + (35u << 20));                 // 16 MB
  unsigned short* C2   = (unsigned short*)(W + (51u << 20));        // 4 MB
  float*          scores = (float*)(W + (55u << 20));               // 1 MB
  char* S = W + (56u << 20);
  float* q1b      = (float*)(S);
  float* q2b      = (float*)(S + 65536);
  float* s2       = (float*)(S + 98304);
  float* w2       = (float*)(S + 226304);
  int*   topk     = (int*)  (S + 354304);
  float* wact_acc = (float*)(S + 482304);
  float* wres_acc = (float*)(S + 498688);
  float* aw       = (float*)(S + 498816);
  float* hp       = (float*)(S + 498944);

  k_split_mem<<<8192, 256, 0, stream>>>(memory, Ahi, Alo);
  k_split_w<<<dim3(24, 32), dim3(32, 8), 0, stream>>>(W1s, W1e, B1hi, B1lo, B2hi);
  k_q1q2<<<dim3(3, 32), 256, 0, stream>>>(features, W1s, W1e, b1s, b1e, q1b, q2b);
  k_gemm1<<<dim3(64, 8), 256, 0, stream>>>(Ahi, Alo, B1hi, B1lo, C1);
  k_gemm2<<<dim3(64, 4), 256, 0, stream>>>(Ahi, B2hi, C2);
  k_scores<<<128, 256, 0, stream>>>(C1, q1b, W2s, b2s, scores);
  k_topk<<<32, 1024, 0, stream>>>(scores, topk);
  k_s2<<<8000, 256, 0, stream>>>(C2, q2b, topk, W2e, b2e, s2);
  k_soft<<<32, 256, 0, stream>>>(s2, w2);
  k_zero<<<17, 256, 0, stream>>>(wact_acc, 4128);
  k_weighted<<<256, 256, 0, stream>>>(topk, w2, memory, wact_acc, wres_acc);
  k_hp<<<dim3(3, 32), 256, 0, stream>>>(features, wact_acc, Wp1, bp1, hp);
  k_logits_init<<<584, 256, 0, stream>>>(bp2, out);
  k_logits<<<dim3(73, 4), 256, 0, stream>>>(hp, Wp2, out);
  k_value_nets<<<dim3(32, 2), 512, 0, stream>>>(features, Wv1, bv1, Wv2, bv2,
                                                Wm1, bm1, Wm2, bm2, aw, out);
  k_finalize<<<17, 256, 0, stream>>>(wact_acc, wres_acc, aw, out);
}

// Round 3
// 389.910 us; speedup vs baseline: 1.9300x; 1.5562x over previous
//
#include <hip/hip_runtime.h>
#include <math.h>

#define B_ 32
#define K_ 8192
#define TOPK_ 1000
#define F_ 1024
#define E_ 1153
#define H1_ 512
#define H2_ 256
#define PH_ 768
#define ADIM_ 4672

// output layout (floats): logits | board_vals | value | wact | wres
#define OFF_BV   149504
#define OFF_VAL  149536
#define OFF_WACT 149568
#define OFF_WRES 153664

typedef __attribute__((ext_vector_type(8))) short v8s;
typedef __attribute__((ext_vector_type(4))) float v4f;
typedef __attribute__((ext_vector_type(4))) unsigned short v4u16;

#define GLD16(gp, lp) __builtin_amdgcn_global_load_lds( \
    (const __attribute__((address_space(1))) void*)(gp), \
    (__attribute__((address_space(3))) void*)(lp), 16, 0, 0)

__device__ __forceinline__ float gelu_f(float x) {
  return 0.5f * x * (1.0f + erff(x * 0.70710678118654752440f));
}
__device__ __forceinline__ unsigned short f2bf(float x) {
  union { float f; unsigned u; } v; v.f = x;
  unsigned r = v.u + 0x7fffu + ((v.u >> 16) & 1u);
  return (unsigned short)(r >> 16);
}
__device__ __forceinline__ float bf2f(unsigned short h) {
  union { unsigned u; float f; } v; v.u = ((unsigned)h) << 16; return v.f;
}

// ---------- split/convert memory[:, :F] -> Ahi, Alo (bf16, [8192][1024]) ----------
__global__ __launch_bounds__(256) void k_split_mem(
    const float* __restrict__ memory, unsigned short* __restrict__ Ahi,
    unsigned short* __restrict__ Alo) {
  const int r = blockIdx.x;
  const int tid = threadIdx.x;
  const float* src = memory + (size_t)r * E_;
#pragma unroll
  for (int i = 0; i < 4; ++i) {
    const float x = src[tid + 256 * i];
    const unsigned short h = f2bf(x);
    Ahi[(size_t)r * 1024 + tid + 256 * i] = h;
    Alo[(size_t)r * 1024 + tid + 256 * i] = f2bf(x - bf2f(h));
  }
}

// ---------- transpose+split weights: B1hi/lo [512][1024], B2hi [256][1024] ----------
__global__ __launch_bounds__(256) void k_split_w(
    const float* __restrict__ W1s, const float* __restrict__ W1e,
    unsigned short* __restrict__ B1hi, unsigned short* __restrict__ B1lo,
    unsigned short* __restrict__ B2hi) {
  __shared__ float t[32][33];
  const int x = threadIdx.x, y = threadIdx.y;  // 32 x 8
  const int j0 = blockIdx.x * 32, k0 = blockIdx.y * 32;
#pragma unroll
  for (int i = 0; i < 4; ++i) {
    const int k = k0 + y + 8 * i;
    const int j = j0 + x;
    t[y + 8 * i][x] = (j < 512) ? W1s[(size_t)(F_ + k) * H1_ + j]
                                : W1e[(size_t)(F_ + k) * H2_ + (j - 512)];
  }
  __syncthreads();
#pragma unroll
  for (int i = 0; i < 4; ++i) {
    const int j = j0 + y + 8 * i;
    const int k = k0 + x;
    const float v = t[x][y + 8 * i];
    const unsigned short h = f2bf(v);
    if (j < 512) {
      B1hi[(size_t)j * 1024 + k] = h;
      B1lo[(size_t)j * 1024 + k] = f2bf(v - bf2f(h));
    } else {
      B2hi[(size_t)(j - 512) * 1024 + k] = h;
    }
  }
}

// ---------- bias init for atomic-accumulated buffers (+ zero wact/wres) ----------
__global__ __launch_bounds__(256) void k_init5(
    const float* __restrict__ b1s, const float* __restrict__ b1e,
    const float* __restrict__ bv1, const float* __restrict__ bm1,
    const float* __restrict__ bp1, float* __restrict__ q1b,
    float* __restrict__ q2b, float* __restrict__ v1h, float* __restrict__ m1h,
    float* __restrict__ hp_acc, float* __restrict__ wact,
    float* __restrict__ wres) {
  const int idx = blockIdx.x * 256 + threadIdx.x;
  if (idx < 32 * 2560) {
    const int b = idx / 2560, j = idx - b * 2560;
    if (j < 512) q1b[b * 512 + j] = b1s[j];
    else if (j < 768) q2b[b * 256 + (j - 512)] = b1e[j - 512];
    else if (j < 1280) v1h[b * 512 + (j - 768)] = bv1[j - 768];
    else if (j < 1792) m1h[b * 512 + (j - 1280)] = bm1[j - 1280];
    else hp_acc[b * 768 + (j - 1792)] = bp1[j - 1792];
  } else {
    const int k = idx - 32 * 2560;
    if (k < 4096) wact[k] = 0.f;
    else if (k < 4128) wres[k - 4096] = 0.f;
  }
}

// ---------- batched split-K GEMM: [q1|q2|v1h|m1h] += features @ W ----------
// grid (28 ntiles, 8 ksplits); A-rows via readfirstlane -> s_load (SALU pipe).
__global__ __launch_bounds__(256) void k_batch1(
    const float* __restrict__ features, const float* __restrict__ W1s,
    const float* __restrict__ W1e, const float* __restrict__ Wv1,
    const float* __restrict__ Wm1, float* __restrict__ q1b,
    float* __restrict__ q2b, float* __restrict__ v1h,
    float* __restrict__ m1h) {
  const int t = blockIdx.x, kc0 = blockIdx.y * 128;
  const float* Wp; float* Cp; int ldw, n0;
  if (t < 8)       { Wp = W1s; Cp = q1b; ldw = 512; n0 = t * 64; }
  else if (t < 12) { Wp = W1e; Cp = q2b; ldw = 256; n0 = (t - 8) * 64; }
  else if (t < 20) { Wp = Wv1; Cp = v1h; ldw = 512; n0 = (t - 12) * 64; }
  else             { Wp = Wm1; Cp = m1h; ldw = 512; n0 = (t - 20) * 64; }
  const int col = n0 + (threadIdx.x & 63);
  const int r0 = __builtin_amdgcn_readfirstlane((int)(threadIdx.x >> 6)) * 8;
  const float* A = features + (size_t)r0 * F_ + kc0;
  float acc[8] = {0.f, 0.f, 0.f, 0.f, 0.f, 0.f, 0.f, 0.f};
  for (int k = 0; k < 128; ++k) {
    const float w = Wp[(size_t)(kc0 + k) * ldw + col];
#pragma unroll
    for (int r = 0; r < 8; ++r) acc[r] = fmaf(A[r * F_ + k], w, acc[r]);
  }
#pragma unroll
  for (int r = 0; r < 8; ++r)
    atomicAdd(&Cp[(size_t)(r0 + r) * ldw + col], acc[r]);
}

// ---------- staging helper: 16B chunks into pad-80 LDS rows (5 chunks/row) ----------
__device__ __forceinline__ void stage80(
    const unsigned short* __restrict__ src, int row_base, int k0,
    char* lds, int lds_off, int nchunks, int tid) {
  for (int i = 0; i * 256 < nchunks; ++i) {
    const int c = i * 256 + tid;
    if (c < nchunks) {
      const int row = c / 5, sub = c % 5;
      const int s = (sub == 4) ? 0 : sub;  // pad chunk loads row start (unused)
      const unsigned short* g = src + (size_t)(row_base + row) * 1024 + k0 + s * 8;
      GLD16(g, lds + lds_off + i * 4096 + ((tid >> 6) * 1024));
    }
  }
}

// ---------- GEMM1 (selection): C1 fp32 [8192][512] = A(hi+lo) @ B1(hi+lo)^T, 3-term ----------
__global__ __launch_bounds__(256) void k_gemm1(
    const unsigned short* __restrict__ Ahi, const unsigned short* __restrict__ Alo,
    const unsigned short* __restrict__ B1hi, const unsigned short* __restrict__ B1lo,
    float* __restrict__ C1) {
  __shared__ unsigned short lds[15360];  // 30720B: Ahi@0 Alo@10240 Bhi@20480 Blo@25600
  char* L = (char*)lds;
  const int tid = threadIdx.x;
  const int lane = tid & 63, w = tid >> 6;
  const int m0 = blockIdx.x * 128;
  const int n0 = blockIdx.y * 64;
  const int wr = w >> 1, wc = w & 1;
  v4f acc[4][2];
#pragma unroll
  for (int mi = 0; mi < 4; ++mi)
#pragma unroll
    for (int ni = 0; ni < 2; ++ni) acc[mi][ni] = (v4f)(0.f);

  for (int k0 = 0; k0 < 1024; k0 += 32) {
    __syncthreads();
    stage80(Ahi, m0, k0, L, 0, 640, tid);
    stage80(Alo, m0, k0, L, 10240, 640, tid);
    stage80(B1hi, n0, k0, L, 20480, 320, tid);
    stage80(B1lo, n0, k0, L, 25600, 320, tid);
    asm volatile("s_waitcnt vmcnt(0)" ::: "memory");
    __syncthreads();
    v8s ah[4], al[4], bh[2], bl[2];
    const int fo = (lane >> 4) * 16;
#pragma unroll
    for (int mi = 0; mi < 4; ++mi) {
      const int ro = (wr * 64 + mi * 16 + (lane & 15)) * 80 + fo;
      ah[mi] = *(const v8s*)(L + ro);
      al[mi] = *(const v8s*)(L + 10240 + ro);
    }
#pragma unroll
    for (int ni = 0; ni < 2; ++ni) {
      const int ro = (wc * 32 + ni * 16 + (lane & 15)) * 80 + fo;
      bh[ni] = *(const v8s*)(L + 20480 + ro);
      bl[ni] = *(const v8s*)(L + 25600 + ro);
    }
#pragma unroll
    for (int mi = 0; mi < 4; ++mi)
#pragma unroll
      for (int ni = 0; ni < 2; ++ni) {
        acc[mi][ni] = __builtin_amdgcn_mfma_f32_16x16x32_bf16(ah[mi], bh[ni], acc[mi][ni], 0, 0, 0);
        acc[mi][ni] = __builtin_amdgcn_mfma_f32_16x16x32_bf16(ah[mi], bl[ni], acc[mi][ni], 0, 0, 0);
        acc[mi][ni] = __builtin_amdgcn_mfma_f32_16x16x32_bf16(al[mi], bh[ni], acc[mi][ni], 0, 0, 0);
      }
  }
#pragma unroll
  for (int mi = 0; mi < 4; ++mi)
#pragma unroll
    for (int ni = 0; ni < 2; ++ni)
#pragma unroll
      for (int j = 0; j < 4; ++j) {
        const int mrow = m0 + wr * 64 + mi * 16 + (lane >> 4) * 4 + j;
        const int ncol = n0 + wc * 32 + ni * 16 + (lane & 15);
        C1[(size_t)mrow * 512 + ncol] = acc[mi][ni][j];
      }
}

// ---------- GEMM2 (evidence): C2 bf16 [8192][256] = Ahi @ B2hi^T, 1-term ----------
__global__ __launch_bounds__(256) void k_gemm2(
    const unsigned short* __restrict__ Ahi, const unsigned short* __restrict__ B2hi,
    unsigned short* __restrict__ C2) {
  __shared__ unsigned short lds[7680];
  char* L = (char*)lds;
  const int tid = threadIdx.x;
  const int lane = tid & 63, w = tid >> 6;
  const int m0 = blockIdx.x * 128;
  const int n0 = blockIdx.y * 64;
  const int wr = w >> 1, wc = w & 1;
  v4f acc[4][2];
#pragma unroll
  for (int mi = 0; mi < 4; ++mi)
#pragma unroll
    for (int ni = 0; ni < 2; ++ni) acc[mi][ni] = (v4f)(0.f);

  for (int k0 = 0; k0 < 1024; k0 += 32) {
    __syncthreads();
    stage80(Ahi, m0, k0, L, 0, 640, tid);
    stage80(B2hi, n0, k0, L, 10240, 320, tid);
    asm volatile("s_waitcnt vmcnt(0)" ::: "memory");
    __syncthreads();
    v8s ah[4], bh[2];
    const int fo = (lane >> 4) * 16;
#pragma unroll
    for (int mi = 0; mi < 4; ++mi)
      ah[mi] = *(const v8s*)(L + (wr * 64 + mi * 16 + (lane & 15)) * 80 + fo);
#pragma unroll
    for (int ni = 0; ni < 2; ++ni)
      bh[ni] = *(const v8s*)(L + 10240 + (wc * 32 + ni * 16 + (lane & 15)) * 80 + fo);
#pragma unroll
    for (int mi = 0; mi < 4; ++mi)
#pragma unroll
      for (int ni = 0; ni < 2; ++ni)
        acc[mi][ni] = __builtin_amdgcn_mfma_f32_16x16x32_bf16(ah[mi], bh[ni], acc[mi][ni], 0, 0, 0);
  }
#pragma unroll
  for (int mi = 0; mi < 4; ++mi)
#pragma unroll
    for (int ni = 0; ni < 2; ++ni)
#pragma unroll
      for (int j = 0; j < 4; ++j) {
        const int mrow = m0 + wr * 64 + mi * 16 + (lane >> 4) * 4 + j;
        const int ncol = n0 + wc * 32 + ni * 16 + (lane & 15);
        C2[(size_t)mrow * 256 + ncol] = f2bf(acc[mi][ni][j]);
      }
}

// ---------- scores v2: 1024 blocks, 8 k-rows staged in LDS, 1 (b,k) per thread ----------
__global__ __launch_bounds__(256) void k_scores2(
    const float* __restrict__ C1, const float* __restrict__ q1b,
    const float* __restrict__ W2s, const float* __restrict__ b2s,
    float* __restrict__ scores) {
  __shared__ float4 c4[8 * 129];  // row pad 129 f4 (516 f): 8 rows cover all 32 banks
  __shared__ float4 w4[128];
  const int tid = threadIdx.x;
  const int kbase = blockIdx.x * 8;
#pragma unroll
  for (int p = 0; p < 4; ++p) {
    const int idx = p * 256 + tid;
    const int row = idx >> 7, c = idx & 127;
    c4[row * 129 + c] = *(const float4*)&C1[(size_t)(kbase + row) * 512 + c * 4];
  }
  if (tid < 128) w4[tid] = *(const float4*)&W2s[tid * 4];
  __syncthreads();
  const int b = tid >> 3, ks = tid & 7;
  const float4* qrow = (const float4*)&q1b[b * 512];
  float acc = 0.f;
  for (int i = 0; i < 128; ++i) {
    const float4 c = c4[ks * 129 + i];
    const float4 q = qrow[i];
    const float4 w = w4[i];
    acc += fmaxf(q.x + c.x, 0.f) * w.x + fmaxf(q.y + c.y, 0.f) * w.y +
           fmaxf(q.z + c.z, 0.f) * w.z + fmaxf(q.w + c.w, 0.f) * w.w;
  }
  scores[(size_t)b * K_ + kbase + ks] = acc + b2s[0];
}

// ---------- exact top-1000 (set semantics; ties by lowest index) ----------
__global__ __launch_bounds__(1024) void k_topk(
    const float* __restrict__ scores, int* __restrict__ topk_idx) {
  __shared__ unsigned key[K_];
  __shared__ unsigned whist[16][256];
  __shared__ unsigned sfx[256];
  __shared__ int eqlist[1024];
  __shared__ unsigned ctl[4];
  const int tid = threadIdx.x;
  const int wid = tid >> 6;
  const int b = blockIdx.x;
  const float* row = scores + (size_t)b * K_;
  for (int i = tid; i < K_; i += 1024) {
    const unsigned u = __float_as_uint(row[i]);
    key[i] = (u & 0x80000000u) ? ~u : (u | 0x80000000u);
  }
  unsigned prefix = 0;
  int r = TOPK_;
  for (int p = 0; p < 4; ++p) {
    const int shift = 24 - 8 * p;
    for (int i = tid; i < 16 * 256; i += 1024) ((unsigned*)whist)[i] = 0;
    __syncthreads();
    const unsigned pmask = (p == 0) ? 0u : (0xFFFFFFFFu << (shift + 8));
    for (int i = tid; i < K_; i += 1024) {
      const unsigned k = key[i];
      if ((k & pmask) == prefix) atomicAdd(&whist[wid][(k >> shift) & 255u], 1u);
    }
    __syncthreads();
    if (tid < 256) {
      unsigned s = 0;
#pragma unroll
      for (int ww = 0; ww < 16; ++ww) s += whist[ww][tid];
      sfx[tid] = s;
    }
    __syncthreads();
    for (int off = 1; off < 256; off <<= 1) {
      unsigned v = 0;
      if (tid < 256) { v = sfx[tid]; if (tid + off < 256) v += sfx[tid + off]; }
      __syncthreads();
      if (tid < 256) sfx[tid] = v;
      __syncthreads();
    }
    if (tid < 256) {
      const int Sge = (int)sfx[tid];
      const int Sgt = (tid < 255) ? (int)sfx[tid + 1] : 0;
      if (Sgt < r && r <= Sge) { ctl[0] = (unsigned)tid; ctl[1] = (unsigned)(r - Sgt); }
    }
    __syncthreads();
    prefix |= ctl[0] << shift;
    r = (int)ctl[1];
    __syncthreads();
  }
  const unsigned T = prefix;
  const int take_eq = r;
  if (tid == 0) { ctl[2] = 0; ctl[3] = 0; }
  __syncthreads();
  int* outp = topk_idx + b * TOPK_;
  for (int i = tid; i < K_; i += 1024) {
    const unsigned k = key[i];
    if (k > T) outp[atomicAdd(&ctl[2], 1u)] = i;
    else if (k == T) { const unsigned e = atomicAdd(&ctl[3], 1u); if (e < 1024) eqlist[e] = i; }
  }
  __syncthreads();
  const int m = (ctl[3] < 1024u) ? (int)ctl[3] : 1024;
  const int ngt = TOPK_ - take_eq;
  for (int sel = 0; sel < take_eq; ++sel) {
    key[tid] = (tid < m) ? (unsigned)eqlist[tid] : 0xFFFFFFFFu;
    __syncthreads();
    for (int s = 512; s > 0; s >>= 1) {
      if (tid < s) key[tid] = min(key[tid], key[tid + s]);
      __syncthreads();
    }
    const unsigned mn = key[0];
    if (tid < m && (unsigned)eqlist[tid] == mn) eqlist[tid] = 0x7FFFFFFF;
    if (tid == 0) outp[ngt + sel] = (int)mn;
    __syncthreads();
  }
}

// ---------- s2[e] = b2e + sum_j gelu(q2b[b][j] + C2[idx][j]) * W2e[j] ----------
__global__ __launch_bounds__(256) void k_s2(
    const unsigned short* __restrict__ C2, const float* __restrict__ q2b,
    const int* __restrict__ topk_idx, const float* __restrict__ W2e,
    const float* __restrict__ b2e, float* __restrict__ s2) {
  const int tid = threadIdx.x;
  const int ln = tid & 63;
  const int e = blockIdx.x * 4 + (tid >> 6);
  const int b = e / TOPK_;
  const int idx = topk_idx[e];
  const v4u16 kv = *(const v4u16*)(C2 + (size_t)idx * H2_ + ln * 4);
  const float4 qv = *(const float4*)(q2b + b * H2_ + ln * 4);
  float s = gelu_f(qv.x + bf2f(kv[0])) * W2e[ln * 4 + 0]
          + gelu_f(qv.y + bf2f(kv[1])) * W2e[ln * 4 + 1]
          + gelu_f(qv.z + bf2f(kv[2])) * W2e[ln * 4 + 2]
          + gelu_f(qv.w + bf2f(kv[3])) * W2e[ln * 4 + 3];
#pragma unroll
  for (int off = 32; off > 0; off >>= 1) s += __shfl_down(s, off);
  if (ln == 0) s2[e] = s + b2e[0];
}

// ---------- w2 = softmax(s2) per row ----------
__global__ __launch_bounds__(256) void k_soft(
    const float* __restrict__ s2, float* __restrict__ w2) {
  __shared__ float red[256];
  const int tid = threadIdx.x, b = blockIdx.x;
  float m = -3.4e38f;
  for (int t = tid; t < TOPK_; t += 256) m = fmaxf(m, s2[b * TOPK_ + t]);
  red[tid] = m;
  __syncthreads();
  for (int s = 128; s > 0; s >>= 1) {
    if (tid < s) red[tid] = fmaxf(red[tid], red[tid + s]);
    __syncthreads();
  }
  m = red[0];
  __syncthreads();
  float ps = 0.f;
  for (int t = tid; t < TOPK_; t += 256) {
    const float ev = expf(s2[b * TOPK_ + t] - m);
    w2[b * TOPK_ + t] = ev;
    ps += ev;
  }
  red[tid] = ps;
  __syncthreads();
  for (int s = 128; s > 0; s >>= 1) {
    if (tid < s) red[tid] += red[tid + s];
    __syncthreads();
  }
  const float inv = 1.f / red[0];
  for (int t = tid; t < TOPK_; t += 256) w2[b * TOPK_ + t] *= inv;
}

// ---------- weighted actions/results (gather-reduce, 8 chunks per b) ----------
__global__ __launch_bounds__(256) void k_weighted(
    const int* __restrict__ topk_idx, const float* __restrict__ w2,
    const float* __restrict__ memory, float* __restrict__ wact_acc,
    float* __restrict__ wres_acc) {
  const int blk = blockIdx.x;
  const int b = blk >> 3, c = blk & 7;
  const int tid = threadIdx.x;
  const int g = tid >> 7, a = tid & 127;
  float acc = 0.f, accr = 0.f;
  for (int t = c * 125 + g; t < (c + 1) * 125; t += 2) {
    const int idx = topk_idx[b * TOPK_ + t];
    const float wv = w2[b * TOPK_ + t];
    acc += truncf(memory[(size_t)idx * E_ + F_ + a]) * wv;
    if (a == 0) accr += wv * memory[(size_t)idx * E_ + (E_ - 1)];
  }
  atomicAdd(&wact_acc[b * 128 + a], acc);
  if (a == 0) atomicAdd(&wres_acc[b], accr);
}

// ---------- value head epilogue: tanh / sigmoid ----------
__global__ __launch_bounds__(512) void k_value_epi(
    const float* __restrict__ v1h, const float* __restrict__ m1h,
    const float* __restrict__ Wv2, const float* __restrict__ bv2,
    const float* __restrict__ Wm2, const float* __restrict__ bm2,
    float* __restrict__ aw, float* __restrict__ out) {
  __shared__ float red[512];
  const int tid = threadIdx.x, b = blockIdx.x, net = blockIdx.y;
  const float* h = net ? m1h : v1h;
  const float* W2 = net ? Wm2 : Wv2;
  red[tid] = gelu_f(h[b * 512 + tid]) * W2[tid];
  __syncthreads();
  for (int s = 256; s > 0; s >>= 1) {
    if (tid < s) red[tid] += red[tid + s];
    __syncthreads();
  }
  if (tid == 0) {
    const float v = red[0] + (net ? bm2[0] : bv2[0]);
    if (net == 0) out[OFF_BV + b] = tanhf(v);
    else aw[b] = 1.f / (1.f + expf(-v));
  }
}

// ---------- hp split-K: hp_acc += [features|wact] @ Wp1 ----------
__global__ __launch_bounds__(256) void k_hp2(
    const float* __restrict__ features, const float* __restrict__ wact,
    const float* __restrict__ Wp1, float* __restrict__ hp_acc) {
  const int kc0 = blockIdx.y * 128;
  const int col = blockIdx.x * 64 + (threadIdx.x & 63);
  const int r0 = __builtin_amdgcn_readfirstlane((int)(threadIdx.x >> 6)) * 8;
  const float* A; int lda;
  if (blockIdx.y == 8) { A = wact + (size_t)r0 * 128; lda = 128; }
  else { A = features + (size_t)r0 * F_ + kc0; lda = F_; }
  float acc[8] = {0.f, 0.f, 0.f, 0.f, 0.f, 0.f, 0.f, 0.f};
  for (int k = 0; k < 128; ++k) {
    const float w = Wp1[(size_t)(kc0 + k) * PH_ + col];
#pragma unroll
    for (int r = 0; r < 8; ++r) acc[r] = fmaf(A[r * lda + k], w, acc[r]);
  }
#pragma unroll
  for (int r = 0; r < 8; ++r)
    atomicAdd(&hp_acc[(size_t)(r0 + r) * PH_ + col], acc[r]);
}

// ---------- in-place gelu ----------
__global__ void k_gelu_ip(float* __restrict__ p, int n) {
  const int i = blockIdx.x * 256 + threadIdx.x;
  if (i < n) p[i] = gelu_f(p[i]);
}

// ---------- logits bias init ----------
__global__ __launch_bounds__(256) void k_logits_init(
    const float* __restrict__ bp2, float* __restrict__ out) {
  const int i = blockIdx.x * 256 + threadIdx.x;
  if (i < B_ * ADIM_) out[i] = bp2[i % ADIM_];
}

// ---------- logits split-K: out += hp @ Wp2 ----------
__global__ __launch_bounds__(256) void k_logits2(
    const float* __restrict__ hp, const float* __restrict__ Wp2,
    float* __restrict__ out) {
  const int kc0 = blockIdx.y * 256;
  const int col = blockIdx.x * 64 + (threadIdx.x & 63);
  const int r0 = __builtin_amdgcn_readfirstlane((int)(threadIdx.x >> 6)) * 8;
  const float* A = hp + (size_t)r0 * PH_ + kc0;
  float acc[8] = {0.f, 0.f, 0.f, 0.f, 0.f, 0.f, 0.f, 0.f};
  for (int k = 0; k < 256; ++k) {
    const float w = Wp2[(size_t)(kc0 + k) * ADIM_ + col];
#pragma unroll
    for (int r = 0; r < 8; ++r) acc[r] = fmaf(A[r * PH_ + k], w, acc[r]);
  }
#pragma unroll
  for (int r = 0; r < 8; ++r)
    atomicAdd(&out[(size_t)(r0 + r) * ADIM_ + col], acc[r]);
}

// ---------- finalize ----------
__global__ __launch_bounds__(256) void k_finalize(
    const float* __restrict__ wact, const float* __restrict__ wres,
    const float* __restrict__ aw, float* __restrict__ out) {
  const int i = blockIdx.x * 256 + threadIdx.x;
  if (i < 4096) {
    out[OFF_WACT + i] = wact[i];
  } else if (i < 4128) {
    const int b = i - 4096;
    out[OFF_WRES + b] = wres[b];
    const float A = aw[b];
    out[OFF_VAL + b] = A * wres[b] + (1.f - A) * out[OFF_BV + b];
  }
}

extern "C" void kernel_launch(void* const* d_in, const int* in_sizes, int n_in,
                              void* d_out, int out_size, void* d_ws,
                              size_t ws_size, hipStream_t stream) {
  (void)in_sizes; (void)n_in; (void)out_size; (void)ws_size;
  const float* features = (const float*)d_in[0];
  const float* memory   = (const float*)d_in[1];
  const float* W1s = (const float*)d_in[2];
  const float* b1s = (const float*)d_in[3];
  const float* W2s = (const float*)d_in[4];
  const float* b2s = (const float*)d_in[5];
  const float* W1e = (const float*)d_in[6];
  const float* b1e = (const float*)d_in[7];
  const float* W2e = (const float*)d_in[8];
  const float* b2e = (const float*)d_in[9];
  const float* Wp1 = (const float*)d_in[10];
  const float* bp1 = (const float*)d_in[11];
  const float* Wp2 = (const float*)d_in[12];
  const float* bp2 = (const float*)d_in[13];
  const float* Wv1 = (const float*)d_in[14];
  const float* bv1 = (const float*)d_in[15];
  const float* Wv2 = (const float*)d_in[16];
  const float* bv2 = (const float*)d_in[17];
  const float* Wm1 = (const float*)d_in[18];
  const float* bm1 = (const float*)d_in[19];
  const float* Wm2 = (const float*)d_in[20];
  const float* bm2 = (const float*)d_in[21];
  float* out = (float*)d_out;

  // workspace layout (bytes)
  char* W = (char*)d_ws;
  unsigned short* Ahi  = (unsigned short*)(W);                      // 16 MB
  unsigned short* Alo  = (unsigned short*)(W + (16u << 20));        // 16 MB
  unsigned short* B1hi = (unsigned short*)(W + (32u << 20));        // 1 MB
  unsigned short* B1lo = (unsigned short*)(W + (33u << 20));        // 1 MB
  unsigned short* B2hi = (unsigned short*)(W + (34u << 20));        // 0.5 MB
  float*          C1   = (float*)(W + (35u << 20));                 // 16 MB
  unsigned short* C2   = (unsigned short*)(W + (51u << 20));        // 4 MB
  float*          scores = (float*)(W + (55u << 20));               // 1 MB
  char* S = W + (56u << 20);
  float* q1b      = (float*)(S);               // 64 KB
  float* q2b      = (float*)(S + 65536);       // 32 KB
  float* s2       = (float*)(S + 98304);       // 125 KB
  float* w2       = (float*)(S + 226304);      // 125 KB
  int*   topk     = (int*)  (S + 354304);      // 125 KB
  float* wact_acc = (float*)(S + 482304);      // 16 KB
  float* wres_acc = (float*)(S + 498688);      // 128 B
  float* aw       = (float*)(S + 498816);      // 128 B
  float* hp_acc   = (float*)(S + 498944);      // 96 KB
  float* v1h      = (float*)(S + 597248);      // 64 KB
  float* m1h      = (float*)(S + 662784);      // 64 KB

  k_split_mem<<<8192, 256, 0, stream>>>(memory, Ahi, Alo);
  k_split_w<<<dim3(24, 32), dim3(32, 8), 0, stream>>>(W1s, W1e, B1hi, B1lo, B2hi);
  k_init5<<<337, 256, 0, stream>>>(b1s, b1e, bv1, bm1, bp1, q1b, q2b, v1h, m1h,
                                   hp_acc, wact_acc, wres_acc);
  k_batch1<<<dim3(28, 8), 256, 0, stream>>>(features, W1s, W1e, Wv1, Wm1,
                                            q1b, q2b, v1h, m1h);
  k_gemm1<<<dim3(64, 8), 256, 0, stream>>>(Ahi, Alo, B1hi, B1lo, C1);
  k_gemm2<<<dim3(64, 4), 256, 0, stream>>>(Ahi, B2hi, C2);
  k_scores2<<<1024, 256, 0, stream>>>(C1, q1b, W2s, b2s, scores);
  k_topk<<<32, 1024, 0, stream>>>(scores, topk);
  k_s2<<<8000, 256, 0, stream>>>(C2, q2b, topk, W2e, b2e, s2);
  k_soft<<<32, 256, 0, stream>>>(s2, w2);
  k_weighted<<<256, 256, 0, stream>>>(topk, w2, memory, wact_acc, wres_acc);
  k_value_epi<<<dim3(32, 2), 512, 0, stream>>>(v1h, m1h, Wv2, bv2, Wm2, bm2, aw, out);
  k_hp2<<<dim3(12, 9), 256, 0, stream>>>(features, wact_acc, Wp1, hp_acc);
  k_gelu_ip<<<96, 256, 0, stream>>>(hp_acc, B_ * PH_);
  k_logits_init<<<584, 256, 0, stream>>>(bp2, out);
  k_logits2<<<dim3(73, 3), 256, 0, stream>>>(hp_acc, Wp2, out);
  k_finalize<<<17, 256, 0, stream>>>(wact_acc, wres_acc, aw, out);
}

// Round 4
// 370.202 us; speedup vs baseline: 2.0328x; 1.0532x over previous
//
#include <hip/hip_runtime.h>
#include <math.h>

#define B_ 32
#define K_ 8192
#define TOPK_ 1000
#define F_ 1024
#define E_ 1153
#define H1_ 512
#define H2_ 256
#define PH_ 768
#define ADIM_ 4672

// output layout (floats): logits | board_vals | value | wact | wres
#define OFF_BV   149504
#define OFF_VAL  149536
#define OFF_WACT 149568
#define OFF_WRES 153664

typedef __attribute__((ext_vector_type(8))) short v8s;
typedef __attribute__((ext_vector_type(4))) float v4f;
typedef __attribute__((ext_vector_type(4))) unsigned short v4u16;

#define GLD16(gp, lp) __builtin_amdgcn_global_load_lds( \
    (const __attribute__((address_space(1))) void*)(gp), \
    (__attribute__((address_space(3))) void*)(lp), 16, 0, 0)

__device__ __forceinline__ float gelu_f(float x) {
  return 0.5f * x * (1.0f + erff(x * 0.70710678118654752440f));
}
__device__ __forceinline__ unsigned short f2bf(float x) {
  union { float f; unsigned u; } v; v.f = x;
  unsigned r = v.u + 0x7fffu + ((v.u >> 16) & 1u);
  return (unsigned short)(r >> 16);
}
__device__ __forceinline__ float bf2f(unsigned short h) {
  union { unsigned u; float f; } v; v.u = ((unsigned)h) << 16; return v.f;
}

// ---------- split/convert memory[:, :F] -> Ahi, Alo (bf16, [8192][1024]) ----------
__global__ __launch_bounds__(256) void k_split_mem(
    const float* __restrict__ memory, unsigned short* __restrict__ Ahi,
    unsigned short* __restrict__ Alo) {
  const int r = blockIdx.x;
  const int tid = threadIdx.x;
  const float* src = memory + (size_t)r * E_;
#pragma unroll
  for (int i = 0; i < 4; ++i) {
    const float x = src[tid + 256 * i];
    const unsigned short h = f2bf(x);
    Ahi[(size_t)r * 1024 + tid + 256 * i] = h;
    Alo[(size_t)r * 1024 + tid + 256 * i] = f2bf(x - bf2f(h));
  }
}

// ---------- transpose+split weights: B1hi/lo [512][1024], B2hi [256][1024] ----------
__global__ __launch_bounds__(256) void k_split_w(
    const float* __restrict__ W1s, const float* __restrict__ W1e,
    unsigned short* __restrict__ B1hi, unsigned short* __restrict__ B1lo,
    unsigned short* __restrict__ B2hi) {
  __shared__ float t[32][33];
  const int x = threadIdx.x, y = threadIdx.y;  // 32 x 8
  const int j0 = blockIdx.x * 32, k0 = blockIdx.y * 32;
#pragma unroll
  for (int i = 0; i < 4; ++i) {
    const int k = k0 + y + 8 * i;
    const int j = j0 + x;
    t[y + 8 * i][x] = (j < 512) ? W1s[(size_t)(F_ + k) * H1_ + j]
                                : W1e[(size_t)(F_ + k) * H2_ + (j - 512)];
  }
  __syncthreads();
#pragma unroll
  for (int i = 0; i < 4; ++i) {
    const int j = j0 + y + 8 * i;
    const int k = k0 + x;
    const float v = t[x][y + 8 * i];
    const unsigned short h = f2bf(v);
    if (j < 512) {
      B1hi[(size_t)j * 1024 + k] = h;
      B1lo[(size_t)j * 1024 + k] = f2bf(v - bf2f(h));
    } else {
      B2hi[(size_t)(j - 512) * 1024 + k] = h;
    }
  }
}

// ---------- bias init for atomic-accumulated buffers (+ zero wact/wres) ----------
__global__ __launch_bounds__(256) void k_init5(
    const float* __restrict__ b1s, const float* __restrict__ b1e,
    const float* __restrict__ bv1, const float* __restrict__ bm1,
    const float* __restrict__ bp1, float* __restrict__ q1b,
    float* __restrict__ q2b, float* __restrict__ v1h, float* __restrict__ m1h,
    float* __restrict__ hp_acc, float* __restrict__ wact,
    float* __restrict__ wres) {
  const int idx = blockIdx.x * 256 + threadIdx.x;
  if (idx < 32 * 2560) {
    const int b = idx / 2560, j = idx - b * 2560;
    if (j < 512) q1b[b * 512 + j] = b1s[j];
    else if (j < 768) q2b[b * 256 + (j - 512)] = b1e[j - 512];
    else if (j < 1280) v1h[b * 512 + (j - 768)] = bv1[j - 768];
    else if (j < 1792) m1h[b * 512 + (j - 1280)] = bm1[j - 1280];
    else hp_acc[b * 768 + (j - 1792)] = bp1[j - 1792];
  } else {
    const int k = idx - 32 * 2560;
    if (k < 4096) wact[k] = 0.f;
    else if (k < 4128) wres[k - 4096] = 0.f;
  }
}

// ---------- skinny-M fp32 GEMM core: C[32][N] += A[32][64-slice] @ W ----------
// 128 threads, 2 cols/thread (256 cols/block), all 32 rows as accumulators.
// A-slice staged transposed in LDS stride 36 (16B-aligned f4 reads, spread banks).
__device__ __forceinline__ void skinny32_body(
    const float* __restrict__ A, int lda, int kbase,
    const float* __restrict__ Wp, int ldw, int n0, int N,
    float* __restrict__ C, int ldc, float* __restrict__ lA) {
  const int tid = threadIdx.x;
#pragma unroll
  for (int j = 0; j < 16; ++j) {
    const int idx = j * 128 + tid;
    const int r = idx >> 6, k = idx & 63;
    lA[k * 36 + r] = A[(size_t)r * lda + kbase + k];
  }
  __syncthreads();
  const int c0 = n0 + tid * 2;
  if (c0 >= N) return;
  float acc[32][2];
#pragma unroll
  for (int r = 0; r < 32; ++r) { acc[r][0] = 0.f; acc[r][1] = 0.f; }
  const float* wp = Wp + (size_t)kbase * ldw + c0;
#pragma unroll 2
  for (int k = 0; k < 64; ++k) {
    const float2 w = *(const float2*)&wp[(size_t)k * ldw];
#pragma unroll
    for (int rq = 0; rq < 8; ++rq) {
      const float4 a = *(const float4*)&lA[k * 36 + rq * 4];
      acc[rq * 4 + 0][0] = fmaf(a.x, w.x, acc[rq * 4 + 0][0]);
      acc[rq * 4 + 0][1] = fmaf(a.x, w.y, acc[rq * 4 + 0][1]);
      acc[rq * 4 + 1][0] = fmaf(a.y, w.x, acc[rq * 4 + 1][0]);
      acc[rq * 4 + 1][1] = fmaf(a.y, w.y, acc[rq * 4 + 1][1]);
      acc[rq * 4 + 2][0] = fmaf(a.z, w.x, acc[rq * 4 + 2][0]);
      acc[rq * 4 + 2][1] = fmaf(a.z, w.y, acc[rq * 4 + 2][1]);
      acc[rq * 4 + 3][0] = fmaf(a.w, w.x, acc[rq * 4 + 3][0]);
      acc[rq * 4 + 3][1] = fmaf(a.w, w.y, acc[rq * 4 + 3][1]);
    }
  }
#pragma unroll
  for (int r = 0; r < 32; ++r) {
    atomicAdd(&C[(size_t)r * ldc + c0], acc[r][0]);
    atomicAdd(&C[(size_t)r * ldc + c0 + 1], acc[r][1]);
  }
}

// grid (7, 16): x -> {q1 lo, q1 hi, q2, v1 lo, v1 hi, m1 lo, m1 hi}
__global__ __launch_bounds__(128) void k_skinny_batch1(
    const float* __restrict__ features, const float* __restrict__ W1s,
    const float* __restrict__ W1e, const float* __restrict__ Wv1,
    const float* __restrict__ Wm1, float* __restrict__ q1b,
    float* __restrict__ q2b, float* __restrict__ v1h,
    float* __restrict__ m1h) {
  __shared__ float lA[64 * 36];
  const int t = blockIdx.x;
  const float* Wp; float* Cp; int ldw, n0;
  switch (t) {
    case 0: Wp = W1s; Cp = q1b; ldw = 512; n0 = 0;   break;
    case 1: Wp = W1s; Cp = q1b; ldw = 512; n0 = 256; break;
    case 2: Wp = W1e; Cp = q2b; ldw = 256; n0 = 0;   break;
    case 3: Wp = Wv1; Cp = v1h; ldw = 512; n0 = 0;   break;
    case 4: Wp = Wv1; Cp = v1h; ldw = 512; n0 = 256; break;
    case 5: Wp = Wm1; Cp = m1h; ldw = 512; n0 = 0;   break;
    default: Wp = Wm1; Cp = m1h; ldw = 512; n0 = 256; break;
  }
  skinny32_body(features, F_, blockIdx.y * 64, Wp, ldw, n0, ldw, Cp, ldw, lA);
}

// grid (3, 16)
__global__ __launch_bounds__(128) void k_skinny_hp_feat(
    const float* __restrict__ features, const float* __restrict__ Wp1,
    float* __restrict__ hp_acc) {
  __shared__ float lA[64 * 36];
  skinny32_body(features, F_, blockIdx.y * 64, Wp1, PH_, blockIdx.x * 256, PH_,
                hp_acc, PH_, lA);
}

// grid (3, 2)
__global__ __launch_bounds__(128) void k_skinny_hp_wact(
    const float* __restrict__ wact, const float* __restrict__ Wp1,
    float* __restrict__ hp_acc) {
  __shared__ float lA[64 * 36];
  skinny32_body(wact, 128, blockIdx.y * 64, Wp1 + (size_t)F_ * PH_, PH_,
                blockIdx.x * 256, PH_, hp_acc, PH_, lA);
}

// grid (19, 12)
__global__ __launch_bounds__(128) void k_skinny_logits(
    const float* __restrict__ hp, const float* __restrict__ Wp2,
    float* __restrict__ out) {
  __shared__ float lA[64 * 36];
  skinny32_body(hp, PH_, blockIdx.y * 64, Wp2, ADIM_, blockIdx.x * 256, ADIM_,
                out, ADIM_, lA);
}

// ---------- staging helper: 16B chunks into pad-80 LDS rows (5 chunks/row) ----------
__device__ __forceinline__ void stage80(
    const unsigned short* __restrict__ src, int row_base, int k0,
    char* lds, int lds_off, int nchunks, int tid) {
  for (int i = 0; i * 256 < nchunks; ++i) {
    const int c = i * 256 + tid;
    if (c < nchunks) {
      const int row = c / 5, sub = c % 5;
      const int s = (sub == 4) ? 0 : sub;  // pad chunk loads row start (unused)
      const unsigned short* g = src + (size_t)(row_base + row) * 1024 + k0 + s * 8;
      GLD16(g, lds + lds_off + i * 4096 + ((tid >> 6) * 1024));
    }
  }
}

// ---------- GEMM1 (selection): C1 fp32 [8192][512] = A(hi+lo) @ B1(hi+lo)^T, 3-term ----------
__global__ __launch_bounds__(256) void k_gemm1(
    const unsigned short* __restrict__ Ahi, const unsigned short* __restrict__ Alo,
    const unsigned short* __restrict__ B1hi, const unsigned short* __restrict__ B1lo,
    float* __restrict__ C1) {
  __shared__ unsigned short lds[15360];  // 30720B: Ahi@0 Alo@10240 Bhi@20480 Blo@25600
  char* L = (char*)lds;
  const int tid = threadIdx.x;
  const int lane = tid & 63, w = tid >> 6;
  const int m0 = blockIdx.x * 128;
  const int n0 = blockIdx.y * 64;
  const int wr = w >> 1, wc = w & 1;
  v4f acc[4][2];
#pragma unroll
  for (int mi = 0; mi < 4; ++mi)
#pragma unroll
    for (int ni = 0; ni < 2; ++ni) acc[mi][ni] = (v4f)(0.f);

  for (int k0 = 0; k0 < 1024; k0 += 32) {
    __syncthreads();
    stage80(Ahi, m0, k0, L, 0, 640, tid);
    stage80(Alo, m0, k0, L, 10240, 640, tid);
    stage80(B1hi, n0, k0, L, 20480, 320, tid);
    stage80(B1lo, n0, k0, L, 25600, 320, tid);
    asm volatile("s_waitcnt vmcnt(0)" ::: "memory");
    __syncthreads();
    v8s ah[4], al[4], bh[2], bl[2];
    const int fo = (lane >> 4) * 16;
#pragma unroll
    for (int mi = 0; mi < 4; ++mi) {
      const int ro = (wr * 64 + mi * 16 + (lane & 15)) * 80 + fo;
      ah[mi] = *(const v8s*)(L + ro);
      al[mi] = *(const v8s*)(L + 10240 + ro);
    }
#pragma unroll
    for (int ni = 0; ni < 2; ++ni) {
      const int ro = (wc * 32 + ni * 16 + (lane & 15)) * 80 + fo;
      bh[ni] = *(const v8s*)(L + 20480 + ro);
      bl[ni] = *(const v8s*)(L + 25600 + ro);
    }
#pragma unroll
    for (int mi = 0; mi < 4; ++mi)
#pragma unroll
      for (int ni = 0; ni < 2; ++ni) {
        acc[mi][ni] = __builtin_amdgcn_mfma_f32_16x16x32_bf16(ah[mi], bh[ni], acc[mi][ni], 0, 0, 0);
        acc[mi][ni] = __builtin_amdgcn_mfma_f32_16x16x32_bf16(ah[mi], bl[ni], acc[mi][ni], 0, 0, 0);
        acc[mi][ni] = __builtin_amdgcn_mfma_f32_16x16x32_bf16(al[mi], bh[ni], acc[mi][ni], 0, 0, 0);
      }
  }
#pragma unroll
  for (int mi = 0; mi < 4; ++mi)
#pragma unroll
    for (int ni = 0; ni < 2; ++ni)
#pragma unroll
      for (int j = 0; j < 4; ++j) {
        const int mrow = m0 + wr * 64 + mi * 16 + (lane >> 4) * 4 + j;
        const int ncol = n0 + wc * 32 + ni * 16 + (lane & 15);
        C1[(size_t)mrow * 512 + ncol] = acc[mi][ni][j];
      }
}

// ---------- GEMM2 (evidence): C2 bf16 [8192][256] = Ahi @ B2hi^T, 1-term ----------
__global__ __launch_bounds__(256) void k_gemm2(
    const unsigned short* __restrict__ Ahi, const unsigned short* __restrict__ B2hi,
    unsigned short* __restrict__ C2) {
  __shared__ unsigned short lds[7680];
  char* L = (char*)lds;
  const int tid = threadIdx.x;
  const int lane = tid & 63, w = tid >> 6;
  const int m0 = blockIdx.x * 128;
  const int n0 = blockIdx.y * 64;
  const int wr = w >> 1, wc = w & 1;
  v4f acc[4][2];
#pragma unroll
  for (int mi = 0; mi < 4; ++mi)
#pragma unroll
    for (int ni = 0; ni < 2; ++ni) acc[mi][ni] = (v4f)(0.f);

  for (int k0 = 0; k0 < 1024; k0 += 32) {
    __syncthreads();
    stage80(Ahi, m0, k0, L, 0, 640, tid);
    stage80(B2hi, n0, k0, L, 10240, 320, tid);
    asm volatile("s_waitcnt vmcnt(0)" ::: "memory");
    __syncthreads();
    v8s ah[4], bh[2];
    const int fo = (lane >> 4) * 16;
#pragma unroll
    for (int mi = 0; mi < 4; ++mi)
      ah[mi] = *(const v8s*)(L + (wr * 64 + mi * 16 + (lane & 15)) * 80 + fo);
#pragma unroll
    for (int ni = 0; ni < 2; ++ni)
      bh[ni] = *(const v8s*)(L + 10240 + (wc * 32 + ni * 16 + (lane & 15)) * 80 + fo);
#pragma unroll
    for (int mi = 0; mi < 4; ++mi)
#pragma unroll
      for (int ni = 0; ni < 2; ++ni)
        acc[mi][ni] = __builtin_amdgcn_mfma_f32_16x16x32_bf16(ah[mi], bh[ni], acc[mi][ni], 0, 0, 0);
  }
#pragma unroll
  for (int mi = 0; mi < 4; ++mi)
#pragma unroll
    for (int ni = 0; ni < 2; ++ni)
#pragma unroll
      for (int j = 0; j < 4; ++j) {
        const int mrow = m0 + wr * 64 + mi * 16 + (lane >> 4) * 4 + j;
        const int ncol = n0 + wc * 32 + ni * 16 + (lane & 15);
        C2[(size_t)mrow * 256 + ncol] = f2bf(acc[mi][ni][j]);
      }
}

// ---------- scores v2: 1024 blocks, 8 k-rows staged in LDS, 1 (b,k) per thread ----------
__global__ __launch_bounds__(256) void k_scores2(
    const float* __restrict__ C1, const float* __restrict__ q1b,
    const float* __restrict__ W2s, const float* __restrict__ b2s,
    float* __restrict__ scores) {
  __shared__ float4 c4[8 * 129];  // row pad 129 f4: 8 rows cover all 32 banks
  __shared__ float4 w4[128];
  const int tid = threadIdx.x;
  const int kbase = blockIdx.x * 8;
#pragma unroll
  for (int p = 0; p < 4; ++p) {
    const int idx = p * 256 + tid;
    const int row = idx >> 7, c = idx & 127;
    c4[row * 129 + c] = *(const float4*)&C1[(size_t)(kbase + row) * 512 + c * 4];
  }
  if (tid < 128) w4[tid] = *(const float4*)&W2s[tid * 4];
  __syncthreads();
  const int b = tid >> 3, ks = tid & 7;
  const float4* qrow = (const float4*)&q1b[b * 512];
  float acc = 0.f;
  for (int i = 0; i < 128; ++i) {
    const float4 c = c4[ks * 129 + i];
    const float4 q = qrow[i];
    const float4 w = w4[i];
    acc += fmaxf(q.x + c.x, 0.f) * w.x + fmaxf(q.y + c.y, 0.f) * w.y +
           fmaxf(q.z + c.z, 0.f) * w.z + fmaxf(q.w + c.w, 0.f) * w.w;
  }
  scores[(size_t)b * K_ + kbase + ks] = acc + b2s[0];
}

// ---------- exact top-1000 (set semantics; ties by lowest index) ----------
__global__ __launch_bounds__(1024) void k_topk(
    const float* __restrict__ scores, int* __restrict__ topk_idx) {
  __shared__ unsigned key[K_];
  __shared__ unsigned whist[16][256];
  __shared__ unsigned sfx[256];
  __shared__ int eqlist[1024];
  __shared__ unsigned ctl[4];
  const int tid = threadIdx.x;
  const int wid = tid >> 6;
  const int b = blockIdx.x;
  const float* row = scores + (size_t)b * K_;
  for (int i = tid; i < K_; i += 1024) {
    const unsigned u = __float_as_uint(row[i]);
    key[i] = (u & 0x80000000u) ? ~u : (u | 0x80000000u);
  }
  unsigned prefix = 0;
  int r = TOPK_;
  for (int p = 0; p < 4; ++p) {
    const int shift = 24 - 8 * p;
    for (int i = tid; i < 16 * 256; i += 1024) ((unsigned*)whist)[i] = 0;
    __syncthreads();
    const unsigned pmask = (p == 0) ? 0u : (0xFFFFFFFFu << (shift + 8));
    for (int i = tid; i < K_; i += 1024) {
      const unsigned k = key[i];
      if ((k & pmask) == prefix) atomicAdd(&whist[wid][(k >> shift) & 255u], 1u);
    }
    __syncthreads();
    if (tid < 256) {
      unsigned s = 0;
#pragma unroll
      for (int ww = 0; ww < 16; ++ww) s += whist[ww][tid];
      sfx[tid] = s;
    }
    __syncthreads();
    for (int off = 1; off < 256; off <<= 1) {
      unsigned v = 0;
      if (tid < 256) { v = sfx[tid]; if (tid + off < 256) v += sfx[tid + off]; }
      __syncthreads();
      if (tid < 256) sfx[tid] = v;
      __syncthreads();
    }
    if (tid < 256) {
      const int Sge = (int)sfx[tid];
      const int Sgt = (tid < 255) ? (int)sfx[tid + 1] : 0;
      if (Sgt < r && r <= Sge) { ctl[0] = (unsigned)tid; ctl[1] = (unsigned)(r - Sgt); }
    }
    __syncthreads();
    prefix |= ctl[0] << shift;
    r = (int)ctl[1];
    __syncthreads();
  }
  const unsigned T = prefix;
  const int take_eq = r;
  if (tid == 0) { ctl[2] = 0; ctl[3] = 0; }
  __syncthreads();
  int* outp = topk_idx + b * TOPK_;
  for (int i = tid; i < K_; i += 1024) {
    const unsigned k = key[i];
    if (k > T) outp[atomicAdd(&ctl[2], 1u)] = i;
    else if (k == T) { const unsigned e = atomicAdd(&ctl[3], 1u); if (e < 1024) eqlist[e] = i; }
  }
  __syncthreads();
  const int m = (ctl[3] < 1024u) ? (int)ctl[3] : 1024;
  const int ngt = TOPK_ - take_eq;
  for (int sel = 0; sel < take_eq; ++sel) {
    key[tid] = (tid < m) ? (unsigned)eqlist[tid] : 0xFFFFFFFFu;
    __syncthreads();
    for (int s = 512; s > 0; s >>= 1) {
      if (tid < s) key[tid] = min(key[tid], key[tid + s]);
      __syncthreads();
    }
    const unsigned mn = key[0];
    if (tid < m && (unsigned)eqlist[tid] == mn) eqlist[tid] = 0x7FFFFFFF;
    if (tid == 0) outp[ngt + sel] = (int)mn;
    __syncthreads();
  }
}

// ---------- s2[e] = b2e + sum_j gelu(q2b[b][j] + C2[idx][j]) * W2e[j] ----------
__global__ __launch_bounds__(256) void k_s2(
    const unsigned short* __restrict__ C2, const float* __restrict__ q2b,
    const int* __restrict__ topk_idx, const float* __restrict__ W2e,
    const float* __restrict__ b2e, float* __restrict__ s2) {
  const int tid = threadIdx.x;
  const int ln = tid & 63;
  const int e = blockIdx.x * 4 + (tid >> 6);
  const int b = e / TOPK_;
  const int idx = topk_idx[e];
  const v4u16 kv = *(const v4u16*)(C2 + (size_t)idx * H2_ + ln * 4);
  const float4 qv = *(const float4*)(q2b + b * H2_ + ln * 4);
  float s = gelu_f(qv.x + bf2f(kv[0])) * W2e[ln * 4 + 0]
          + gelu_f(qv.y + bf2f(kv[1])) * W2e[ln * 4 + 1]
          + gelu_f(qv.z + bf2f(kv[2])) * W2e[ln * 4 + 2]
          + gelu_f(qv.w + bf2f(kv[3])) * W2e[ln * 4 + 3];
#pragma unroll
  for (int off = 32; off > 0; off >>= 1) s += __shfl_down(s, off);
  if (ln == 0) s2[e] = s + b2e[0];
}

// ---------- w2 = softmax(s2) per row ----------
__global__ __launch_bounds__(256) void k_soft(
    const float* __restrict__ s2, float* __restrict__ w2) {
  __shared__ float red[256];
  const int tid = threadIdx.x, b = blockIdx.x;
  float m = -3.4e38f;
  for (int t = tid; t < TOPK_; t += 256) m = fmaxf(m, s2[b * TOPK_ + t]);
  red[tid] = m;
  __syncthreads();
  for (int s = 128; s > 0; s >>= 1) {
    if (tid < s) red[tid] = fmaxf(red[tid], red[tid + s]);
    __syncthreads();
  }
  m = red[0];
  __syncthreads();
  float ps = 0.f;
  for (int t = tid; t < TOPK_; t += 256) {
    const float ev = expf(s2[b * TOPK_ + t] - m);
    w2[b * TOPK_ + t] = ev;
    ps += ev;
  }
  red[tid] = ps;
  __syncthreads();
  for (int s = 128; s > 0; s >>= 1) {
    if (tid < s) red[tid] += red[tid + s];
    __syncthreads();
  }
  const float inv = 1.f / red[0];
  for (int t = tid; t < TOPK_; t += 256) w2[b * TOPK_ + t] *= inv;
}

// ---------- weighted actions/results (gather-reduce, 8 chunks per b) ----------
__global__ __launch_bounds__(256) void k_weighted(
    const int* __restrict__ topk_idx, const float* __restrict__ w2,
    const float* __restrict__ memory, float* __restrict__ wact_acc,
    float* __restrict__ wres_acc) {
  const int blk = blockIdx.x;
  const int b = blk >> 3, c = blk & 7;
  const int tid = threadIdx.x;
  const int g = tid >> 7, a = tid & 127;
  float acc = 0.f, accr = 0.f;
  for (int t = c * 125 + g; t < (c + 1) * 125; t += 2) {
    const int idx = topk_idx[b * TOPK_ + t];
    const float wv = w2[b * TOPK_ + t];
    acc += truncf(memory[(size_t)idx * E_ + F_ + a]) * wv;
    if (a == 0) accr += wv * memory[(size_t)idx * E_ + (E_ - 1)];
  }
  atomicAdd(&wact_acc[b * 128 + a], acc);
  if (a == 0) atomicAdd(&wres_acc[b], accr);
}

// ---------- value head epilogue: tanh / sigmoid ----------
__global__ __launch_bounds__(512) void k_value_epi(
    const float* __restrict__ v1h, const float* __restrict__ m1h,
    const float* __restrict__ Wv2, const float* __restrict__ bv2,
    const float* __restrict__ Wm2, const float* __restrict__ bm2,
    float* __restrict__ aw, float* __restrict__ out) {
  __shared__ float red[512];
  const int tid = threadIdx.x, b = blockIdx.x, net = blockIdx.y;
  const float* h = net ? m1h : v1h;
  const float* W2 = net ? Wm2 : Wv2;
  red[tid] = gelu_f(h[b * 512 + tid]) * W2[tid];
  __syncthreads();
  for (int s = 256; s > 0; s >>= 1) {
    if (tid < s) red[tid] += red[tid + s];
    __syncthreads();
  }
  if (tid == 0) {
    const float v = red[0] + (net ? bm2[0] : bv2[0]);
    if (net == 0) out[OFF_BV + b] = tanhf(v);
    else aw[b] = 1.f / (1.f + expf(-v));
  }
}

// ---------- in-place gelu ----------
__global__ void k_gelu_ip(float* __restrict__ p, int n) {
  const int i = blockIdx.x * 256 + threadIdx.x;
  if (i < n) p[i] = gelu_f(p[i]);
}

// ---------- logits bias init ----------
__global__ __launch_bounds__(256) void k_logits_init(
    const float* __restrict__ bp2, float* __restrict__ out) {
  const int i = blockIdx.x * 256 + threadIdx.x;
  if (i < B_ * ADIM_) out[i] = bp2[i % ADIM_];
}

// ---------- finalize ----------
__global__ __launch_bounds__(256) void k_finalize(
    const float* __restrict__ wact, const float* __restrict__ wres,
    const float* __restrict__ aw, float* __restrict__ out) {
  const int i = blockIdx.x * 256 + threadIdx.x;
  if (i < 4096) {
    out[OFF_WACT + i] = wact[i];
  } else if (i < 4128) {
    const int b = i - 4096;
    out[OFF_WRES + b] = wres[b];
    const float A = aw[b];
    out[OFF_VAL + b] = A * wres[b] + (1.f - A) * out[OFF_BV + b];
  }
}

extern "C" void kernel_launch(void* const* d_in, const int* in_sizes, int n_in,
                              void* d_out, int out_size, void* d_ws,
                              size_t ws_size, hipStream_t stream) {
  (void)in_sizes; (void)n_in; (void)out_size; (void)ws_size;
  const float* features = (const float*)d_in[0];
  const float* memory   = (const float*)d_in[1];
  const float* W1s = (const float*)d_in[2];
  const float* b1s = (const float*)d_in[3];
  const float* W2s = (const float*)d_in[4];
  const float* b2s = (const float*)d_in[5];
  const float* W1e = (const float*)d_in[6];
  const float* b1e = (const float*)d_in[7];
  const float* W2e = (const float*)d_in[8];
  const float* b2e = (const float*)d_in[9];
  const float* Wp1 = (const float*)d_in[10];
  const float* bp1 = (const float*)d_in[11];
  const float* Wp2 = (const float*)d_in[12];
  const float* bp2 = (const float*)d_in[13];
  const float* Wv1 = (const float*)d_in[14];
  const float* bv1 = (const float*)d_in[15];
  const float* Wv2 = (const float*)d_in[16];
  const float* bv2 = (const float*)d_in[17];
  const float* Wm1 = (const float*)d_in[18];
  const float* bm1 = (const float*)d_in[19];
  const float* Wm2 = (const float*)d_in[20];
  const float* bm2 = (const float*)d_in[21];
  float* out = (float*)d_out;

  // workspace layout (bytes)
  char* W = (char*)d_ws;
  unsigned short* Ahi  = (unsigned short*)(W);                      // 16 MB
  unsigned short* Alo  = (unsigned short*)(W + (16u << 20));        // 16 MB
  unsigned short* B1hi = (unsigned short*)(W + (32u << 20));        // 1 MB
  unsigned short* B1lo = (unsigned short*)(W + (33u << 20));        // 1 MB
  unsigned short* B2hi = (unsigned short*)(W + (34u << 20));        // 0.5 MB
  float*          C1   = (float*)(W + (35u << 20));                 // 16 MB
  unsigned short* C2   = (unsigned short*)(W + (51u << 20));        // 4 MB
  float*          scores = (float*)(W + (55u << 20));               // 1 MB
  char* S = W + (56u << 20);
  float* q1b      = (float*)(S);               // 64 KB
  float* q2b      = (float*)(S + 65536);       // 32 KB
  float* s2       = (float*)(S + 98304);       // 125 KB
  float* w2       = (float*)(S + 226304);      // 125 KB
  int*   topk     = (int*)  (S + 354304);      // 125 KB
  float* wact_acc = (float*)(S + 482304);      // 16 KB
  float* wres_acc = (float*)(S + 498688);      // 128 B
  float* aw       = (float*)(S + 498816);      // 128 B
  float* hp_acc   = (float*)(S + 498944);      // 96 KB
  float* v1h      = (float*)(S + 597248);      // 64 KB
  float* m1h      = (float*)(S + 662784);      // 64 KB

  k_split_mem<<<8192, 256, 0, stream>>>(memory, Ahi, Alo);
  k_split_w<<<dim3(24, 32), dim3(32, 8), 0, stream>>>(W1s, W1e, B1hi, B1lo, B2hi);
  k_init5<<<337, 256, 0, stream>>>(b1s, b1e, bv1, bm1, bp1, q1b, q2b, v1h, m1h,
                                   hp_acc, wact_acc, wres_acc);
  k_skinny_batch1<<<dim3(7, 16), 128, 0, stream>>>(features, W1s, W1e, Wv1, Wm1,
                                                   q1b, q2b, v1h, m1h);
  k_skinny_hp_feat<<<dim3(3, 16), 128, 0, stream>>>(features, Wp1, hp_acc);
  k_gemm1<<<dim3(64, 8), 256, 0, stream>>>(Ahi, Alo, B1hi, B1lo, C1);
  k_gemm2<<<dim3(64, 4), 256, 0, stream>>>(Ahi, B2hi, C2);
  k_scores2<<<1024, 256, 0, stream>>>(C1, q1b, W2s, b2s, scores);
  k_topk<<<32, 1024, 0, stream>>>(scores, topk);
  k_s2<<<8000, 256, 0, stream>>>(C2, q2b, topk, W2e, b2e, s2);
  k_soft<<<32, 256, 0, stream>>>(s2, w2);
  k_weighted<<<256, 256, 0, stream>>>(topk, w2, memory, wact_acc, wres_acc);
  k_skinny_hp_wact<<<dim3(3, 2), 128, 0, stream>>>(wact_acc, Wp1, hp_acc);
  k_gelu_ip<<<96, 256, 0, stream>>>(hp_acc, B_ * PH_);
  k_value_epi<<<dim3(32, 2), 512, 0, stream>>>(v1h, m1h, Wv2, bv2, Wm2, bm2, aw, out);
  k_logits_init<<<584, 256, 0, stream>>>(bp2, out);
  k_skinny_logits<<<dim3(19, 12), 128, 0, stream>>>(hp_acc, Wp2, out);
  k_finalize<<<17, 256, 0, stream>>>(wact_acc, wres_acc, aw, out);
}

// Round 5
// 344.729 us; speedup vs baseline: 2.1830x; 1.0739x over previous
//
#include <hip/hip_runtime.h>
#include <math.h>

#define B_ 32
#define K_ 8192
#define TOPK_ 1000
#define F_ 1024
#define E_ 1153
#define H1_ 512
#define H2_ 256
#define PH_ 768
#define ADIM_ 4672

// output layout (floats): logits | board_vals | value | wact | wres
#define OFF_BV   149504
#define OFF_VAL  149536
#define OFF_WACT 149568
#define OFF_WRES 153664

typedef __attribute__((ext_vector_type(8))) short v8s;
typedef __attribute__((ext_vector_type(4))) float v4f;
typedef __attribute__((ext_vector_type(4))) unsigned short v4u16;

#define GLD16(gp, lp) __builtin_amdgcn_global_load_lds( \
    (const __attribute__((address_space(1))) void*)(gp), \
    (__attribute__((address_space(3))) void*)(lp), 16, 0, 0)

__device__ __forceinline__ float gelu_f(float x) {
  return 0.5f * x * (1.0f + erff(x * 0.70710678118654752440f));
}
__device__ __forceinline__ unsigned short f2bf(float x) {
  union { float f; unsigned u; } v; v.f = x;
  unsigned r = v.u + 0x7fffu + ((v.u >> 16) & 1u);
  return (unsigned short)(r >> 16);
}
__device__ __forceinline__ float bf2f(unsigned short h) {
  union { unsigned u; float f; } v; v.u = ((unsigned)h) << 16; return v.f;
}

// ---------- convert memory[:, :F] -> Ahi bf16 [8192][1024] (A single-plane) ----------
__global__ __launch_bounds__(256) void k_split_mem(
    const float* __restrict__ memory, unsigned short* __restrict__ Ahi) {
  const int r = blockIdx.x;
  const int t = threadIdx.x;
  const float* src = memory + (size_t)r * E_ + 4 * t;
  unsigned* dst = (unsigned*)(Ahi + (size_t)r * 1024);
  const float x0 = src[0], x1 = src[1], x2 = src[2], x3 = src[3];
  dst[2 * t]     = (unsigned)f2bf(x0) | ((unsigned)f2bf(x1) << 16);
  dst[2 * t + 1] = (unsigned)f2bf(x2) | ((unsigned)f2bf(x3) << 16);
}

// ---------- transpose+split weights: B1hi/lo [512][1024], B2hi [256][1024] ----------
// B kept as TWO bf16 planes: a*(bhi) + a*(blo) accumulated in fp32 == a * W_fp32.
__global__ __launch_bounds__(256) void k_split_w(
    const float* __restrict__ W1s, const float* __restrict__ W1e,
    unsigned short* __restrict__ B1hi, unsigned short* __restrict__ B1lo,
    unsigned short* __restrict__ B2hi) {
  __shared__ float t[32][33];
  const int x = threadIdx.x, y = threadIdx.y;  // 32 x 8
  const int j0 = blockIdx.x * 32, k0 = blockIdx.y * 32;
#pragma unroll
  for (int i = 0; i < 4; ++i) {
    const int k = k0 + y + 8 * i;
    const int j = j0 + x;
    t[y + 8 * i][x] = (j < 512) ? W1s[(size_t)(F_ + k) * H1_ + j]
                                : W1e[(size_t)(F_ + k) * H2_ + (j - 512)];
  }
  __syncthreads();
#pragma unroll
  for (int i = 0; i < 4; ++i) {
    const int j = j0 + y + 8 * i;
    const int k = k0 + x;
    const float v = t[x][y + 8 * i];
    const unsigned short h = f2bf(v);
    if (j < 512) {
      B1hi[(size_t)j * 1024 + k] = h;
      B1lo[(size_t)j * 1024 + k] = f2bf(v - bf2f(h));
    } else {
      B2hi[(size_t)(j - 512) * 1024 + k] = h;
    }
  }
}

// ---------- merged init: per-b biases, wact/wres zero, out logits bias ----------
__global__ __launch_bounds__(256) void k_init(
    const float* __restrict__ b1s, const float* __restrict__ b1e,
    const float* __restrict__ bv1, const float* __restrict__ bm1,
    const float* __restrict__ bp1, const float* __restrict__ bp2,
    float* __restrict__ q1b, float* __restrict__ q2b, float* __restrict__ v1h,
    float* __restrict__ m1h, float* __restrict__ hp, float* __restrict__ wact,
    float* __restrict__ wres, float* __restrict__ out) {
  const int idx = blockIdx.x * 256 + threadIdx.x;
  if (idx < 32 * 2560) {
    const int b = idx / 2560, j = idx - b * 2560;
    if (j < 512) q1b[b * 512 + j] = b1s[j];
    else if (j < 768) q2b[b * 256 + (j - 512)] = b1e[j - 512];
    else if (j < 1280) v1h[b * 512 + (j - 768)] = bv1[j - 768];
    else if (j < 1792) m1h[b * 512 + (j - 1280)] = bm1[j - 1280];
    else hp[b * 768 + (j - 1792)] = bp1[j - 1792];
  } else if (idx < 32 * 2560 + 4128) {
    const int k = idx - 32 * 2560;
    if (k < 4096) wact[k] = 0.f;
    else wres[k - 4096] = 0.f;
  } else {
    const int k = idx - (32 * 2560 + 4128);
    if (k < B_ * ADIM_) out[k] = bp2[k % ADIM_];
  }
}

// ---------- skinny-M fp32 GEMM core: C[32][N] += A[32][64-slice] @ W ----------
__device__ __forceinline__ void skinny32_body(
    const float* __restrict__ A, int lda, int kbase,
    const float* __restrict__ Wp, int ldw, int n0, int N,
    float* __restrict__ C, int ldc, float* __restrict__ lA) {
  const int tid = threadIdx.x;
#pragma unroll
  for (int j = 0; j < 16; ++j) {
    const int idx = j * 128 + tid;
    const int r = idx >> 6, k = idx & 63;
    lA[k * 36 + r] = A[(size_t)r * lda + kbase + k];
  }
  __syncthreads();
  const int c0 = n0 + tid * 2;
  if (c0 >= N) return;
  float acc[32][2];
#pragma unroll
  for (int r = 0; r < 32; ++r) { acc[r][0] = 0.f; acc[r][1] = 0.f; }
  const float* wp = Wp + (size_t)kbase * ldw + c0;
#pragma unroll 2
  for (int k = 0; k < 64; ++k) {
    const float2 w = *(const float2*)&wp[(size_t)k * ldw];
#pragma unroll
    for (int rq = 0; rq < 8; ++rq) {
      const float4 a = *(const float4*)&lA[k * 36 + rq * 4];
      acc[rq * 4 + 0][0] = fmaf(a.x, w.x, acc[rq * 4 + 0][0]);
      acc[rq * 4 + 0][1] = fmaf(a.x, w.y, acc[rq * 4 + 0][1]);
      acc[rq * 4 + 1][0] = fmaf(a.y, w.x, acc[rq * 4 + 1][0]);
      acc[rq * 4 + 1][1] = fmaf(a.y, w.y, acc[rq * 4 + 1][1]);
      acc[rq * 4 + 2][0] = fmaf(a.z, w.x, acc[rq * 4 + 2][0]);
      acc[rq * 4 + 2][1] = fmaf(a.z, w.y, acc[rq * 4 + 2][1]);
      acc[rq * 4 + 3][0] = fmaf(a.w, w.x, acc[rq * 4 + 3][0]);
      acc[rq * 4 + 3][1] = fmaf(a.w, w.y, acc[rq * 4 + 3][1]);
    }
  }
#pragma unroll
  for (int r = 0; r < 32; ++r) {
    atomicAdd(&C[(size_t)r * ldc + c0], acc[r][0]);
    atomicAdd(&C[(size_t)r * ldc + c0 + 1], acc[r][1]);
  }
}

// grid (7, 16): x -> {q1 lo, q1 hi, q2, v1 lo, v1 hi, m1 lo, m1 hi}
__global__ __launch_bounds__(128) void k_skinny_batch1(
    const float* __restrict__ features, const float* __restrict__ W1s,
    const float* __restrict__ W1e, const float* __restrict__ Wv1,
    const float* __restrict__ Wm1, float* __restrict__ q1b,
    float* __restrict__ q2b, float* __restrict__ v1h,
    float* __restrict__ m1h) {
  __shared__ float lA[64 * 36];
  const int t = blockIdx.x;
  const float* Wp; float* Cp; int ldw, n0;
  switch (t) {
    case 0: Wp = W1s; Cp = q1b; ldw = 512; n0 = 0;   break;
    case 1: Wp = W1s; Cp = q1b; ldw = 512; n0 = 256; break;
    case 2: Wp = W1e; Cp = q2b; ldw = 256; n0 = 0;   break;
    case 3: Wp = Wv1; Cp = v1h; ldw = 512; n0 = 0;   break;
    case 4: Wp = Wv1; Cp = v1h; ldw = 512; n0 = 256; break;
    case 5: Wp = Wm1; Cp = m1h; ldw = 512; n0 = 0;   break;
    default: Wp = Wm1; Cp = m1h; ldw = 512; n0 = 256; break;
  }
  skinny32_body(features, F_, blockIdx.y * 64, Wp, ldw, n0, ldw, Cp, ldw, lA);
}

// grid (3, 16)
__global__ __launch_bounds__(128) void k_skinny_hp_feat(
    const float* __restrict__ features, const float* __restrict__ Wp1,
    float* __restrict__ hp_acc) {
  __shared__ float lA[64 * 36];
  skinny32_body(features, F_, blockIdx.y * 64, Wp1, PH_, blockIdx.x * 256, PH_,
                hp_acc, PH_, lA);
}

// grid (19, 12)
__global__ __launch_bounds__(128) void k_skinny_logits(
    const float* __restrict__ hp, const float* __restrict__ Wp2,
    float* __restrict__ out) {
  __shared__ float lA[64 * 36];
  skinny32_body(hp, PH_, blockIdx.y * 64, Wp2, ADIM_, blockIdx.x * 256, ADIM_,
                out, ADIM_, lA);
}

// ---------- staging helper: 16B chunks into pad-80 LDS rows (5 chunks/row) ----------
__device__ __forceinline__ void stage80(
    const unsigned short* __restrict__ src, int row_base, int k0,
    char* lds, int lds_off, int nchunks, int tid) {
  for (int i = 0; i * 256 < nchunks; ++i) {
    const int c = i * 256 + tid;
    if (c < nchunks) {
      const int row = c / 5, sub = c % 5;
      const int s = (sub == 4) ? 0 : sub;  // pad chunk loads row start (unused)
      const unsigned short* g = src + (size_t)(row_base + row) * 1024 + k0 + s * 8;
      GLD16(g, lds + lds_off + i * 4096 + ((tid >> 6) * 1024));
    }
  }
}

// ---------- fused GEMM: y<8 -> C1 fp32 (2-term B1), y>=8 -> C2 bf16 (1-term B2) ----------
// grid (64, 12): bid = x + 64y -> XCD = x%8, so all 12 y share one XCD's L2 A-copy.
__global__ __launch_bounds__(256) void k_gemmA(
    const unsigned short* __restrict__ Ahi, const unsigned short* __restrict__ B1hi,
    const unsigned short* __restrict__ B1lo, const unsigned short* __restrict__ B2hi,
    float* __restrict__ C1, unsigned short* __restrict__ C2) {
  __shared__ unsigned short lds[10240];  // 20480B: A@0 Bh@10240 Bl@15360
  char* L = (char*)lds;
  const int tid = threadIdx.x;
  const int lane = tid & 63, w = tid >> 6;
  const int m0 = blockIdx.x * 128;
  const int y = blockIdx.y;
  const bool two = (y < 8);
  const int n0 = two ? y * 64 : (y - 8) * 64;
  const unsigned short* Bh = two ? B1hi : B2hi;
  const int wr = w >> 1, wc = w & 1;
  v4f acc[4][2];
#pragma unroll
  for (int mi = 0; mi < 4; ++mi)
#pragma unroll
    for (int ni = 0; ni < 2; ++ni) acc[mi][ni] = (v4f)(0.f);

  for (int k0 = 0; k0 < 1024; k0 += 32) {
    __syncthreads();
    stage80(Ahi, m0, k0, L, 0, 640, tid);
    stage80(Bh, n0, k0, L, 10240, 320, tid);
    if (two) stage80(B1lo, n0, k0, L, 15360, 320, tid);
    asm volatile("s_waitcnt vmcnt(0)" ::: "memory");
    __syncthreads();
    v8s ah[4], bh[2], bl[2];
    const int fo = (lane >> 4) * 16;
#pragma unroll
    for (int mi = 0; mi < 4; ++mi)
      ah[mi] = *(const v8s*)(L + (wr * 64 + mi * 16 + (lane & 15)) * 80 + fo);
#pragma unroll
    for (int ni = 0; ni < 2; ++ni) {
      const int ro = (wc * 32 + ni * 16 + (lane & 15)) * 80 + fo;
      bh[ni] = *(const v8s*)(L + 10240 + ro);
      if (two) bl[ni] = *(const v8s*)(L + 15360 + ro);
    }
#pragma unroll
    for (int mi = 0; mi < 4; ++mi)
#pragma unroll
      for (int ni = 0; ni < 2; ++ni) {
        acc[mi][ni] = __builtin_amdgcn_mfma_f32_16x16x32_bf16(ah[mi], bh[ni], acc[mi][ni], 0, 0, 0);
        if (two)
          acc[mi][ni] = __builtin_amdgcn_mfma_f32_16x16x32_bf16(ah[mi], bl[ni], acc[mi][ni], 0, 0, 0);
      }
  }
  if (two) {
#pragma unroll
    for (int mi = 0; mi < 4; ++mi)
#pragma unroll
      for (int ni = 0; ni < 2; ++ni)
#pragma unroll
        for (int j = 0; j < 4; ++j) {
          const int mrow = m0 + wr * 64 + mi * 16 + (lane >> 4) * 4 + j;
          const int ncol = n0 + wc * 32 + ni * 16 + (lane & 15);
          C1[(size_t)mrow * 512 + ncol] = acc[mi][ni][j];
        }
  } else {
#pragma unroll
    for (int mi = 0; mi < 4; ++mi)
#pragma unroll
      for (int ni = 0; ni < 2; ++ni)
#pragma unroll
        for (int j = 0; j < 4; ++j) {
          const int mrow = m0 + wr * 64 + mi * 16 + (lane >> 4) * 4 + j;
          const int ncol = n0 + wc * 32 + ni * 16 + (lane & 15);
          C2[(size_t)mrow * 256 + ncol] = f2bf(acc[mi][ni][j]);
        }
  }
}

// ---------- scores: 1024 blocks, 8 k-rows staged in LDS, 1 (b,k) per thread ----------
__global__ __launch_bounds__(256) void k_scores2(
    const float* __restrict__ C1, const float* __restrict__ q1b,
    const float* __restrict__ W2s, const float* __restrict__ b2s,
    float* __restrict__ scores) {
  __shared__ float4 c4[8 * 129];  // row pad 129 f4: 8 rows cover all 32 banks
  __shared__ float4 w4[128];
  const int tid = threadIdx.x;
  const int kbase = blockIdx.x * 8;
#pragma unroll
  for (int p = 0; p < 4; ++p) {
    const int idx = p * 256 + tid;
    const int row = idx >> 7, c = idx & 127;
    c4[row * 129 + c] = *(const float4*)&C1[(size_t)(kbase + row) * 512 + c * 4];
  }
  if (tid < 128) w4[tid] = *(const float4*)&W2s[tid * 4];
  __syncthreads();
  const int b = tid >> 3, ks = tid & 7;
  const float4* qrow = (const float4*)&q1b[b * 512];
  float acc = 0.f;
  for (int i = 0; i < 128; ++i) {
    const float4 c = c4[ks * 129 + i];
    const float4 q = qrow[i];
    const float4 w = w4[i];
    acc += fmaxf(q.x + c.x, 0.f) * w.x + fmaxf(q.y + c.y, 0.f) * w.y +
           fmaxf(q.z + c.z, 0.f) * w.z + fmaxf(q.w + c.w, 0.f) * w.w;
  }
  scores[(size_t)b * K_ + kbase + ks] = acc + b2s[0];
}

// ---------- exact top-1000 (set semantics; ties by lowest index) ----------
__global__ __launch_bounds__(1024) void k_topk(
    const float* __restrict__ scores, int* __restrict__ topk_idx) {
  __shared__ unsigned key[K_];
  __shared__ unsigned whist[16][256];
  __shared__ unsigned sfx[256];
  __shared__ int eqlist[1024];
  __shared__ unsigned ctl[4];
  const int tid = threadIdx.x;
  const int wid = tid >> 6;
  const int b = blockIdx.x;
  const float* row = scores + (size_t)b * K_;
  for (int i = tid; i < K_; i += 1024) {
    const unsigned u = __float_as_uint(row[i]);
    key[i] = (u & 0x80000000u) ? ~u : (u | 0x80000000u);
  }
  unsigned prefix = 0;
  int r = TOPK_;
  for (int p = 0; p < 4; ++p) {
    const int shift = 24 - 8 * p;
    for (int i = tid; i < 16 * 256; i += 1024) ((unsigned*)whist)[i] = 0;
    __syncthreads();
    const unsigned pmask = (p == 0) ? 0u : (0xFFFFFFFFu << (shift + 8));
    for (int i = tid; i < K_; i += 1024) {
      const unsigned k = key[i];
      if ((k & pmask) == prefix) atomicAdd(&whist[wid][(k >> shift) & 255u], 1u);
    }
    __syncthreads();
    if (tid < 256) {
      unsigned s = 0;
#pragma unroll
      for (int ww = 0; ww < 16; ++ww) s += whist[ww][tid];
      sfx[tid] = s;
    }
    __syncthreads();
    for (int off = 1; off < 256; off <<= 1) {
      unsigned v = 0;
      if (tid < 256) { v = sfx[tid]; if (tid + off < 256) v += sfx[tid + off]; }
      __syncthreads();
      if (tid < 256) sfx[tid] = v;
      __syncthreads();
    }
    if (tid < 256) {
      const int Sge = (int)sfx[tid];
      const int Sgt = (tid < 255) ? (int)sfx[tid + 1] : 0;
      if (Sgt < r && r <= Sge) { ctl[0] = (unsigned)tid; ctl[1] = (unsigned)(r - Sgt); }
    }
    __syncthreads();
    prefix |= ctl[0] << shift;
    r = (int)ctl[1];
    __syncthreads();
  }
  const unsigned T = prefix;
  const int take_eq = r;
  if (tid == 0) { ctl[2] = 0; ctl[3] = 0; }
  __syncthreads();
  int* outp = topk_idx + b * TOPK_;
  for (int i = tid; i < K_; i += 1024) {
    const unsigned k = key[i];
    if (k > T) outp[atomicAdd(&ctl[2], 1u)] = i;
    else if (k == T) { const unsigned e = atomicAdd(&ctl[3], 1u); if (e < 1024) eqlist[e] = i; }
  }
  __syncthreads();
  const int m = (ctl[3] < 1024u) ? (int)ctl[3] : 1024;
  const int ngt = TOPK_ - take_eq;
  for (int sel = 0; sel < take_eq; ++sel) {
    key[tid] = (tid < m) ? (unsigned)eqlist[tid] : 0xFFFFFFFFu;
    __syncthreads();
    for (int s = 512; s > 0; s >>= 1) {
      if (tid < s) key[tid] = min(key[tid], key[tid + s]);
      __syncthreads();
    }
    const unsigned mn = key[0];
    if (tid < m && (unsigned)eqlist[tid] == mn) eqlist[tid] = 0x7FFFFFFF;
    if (tid == 0) outp[ngt + sel] = (int)mn;
    __syncthreads();
  }
}

// ---------- s2[e] = b2e + sum_j gelu(q2b[b][j] + C2[idx][j]) * W2e[j] ----------
__global__ __launch_bounds__(256) void k_s2(
    const unsigned short* __restrict__ C2, const float* __restrict__ q2b,
    const int* __restrict__ topk_idx, const float* __restrict__ W2e,
    const float* __restrict__ b2e, float* __restrict__ s2) {
  const int tid = threadIdx.x;
  const int ln = tid & 63;
  const int e = blockIdx.x * 4 + (tid >> 6);
  const int b = e / TOPK_;
  const int idx = topk_idx[e];
  const v4u16 kv = *(const v4u16*)(C2 + (size_t)idx * H2_ + ln * 4);
  const float4 qv = *(const float4*)(q2b + b * H2_ + ln * 4);
  float s = gelu_f(qv.x + bf2f(kv[0])) * W2e[ln * 4 + 0]
          + gelu_f(qv.y + bf2f(kv[1])) * W2e[ln * 4 + 1]
          + gelu_f(qv.z + bf2f(kv[2])) * W2e[ln * 4 + 2]
          + gelu_f(qv.w + bf2f(kv[3])) * W2e[ln * 4 + 3];
#pragma unroll
  for (int off = 32; off > 0; off >>= 1) s += __shfl_down(s, off);
  if (ln == 0) s2[e] = s + b2e[0];
}

// ---------- w2 = softmax(s2) per row ----------
__global__ __launch_bounds__(256) void k_soft(
    const float* __restrict__ s2, float* __restrict__ w2) {
  __shared__ float red[256];
  const int tid = threadIdx.x, b = blockIdx.x;
  float m = -3.4e38f;
  for (int t = tid; t < TOPK_; t += 256) m = fmaxf(m, s2[b * TOPK_ + t]);
  red[tid] = m;
  __syncthreads();
  for (int s = 128; s > 0; s >>= 1) {
    if (tid < s) red[tid] = fmaxf(red[tid], red[tid + s]);
    __syncthreads();
  }
  m = red[0];
  __syncthreads();
  float ps = 0.f;
  for (int t = tid; t < TOPK_; t += 256) {
    const float ev = expf(s2[b * TOPK_ + t] - m);
    w2[b * TOPK_ + t] = ev;
    ps += ev;
  }
  red[tid] = ps;
  __syncthreads();
  for (int s = 128; s > 0; s >>= 1) {
    if (tid < s) red[tid] += red[tid + s];
    __syncthreads();
  }
  const float inv = 1.f / red[0];
  for (int t = tid; t < TOPK_; t += 256) w2[b * TOPK_ + t] *= inv;
}

// ---------- weighted actions/results (gather-reduce, 8 chunks per b) ----------
__global__ __launch_bounds__(256) void k_weighted(
    const int* __restrict__ topk_idx, const float* __restrict__ w2,
    const float* __restrict__ memory, float* __restrict__ wact_acc,
    float* __restrict__ wres_acc) {
  const int blk = blockIdx.x;
  const int b = blk >> 3, c = blk & 7;
  const int tid = threadIdx.x;
  const int g = tid >> 7, a = tid & 127;
  float acc = 0.f, accr = 0.f;
  for (int t = c * 125 + g; t < (c + 1) * 125; t += 2) {
    const int idx = topk_idx[b * TOPK_ + t];
    const float wv = w2[b * TOPK_ + t];
    acc += truncf(memory[(size_t)idx * E_ + F_ + a]) * wv;
    if (a == 0) accr += wv * memory[(size_t)idx * E_ + (E_ - 1)];
  }
  atomicAdd(&wact_acc[b * 128 + a], acc);
  if (a == 0) atomicAdd(&wres_acc[b], accr);
}

// ---------- hp finalize: += wact @ Wp1b, then gelu (in place) ----------
__global__ __launch_bounds__(768) void k_hp_final(
    const float* __restrict__ wact, const float* __restrict__ Wp1,
    float* __restrict__ hp) {
  __shared__ float lw[128];
  const int b = blockIdx.x, j = threadIdx.x;
  if (j < 128) lw[j] = wact[b * 128 + j];
  __syncthreads();
  float acc = hp[b * PH_ + j];
  const float* wp = Wp1 + (size_t)F_ * PH_ + j;
#pragma unroll 4
  for (int h = 0; h < 128; ++h) acc = fmaf(lw[h], wp[(size_t)h * PH_], acc);
  hp[b * PH_ + j] = gelu_f(acc);
}

// ---------- value heads + finalize (both 512-dots per b in one block) ----------
__global__ __launch_bounds__(512) void k_value_fin(
    const float* __restrict__ v1h, const float* __restrict__ m1h,
    const float* __restrict__ Wv2, const float* __restrict__ bv2,
    const float* __restrict__ Wm2, const float* __restrict__ bm2,
    const float* __restrict__ wres, const float* __restrict__ wact,
    float* __restrict__ out) {
  const int b = blockIdx.x, tid = threadIdx.x;
  if (b == 32) {
#pragma unroll
    for (int i = 0; i < 8; ++i) out[OFF_WACT + i * 512 + tid] = wact[i * 512 + tid];
    return;
  }
  __shared__ float red[512];
  red[tid] = gelu_f(v1h[b * 512 + tid]) * Wv2[tid];
  __syncthreads();
  for (int s = 256; s > 0; s >>= 1) {
    if (tid < s) red[tid] += red[tid + s];
    __syncthreads();
  }
  if (tid == 0) red[0] = tanhf(red[0] + bv2[0]);
  __syncthreads();
  const float bv = red[0];
  __syncthreads();
  red[tid] = gelu_f(m1h[b * 512 + tid]) * Wm2[tid];
  __syncthreads();
  for (int s = 256; s > 0; s >>= 1) {
    if (tid < s) red[tid] += red[tid + s];
    __syncthreads();
  }
  if (tid == 0) {
    const float aw = 1.f / (1.f + expf(-(red[0] + bm2[0])));
    out[OFF_BV + b] = bv;
    out[OFF_VAL + b] = aw * wres[b] + (1.f - aw) * bv;
    out[OFF_WRES + b] = wres[b];
  }
}

extern "C" void kernel_launch(void* const* d_in, const int* in_sizes, int n_in,
                              void* d_out, int out_size, void* d_ws,
                              size_t ws_size, hipStream_t stream) {
  (void)in_sizes; (void)n_in; (void)out_size; (void)ws_size;
  const float* features = (const float*)d_in[0];
  const float* memory   = (const float*)d_in[1];
  const float* W1s = (const float*)d_in[2];
  const float* b1s = (const float*)d_in[3];
  const float* W2s = (const float*)d_in[4];
  const float* b2s = (const float*)d_in[5];
  const float* W1e = (const float*)d_in[6];
  const float* b1e = (const float*)d_in[7];
  const float* W2e = (const float*)d_in[8];
  const float* b2e = (const float*)d_in[9];
  const float* Wp1 = (const float*)d_in[10];
  const float* bp1 = (const float*)d_in[11];
  const float* Wp2 = (const float*)d_in[12];
  const float* bp2 = (const float*)d_in[13];
  const float* Wv1 = (const float*)d_in[14];
  const float* bv1 = (const float*)d_in[15];
  const float* Wv2 = (const float*)d_in[16];
  const float* bv2 = (const float*)d_in[17];
  const float* Wm1 = (const float*)d_in[18];
  const float* bm1 = (const float*)d_in[19];
  const float* Wm2 = (const float*)d_in[20];
  const float* bm2 = (const float*)d_in[21];
  float* out = (float*)d_out;

  // workspace layout (bytes)
  char* W = (char*)d_ws;
  unsigned short* Ahi  = (unsigned short*)(W);                      // 16 MB
  unsigned short* B1hi = (unsigned short*)(W + (16u << 20));        // 1 MB
  unsigned short* B1lo = (unsigned short*)(W + (17u << 20));        // 1 MB
  unsigned short* B2hi = (unsigned short*)(W + (18u << 20));        // 0.5 MB
  float*          C1   = (float*)(W + (19u << 20));                 // 16 MB
  unsigned short* C2   = (unsigned short*)(W + (35u << 20));        // 4 MB
  float*          scores = (float*)(W + (39u << 20));               // 1 MB
  char* S = W + (40u << 20);
  float* q1b      = (float*)(S);               // 64 KB
  float* q2b      = (float*)(S + 65536);       // 32 KB
  float* s2       = (float*)(S + 98304);       // 125 KB
  float* w2       = (float*)(S + 226304);      // 125 KB
  int*   topk     = (int*)  (S + 354304);      // 125 KB
  float* wact_acc = (float*)(S + 482304);      // 16 KB
  float* wres_acc = (float*)(S + 498688);      // 128 B
  float* aw_un    = (float*)(S + 498816);      // 128 B (unused)
  float* hp_acc   = (float*)(S + 498944);      // 96 KB
  float* v1h      = (float*)(S + 597248);      // 64 KB
  float* m1h      = (float*)(S + 662784);      // 64 KB
  (void)aw_un;

  k_split_mem<<<8192, 256, 0, stream>>>(memory, Ahi);
  k_split_w<<<dim3(24, 32), dim3(32, 8), 0, stream>>>(W1s, W1e, B1hi, B1lo, B2hi);
  k_init<<<921, 256, 0, stream>>>(b1s, b1e, bv1, bm1, bp1, bp2, q1b, q2b, v1h,
                                  m1h, hp_acc, wact_acc, wres_acc, out);
  k_skinny_batch1<<<dim3(7, 16), 128, 0, stream>>>(features, W1s, W1e, Wv1, Wm1,
                                                   q1b, q2b, v1h, m1h);
  k_skinny_hp_feat<<<dim3(3, 16), 128, 0, stream>>>(features, Wp1, hp_acc);
  k_gemmA<<<dim3(64, 12), 256, 0, stream>>>(Ahi, B1hi, B1lo, B2hi, C1, C2);
  k_scores2<<<1024, 256, 0, stream>>>(C1, q1b, W2s, b2s, scores);
  k_topk<<<32, 1024, 0, stream>>>(scores, topk);
  k_s2<<<8000, 256, 0, stream>>>(C2, q2b, topk, W2e, b2e, s2);
  k_soft<<<32, 256, 0, stream>>>(s2, w2);
  k_weighted<<<256, 256, 0, stream>>>(topk, w2, memory, wact_acc, wres_acc);
  k_hp_final<<<32, 768, 0, stream>>>(wact_acc, Wp1, hp_acc);
  k_value_fin<<<33, 512, 0, stream>>>(v1h, m1h, Wv2, bv2, Wm2, bm2, wres_acc,
                                      wact_acc, out);
  k_skinny_logits<<<dim3(19, 12), 128, 0, stream>>>(hp_acc, Wp2, out);
}

// Round 7
// 329.550 us; speedup vs baseline: 2.2836x; 1.0461x over previous
//
#include <hip/hip_runtime.h>
#include <math.h>

#define B_ 32
#define K_ 8192
#define TOPK_ 1000
#define F_ 1024
#define E_ 1153
#define H1_ 512
#define H2_ 256
#define PH_ 768
#define ADIM_ 4672

// output layout (floats): logits | board_vals | value | wact | wres
#define OFF_BV   149504
#define OFF_VAL  149536
#define OFF_WACT 149568
#define OFF_WRES 153664

typedef __attribute__((ext_vector_type(8))) short v8s;
typedef __attribute__((ext_vector_type(4))) float v4f;
typedef __attribute__((ext_vector_type(4))) unsigned short v4u16;

#define GLD16(gp, lp) __builtin_amdgcn_global_load_lds( \
    (const __attribute__((address_space(1))) void*)(gp), \
    (__attribute__((address_space(3))) void*)(lp), 16, 0, 0)

__device__ __forceinline__ float gelu_f(float x) {
  return 0.5f * x * (1.0f + erff(x * 0.70710678118654752440f));
}
__device__ __forceinline__ unsigned short f2bf(float x) {
  union { float f; unsigned u; } v; v.f = x;
  unsigned r = v.u + 0x7fffu + ((v.u >> 16) & 1u);
  return (unsigned short)(r >> 16);
}
__device__ __forceinline__ float bf2f(unsigned short h) {
  union { unsigned u; float f; } v; v.u = ((unsigned)h) << 16; return v.f;
}

// ---------- merged prep: split_mem | split_w | init (branch on blockIdx) ----------
__global__ __launch_bounds__(256) void k_prep(
    const float* __restrict__ memory, const float* __restrict__ W1s,
    const float* __restrict__ W1e, const float* __restrict__ b1s,
    const float* __restrict__ b1e, const float* __restrict__ bv1,
    const float* __restrict__ bm1, const float* __restrict__ bp1,
    const float* __restrict__ bp2, unsigned short* __restrict__ Ahi,
    unsigned short* __restrict__ B1hi, unsigned short* __restrict__ B1lo,
    unsigned short* __restrict__ B2hi, float* __restrict__ q1b,
    float* __restrict__ q2b, float* __restrict__ v1h, float* __restrict__ m1h,
    float* __restrict__ hp, float* __restrict__ wact, float* __restrict__ wres,
    float* __restrict__ out) {
  const int blk = blockIdx.x;
  const int tid = threadIdx.x;
  if (blk < 8192) {  // split_mem: row blk
    const float* src = memory + (size_t)blk * E_ + 4 * tid;
    unsigned* dst = (unsigned*)(Ahi + (size_t)blk * 1024);
    const float x0 = src[0], x1 = src[1], x2 = src[2], x3 = src[3];
    dst[2 * tid]     = (unsigned)f2bf(x0) | ((unsigned)f2bf(x1) << 16);
    dst[2 * tid + 1] = (unsigned)f2bf(x2) | ((unsigned)f2bf(x3) << 16);
  } else if (blk < 8960) {  // split_w
    __shared__ float t[32][33];
    const int blk2 = blk - 8192;
    const int x = tid & 31, y = tid >> 5;  // 32 x 8
    const int j0 = (blk2 % 24) * 32, k0 = (blk2 / 24) * 32;
#pragma unroll
    for (int i = 0; i < 4; ++i) {
      const int k = k0 + y + 8 * i;
      const int j = j0 + x;
      t[y + 8 * i][x] = (j < 512) ? W1s[(size_t)(F_ + k) * H1_ + j]
                                  : W1e[(size_t)(F_ + k) * H2_ + (j - 512)];
    }
    __syncthreads();
#pragma unroll
    for (int i = 0; i < 4; ++i) {
      const int j = j0 + y + 8 * i;
      const int k = k0 + x;
      const float v = t[x][y + 8 * i];
      const unsigned short h = f2bf(v);
      if (j < 512) {
        B1hi[(size_t)j * 1024 + k] = h;
        B1lo[(size_t)j * 1024 + k] = f2bf(v - bf2f(h));
      } else {
        B2hi[(size_t)(j - 512) * 1024 + k] = h;
      }
    }
  } else {  // init
    const int idx = (blk - 8960) * 256 + tid;
    if (idx < 32 * 2560) {
      const int b = idx / 2560, j = idx - b * 2560;
      if (j < 512) q1b[b * 512 + j] = b1s[j];
      else if (j < 768) q2b[b * 256 + (j - 512)] = b1e[j - 512];
      else if (j < 1280) v1h[b * 512 + (j - 768)] = bv1[j - 768];
      else if (j < 1792) m1h[b * 512 + (j - 1280)] = bm1[j - 1280];
      else hp[b * 768 + (j - 1792)] = bp1[j - 1792];
    } else if (idx < 32 * 2560 + 4128) {
      const int k = idx - 32 * 2560;
      if (k < 4096) wact[k] = 0.f;
      else wres[k - 4096] = 0.f;
    } else {
      const int k = idx - (32 * 2560 + 4128);
      if (k < B_ * ADIM_) out[k] = bp2[k % ADIM_];
    }
  }
}

// ---------- skinny-M fp32 GEMM core: C[32][N] += A[32][64-slice] @ W ----------
__device__ __forceinline__ void skinny32_body(
    const float* __restrict__ A, int lda, int kbase,
    const float* __restrict__ Wp, int ldw, int n0, int N,
    float* __restrict__ C, int ldc, float* __restrict__ lA) {
  const int tid = threadIdx.x;
#pragma unroll
  for (int j = 0; j < 16; ++j) {
    const int idx = j * 128 + tid;
    const int r = idx >> 6, k = idx & 63;
    lA[k * 36 + r] = A[(size_t)r * lda + kbase + k];
  }
  __syncthreads();
  const int c0 = n0 + tid * 2;
  if (c0 >= N) return;
  float acc[32][2];
#pragma unroll
  for (int r = 0; r < 32; ++r) { acc[r][0] = 0.f; acc[r][1] = 0.f; }
  const float* wp = Wp + (size_t)kbase * ldw + c0;
#pragma unroll 2
  for (int k = 0; k < 64; ++k) {
    const float2 w = *(const float2*)&wp[(size_t)k * ldw];
#pragma unroll
    for (int rq = 0; rq < 8; ++rq) {
      const float4 a = *(const float4*)&lA[k * 36 + rq * 4];
      acc[rq * 4 + 0][0] = fmaf(a.x, w.x, acc[rq * 4 + 0][0]);
      acc[rq * 4 + 0][1] = fmaf(a.x, w.y, acc[rq * 4 + 0][1]);
      acc[rq * 4 + 1][0] = fmaf(a.y, w.x, acc[rq * 4 + 1][0]);
      acc[rq * 4 + 1][1] = fmaf(a.y, w.y, acc[rq * 4 + 1][1]);
      acc[rq * 4 + 2][0] = fmaf(a.z, w.x, acc[rq * 4 + 2][0]);
      acc[rq * 4 + 2][1] = fmaf(a.z, w.y, acc[rq * 4 + 2][1]);
      acc[rq * 4 + 3][0] = fmaf(a.w, w.x, acc[rq * 4 + 3][0]);
      acc[rq * 4 + 3][1] = fmaf(a.w, w.y, acc[rq * 4 + 3][1]);
    }
  }
#pragma unroll
  for (int r = 0; r < 32; ++r) {
    atomicAdd(&C[(size_t)r * ldc + c0], acc[r][0]);
    atomicAdd(&C[(size_t)r * ldc + c0 + 1], acc[r][1]);
  }
}

// grid (10, 16): x<7 -> {q1 lo, q1 hi, q2, v1 lo, v1 hi, m1 lo, m1 hi}; x>=7 -> hp
__global__ __launch_bounds__(128) void k_skinny_all(
    const float* __restrict__ features, const float* __restrict__ W1s,
    const float* __restrict__ W1e, const float* __restrict__ Wv1,
    const float* __restrict__ Wm1, const float* __restrict__ Wp1,
    float* __restrict__ q1b, float* __restrict__ q2b, float* __restrict__ v1h,
    float* __restrict__ m1h, float* __restrict__ hp_acc) {
  __shared__ float lA[64 * 36];
  const int t = blockIdx.x;
  const float* Wp; float* Cp; int ldw, n0;
  switch (t) {
    case 0: Wp = W1s; Cp = q1b; ldw = 512; n0 = 0;   break;
    case 1: Wp = W1s; Cp = q1b; ldw = 512; n0 = 256; break;
    case 2: Wp = W1e; Cp = q2b; ldw = 256; n0 = 0;   break;
    case 3: Wp = Wv1; Cp = v1h; ldw = 512; n0 = 0;   break;
    case 4: Wp = Wv1; Cp = v1h; ldw = 512; n0 = 256; break;
    case 5: Wp = Wm1; Cp = m1h; ldw = 512; n0 = 0;   break;
    case 6: Wp = Wm1; Cp = m1h; ldw = 512; n0 = 256; break;
    default: Wp = Wp1; Cp = hp_acc; ldw = PH_; n0 = (t - 7) * 256; break;
  }
  skinny32_body(features, F_, blockIdx.y * 64, Wp, ldw, n0, ldw, Cp, ldw, lA);
}

// grid (19, 12)
__global__ __launch_bounds__(128) void k_skinny_logits(
    const float* __restrict__ hp, const float* __restrict__ Wp2,
    float* __restrict__ out) {
  __shared__ float lA[64 * 36];
  skinny32_body(hp, PH_, blockIdx.y * 64, Wp2, ADIM_, blockIdx.x * 256, ADIM_,
                out, ADIM_, lA);
}

// ---------- staging helper: 16B chunks into pad-80 LDS rows (5 chunks/row) ----------
__device__ __forceinline__ void stage80(
    const unsigned short* __restrict__ src, int row_base, int k0,
    char* lds, int lds_off, int nchunks, int tid) {
  for (int i = 0; i * 256 < nchunks; ++i) {
    const int c = i * 256 + tid;
    if (c < nchunks) {
      const int row = c / 5, sub = c % 5;
      const int s = (sub == 4) ? 0 : sub;  // pad chunk loads row start (unused)
      const unsigned short* g = src + (size_t)(row_base + row) * 1024 + k0 + s * 8;
      GLD16(g, lds + lds_off + i * 4096 + ((tid >> 6) * 1024));
    }
  }
}

// ---------- fused GEMM, 128x128 tiles: y<4 -> C1 fp32 (2-term), y in {4,5} -> C2 bf16 ----------
// grid (64, 6): bid = x + 64y -> XCD = x%8; 6 y-blocks share one XCD's L2 A-copy.
__global__ __launch_bounds__(256) void k_gemmA(
    const unsigned short* __restrict__ Ahi, const unsigned short* __restrict__ B1hi,
    const unsigned short* __restrict__ B1lo, const unsigned short* __restrict__ B2hi,
    float* __restrict__ C1, unsigned short* __restrict__ C2) {
  __shared__ unsigned short lds[15360];  // 30720B: A@0 Bh@10240 Bl@20480
  char* L = (char*)lds;
  const int tid = threadIdx.x;
  const int lane = tid & 63, w = tid >> 6;
  const int m0 = blockIdx.x * 128;
  const int y = blockIdx.y;
  const bool two = (y < 4);
  const int n0 = two ? y * 128 : (y - 4) * 128;
  const unsigned short* Bh = two ? B1hi : B2hi;
  const int wr = w >> 1, wc = w & 1;
  v4f acc[4][4];
#pragma unroll
  for (int mi = 0; mi < 4; ++mi)
#pragma unroll
    for (int ni = 0; ni < 4; ++ni) acc[mi][ni] = (v4f)(0.f);

  for (int k0 = 0; k0 < 1024; k0 += 32) {
    __syncthreads();
    stage80(Ahi, m0, k0, L, 0, 640, tid);
    stage80(Bh, n0, k0, L, 10240, 640, tid);
    if (two) stage80(B1lo, n0, k0, L, 20480, 640, tid);
    asm volatile("s_waitcnt vmcnt(0)" ::: "memory");
    __syncthreads();
    v8s ah[4], bh[4], bl[4];
    const int fo = (lane >> 4) * 16;
#pragma unroll
    for (int mi = 0; mi < 4; ++mi)
      ah[mi] = *(const v8s*)(L + (wr * 64 + mi * 16 + (lane & 15)) * 80 + fo);
#pragma unroll
    for (int ni = 0; ni < 4; ++ni) {
      const int ro = (wc * 64 + ni * 16 + (lane & 15)) * 80 + fo;
      bh[ni] = *(const v8s*)(L + 10240 + ro);
      if (two) bl[ni] = *(const v8s*)(L + 20480 + ro);
    }
#pragma unroll
    for (int mi = 0; mi < 4; ++mi)
#pragma unroll
      for (int ni = 0; ni < 4; ++ni) {
        acc[mi][ni] = __builtin_amdgcn_mfma_f32_16x16x32_bf16(ah[mi], bh[ni], acc[mi][ni], 0, 0, 0);
        if (two)
          acc[mi][ni] = __builtin_amdgcn_mfma_f32_16x16x32_bf16(ah[mi], bl[ni], acc[mi][ni], 0, 0, 0);
      }
  }
  if (two) {
#pragma unroll
    for (int mi = 0; mi < 4; ++mi)
#pragma unroll
      for (int ni = 0; ni < 4; ++ni)
#pragma unroll
        for (int j = 0; j < 4; ++j) {
          const int mrow = m0 + wr * 64 + mi * 16 + (lane >> 4) * 4 + j;
          const int ncol = n0 + wc * 64 + ni * 16 + (lane & 15);
          C1[(size_t)mrow * 512 + ncol] = acc[mi][ni][j];
        }
  } else {
#pragma unroll
    for (int mi = 0; mi < 4; ++mi)
#pragma unroll
      for (int ni = 0; ni < 4; ++ni)
#pragma unroll
        for (int j = 0; j < 4; ++j) {
          const int mrow = m0 + wr * 64 + mi * 16 + (lane >> 4) * 4 + j;
          const int ncol = n0 + wc * 64 + ni * 16 + (lane & 15);
          C2[(size_t)mrow * 256 + ncol] = f2bf(acc[mi][ni][j]);
        }
  }
}

// ---------- scores: 1024 blocks, 8 k-rows staged in LDS, 1 (b,k) per thread ----------
__global__ __launch_bounds__(256) void k_scores2(
    const float* __restrict__ C1, const float* __restrict__ q1b,
    const float* __restrict__ W2s, const float* __restrict__ b2s,
    float* __restrict__ scores) {
  __shared__ float4 c4[8 * 129];  // row pad 129 f4: 8 rows cover all 32 banks
  __shared__ float4 w4[128];
  const int tid = threadIdx.x;
  const int kbase = blockIdx.x * 8;
#pragma unroll
  for (int p = 0; p < 4; ++p) {
    const int idx = p * 256 + tid;
    const int row = idx >> 7, c = idx & 127;
    c4[row * 129 + c] = *(const float4*)&C1[(size_t)(kbase + row) * 512 + c * 4];
  }
  if (tid < 128) w4[tid] = *(const float4*)&W2s[tid * 4];
  __syncthreads();
  const int b = tid >> 3, ks = tid & 7;
  const float4* qrow = (const float4*)&q1b[b * 512];
  float acc = 0.f;
  for (int i = 0; i < 128; ++i) {
    const float4 c = c4[ks * 129 + i];
    const float4 q = qrow[i];
    const float4 w = w4[i];
    acc += fmaxf(q.x + c.x, 0.f) * w.x + fmaxf(q.y + c.y, 0.f) * w.y +
           fmaxf(q.z + c.z, 0.f) * w.z + fmaxf(q.w + c.w, 0.f) * w.w;
  }
  scores[(size_t)b * K_ + kbase + ks] = acc + b2s[0];
}

// ---------- exact top-1000: 2 full radix passes + candidate-list passes 3/4 ----------
__global__ __launch_bounds__(1024) void k_topk(
    const float* __restrict__ scores, int* __restrict__ topk_idx) {
  __shared__ unsigned key[K_];         // 32 KB (reused as scratch at end)
  __shared__ unsigned whist[16][256];  // 16 KB; [1..15] overlaid by cand list
  __shared__ unsigned sfx[256];
  __shared__ int eqlist[1024];
  __shared__ unsigned ctl[6];  // d, r, n_out, eq_cnt, ncand
  int* cand = (int*)&whist[1][0];      // 3840 entries
  const int NCAND = 3840;
  const int tid = threadIdx.x;
  const int wid = tid >> 6;
  const int b = blockIdx.x;
  const float* row = scores + (size_t)b * K_;

  // pass 1: fused convert + per-wave hist on byte 3
  for (int i = tid; i < 16 * 256; i += 1024) ((unsigned*)whist)[i] = 0;
  __syncthreads();
  for (int i = tid; i < K_; i += 1024) {
    const unsigned u = __float_as_uint(row[i]);
    const unsigned k = (u & 0x80000000u) ? ~u : (u | 0x80000000u);
    key[i] = k;
    atomicAdd(&whist[wid][k >> 24], 1u);
  }
  __syncthreads();
  unsigned prefix = 0;
  int r = TOPK_;
#pragma unroll
  for (int p = 0; p < 2; ++p) {  // passes 1,2 share reduce/select code
    const int shift = 24 - 8 * p;
    if (tid < 256) {
      unsigned s = 0;
#pragma unroll
      for (int ww = 0; ww < 16; ++ww) s += whist[ww][tid];
      sfx[tid] = s;
    }
    __syncthreads();
    for (int off = 1; off < 256; off <<= 1) {
      unsigned v = 0;
      if (tid < 256) { v = sfx[tid]; if (tid + off < 256) v += sfx[tid + off]; }
      __syncthreads();
      if (tid < 256) sfx[tid] = v;
      __syncthreads();
    }
    if (tid < 256) {
      const int Sge = (int)sfx[tid];
      const int Sgt = (tid < 255) ? (int)sfx[tid + 1] : 0;
      if (Sgt < r && r <= Sge) { ctl[0] = (unsigned)tid; ctl[1] = (unsigned)(r - Sgt); }
    }
    __syncthreads();
    prefix |= ctl[0] << shift;
    r = (int)ctl[1];
    __syncthreads();
    if (p == 0) {  // pass 2 hist on byte 2 (full scan)
      for (int i = tid; i < 16 * 256; i += 1024) ((unsigned*)whist)[i] = 0;
      __syncthreads();
      for (int i = tid; i < K_; i += 1024) {
        const unsigned k = key[i];
        if ((k >> 24) == prefix >> 24) atomicAdd(&whist[wid][(k >> 16) & 255u], 1u);
      }
      __syncthreads();
    }
  }
  // append candidates matching 2-byte prefix
  if (tid == 0) ctl[4] = 0;
  __syncthreads();
  for (int i = tid; i < K_; i += 1024) {
    if ((key[i] >> 16) == (prefix >> 16)) {
      const unsigned pos = atomicAdd(&ctl[4], 1u);
      if (pos < (unsigned)NCAND) cand[pos] = i;
    }
  }
  __syncthreads();
  const int ncand = (ctl[4] < (unsigned)NCAND) ? (int)ctl[4] : NCAND;
  const bool ovf = ctl[4] > (unsigned)NCAND;
  // passes 3,4 on candidates (single hist whist[0])
#pragma unroll
  for (int p = 2; p < 4; ++p) {
    const int shift = 24 - 8 * p;
    if (tid < 256) whist[0][tid] = 0;
    __syncthreads();
    if (!ovf) {
      for (int j = tid; j < ncand; j += 1024) {
        const unsigned k = key[cand[j]];
        if (p == 2 || ((k >> 8) << 8 >> 16 == (prefix >> 8) << 8 >> 16)) {
          if (p == 2) atomicAdd(&whist[0][(k >> 8) & 255u], 1u);
          else if ((k & 0xFFFFFF00u) == prefix) atomicAdd(&whist[0][k & 255u], 1u);
        }
      }
    } else {
      const unsigned pmask = 0xFFFFFFFFu << (shift + 8);
      for (int i = tid; i < K_; i += 1024) {
        const unsigned k = key[i];
        if ((k & pmask) == prefix) atomicAdd(&whist[0][(k >> shift) & 255u], 1u);
      }
    }
    __syncthreads();
    if (tid < 256) sfx[tid] = whist[0][tid];
    __syncthreads();
    for (int off = 1; off < 256; off <<= 1) {
      unsigned v = 0;
      if (tid < 256) { v = sfx[tid]; if (tid + off < 256) v += sfx[tid + off]; }
      __syncthreads();
      if (tid < 256) sfx[tid] = v;
      __syncthreads();
    }
    if (tid < 256) {
      const int Sge = (int)sfx[tid];
      const int Sgt = (tid < 255) ? (int)sfx[tid + 1] : 0;
      if (Sgt < r && r <= Sge) { ctl[0] = (unsigned)tid; ctl[1] = (unsigned)(r - Sgt); }
    }
    __syncthreads();
    prefix |= ctl[0] << shift;
    r = (int)ctl[1];
    __syncthreads();
  }
  const unsigned T = prefix;
  const int take_eq = r;
  if (tid == 0) { ctl[2] = 0; ctl[3] = 0; }
  __syncthreads();
  int* outp = topk_idx + b * TOPK_;
  for (int i = tid; i < K_; i += 1024) {
    const unsigned k = key[i];
    if (k > T) outp[atomicAdd(&ctl[2], 1u)] = i;
    else if (k == T) { const unsigned e = atomicAdd(&ctl[3], 1u); if (e < 1024) eqlist[e] = i; }
  }
  __syncthreads();
  const int m = (ctl[3] < 1024u) ? (int)ctl[3] : 1024;
  const int ngt = TOPK_ - take_eq;
  for (int sel = 0; sel < take_eq; ++sel) {
    key[tid] = (tid < m) ? (unsigned)eqlist[tid] : 0xFFFFFFFFu;
    __syncthreads();
    for (int s = 512; s > 0; s >>= 1) {
      if (tid < s) key[tid] = min(key[tid], key[tid + s]);
      __syncthreads();
    }
    const unsigned mn = key[0];
    if (tid < m && (unsigned)eqlist[tid] == mn) eqlist[tid] = 0x7FFFFFFF;
    if (tid == 0) outp[ngt + sel] = (int)mn;
    __syncthreads();
  }
}

// ---------- s2[e] = b2e + sum_j gelu(q2b[b][j] + C2[idx][j]) * W2e[j] ----------
__global__ __launch_bounds__(256) void k_s2(
    const unsigned short* __restrict__ C2, const float* __restrict__ q2b,
    const int* __restrict__ topk_idx, const float* __restrict__ W2e,
    const float* __restrict__ b2e, float* __restrict__ s2) {
  const int tid = threadIdx.x;
  const int ln = tid & 63;
  const int e = blockIdx.x * 4 + (tid >> 6);
  const int b = e / TOPK_;
  const int idx = topk_idx[e];
  const v4u16 kv = *(const v4u16*)(C2 + (size_t)idx * H2_ + ln * 4);
  const float4 qv = *(const float4*)(q2b + b * H2_ + ln * 4);
  float s = gelu_f(qv.x + bf2f(kv[0])) * W2e[ln * 4 + 0]
          + gelu_f(qv.y + bf2f(kv[1])) * W2e[ln * 4 + 1]
          + gelu_f(qv.z + bf2f(kv[2])) * W2e[ln * 4 + 2]
          + gelu_f(qv.w + bf2f(kv[3])) * W2e[ln * 4 + 3];
#pragma unroll
  for (int off = 32; off > 0; off >>= 1) s += __shfl_down(s, off);
  if (ln == 0) s2[e] = s + b2e[0];
}

// ---------- weighted actions/results with inline softmax (8 chunks per b) ----------
// Each of the 8 chunk-blocks recomputes the identical softmax denominator
// (deterministic: same code, same inputs -> bitwise-equal m, sum).
__global__ __launch_bounds__(256) void k_weighted(
    const int* __restrict__ topk_idx, const float* __restrict__ s2,
    const float* __restrict__ memory, float* __restrict__ wact_acc,
    float* __restrict__ wres_acc) {
  __shared__ float ev[TOPK_];
  __shared__ float red[256];
  const int blk = blockIdx.x;
  const int b = blk >> 3, c = blk & 7;
  const int tid = threadIdx.x;
  float m = -3.4e38f;
  for (int t = tid; t < TOPK_; t += 256) m = fmaxf(m, s2[b * TOPK_ + t]);
  red[tid] = m;
  __syncthreads();
  for (int s = 128; s > 0; s >>= 1) {
    if (tid < s) red[tid] = fmaxf(red[tid], red[tid + s]);
    __syncthreads();
  }
  m = red[0];
  __syncthreads();
  float ps = 0.f;
  for (int t = tid; t < TOPK_; t += 256) {
    const float e = expf(s2[b * TOPK_ + t] - m);
    ev[t] = e;
    ps += e;
  }
  red[tid] = ps;
  __syncthreads();
  for (int s = 128; s > 0; s >>= 1) {
    if (tid < s) red[tid] += red[tid + s];
    __syncthreads();
  }
  const float inv = 1.f / red[0];
  __syncthreads();
  const int g = tid >> 7, a = tid & 127;
  float acc = 0.f, accr = 0.f;
  for (int t = c * 125 + g; t < (c + 1) * 125; t += 2) {
    const int idx = topk_idx[b * TOPK_ + t];
    const float wv = ev[t] * inv;
    acc += truncf(memory[(size_t)idx * E_ + F_ + a]) * wv;
    if (a == 0) accr += wv * memory[(size_t)idx * E_ + (E_ - 1)];
  }
  atomicAdd(&wact_acc[b * 128 + a], acc);
  if (a == 0) atomicAdd(&wres_acc[b], accr);
}

// ---------- tail: hp_final (b<32) | value heads+finalize (32..63) | wact copy (64) ----------
__global__ __launch_bounds__(512) void k_tail(
    const float* __restrict__ wact, const float* __restrict__ wres,
    const float* __restrict__ v1h, const float* __restrict__ m1h,
    const float* __restrict__ Wv2, const float* __restrict__ bv2,
    const float* __restrict__ Wm2, const float* __restrict__ bm2,
    const float* __restrict__ Wp1, float* __restrict__ hp,
    float* __restrict__ out) {
  const int blk = blockIdx.x, tid = threadIdx.x;
  if (blk < 32) {  // hp += wact @ Wp1b, gelu
    __shared__ float lw[128];
    if (tid < 128) lw[tid] = wact[blk * 128 + tid];
    __syncthreads();
    for (int j = tid; j < PH_; j += 512) {
      float acc = hp[blk * PH_ + j];
      const float* wp = Wp1 + (size_t)F_ * PH_ + j;
#pragma unroll 4
      for (int h = 0; h < 128; ++h) acc = fmaf(lw[h], wp[(size_t)h * PH_], acc);
      hp[blk * PH_ + j] = gelu_f(acc);
    }
  } else if (blk < 64) {  // value heads + value_output
    const int b = blk - 32;
    __shared__ float red[512];
    red[tid] = gelu_f(v1h[b * 512 + tid]) * Wv2[tid];
    __syncthreads();
    for (int s = 256; s > 0; s >>= 1) {
      if (tid < s) red[tid] += red[tid + s];
      __syncthreads();
    }
    if (tid == 0) red[0] = tanhf(red[0] + bv2[0]);
    __syncthreads();
    const float bv = red[0];
    __syncthreads();
    red[tid] = gelu_f(m1h[b * 512 + tid]) * Wm2[tid];
    __syncthreads();
    for (int s = 256; s > 0; s >>= 1) {
      if (tid < s) red[tid] += red[tid + s];
      __syncthreads();
    }
    if (tid == 0) {
      const float aw = 1.f / (1.f + expf(-(red[0] + bm2[0])));
      out[OFF_BV + b] = bv;
      out[OFF_VAL + b] = aw * wres[b] + (1.f - aw) * bv;
      out[OFF_WRES + b] = wres[b];
    }
  } else {  // wact copy
#pragma unroll
    for (int i = 0; i < 8; ++i) out[OFF_WACT + i * 512 + tid] = wact[i * 512 + tid];
  }
}

extern "C" void kernel_launch(void* const* d_in, const int* in_sizes, int n_in,
                              void* d_out, int out_size, void* d_ws,
                              size_t ws_size, hipStream_t stream) {
  (void)in_sizes; (void)n_in; (void)out_size; (void)ws_size;
  const float* features = (const float*)d_in[0];
  const float* memory   = (const float*)d_in[1];
  const float* W1s = (const float*)d_in[2];
  const float* b1s = (const float*)d_in[3];
  const float* W2s = (const float*)d_in[4];
  const float* b2s = (const float*)d_in[5];
  const float* W1e = (const float*)d_in[6];
  const float* b1e = (const float*)d_in[7];
  const float* W2e = (const float*)d_in[8];
  const float* b2e = (const float*)d_in[9];
  const float* Wp1 = (const float*)d_in[10];
  const float* bp1 = (const float*)d_in[11];
  const float* Wp2 = (const float*)d_in[12];
  const float* bp2 = (const float*)d_in[13];
  const float* Wv1 = (const float*)d_in[14];
  const float* bv1 = (const float*)d_in[15];
  const float* Wv2 = (const float*)d_in[16];
  const float* bv2 = (const float*)d_in[17];
  const float* Wm1 = (const float*)d_in[18];
  const float* bm1 = (const float*)d_in[19];
  const float* Wm2 = (const float*)d_in[20];
  const float* bm2 = (const float*)d_in[21];
  float* out = (float*)d_out;

  // workspace layout (bytes)
  char* W = (char*)d_ws;
  unsigned short* Ahi  = (unsigned short*)(W);                      // 16 MB
  unsigned short* B1hi = (unsigned short*)(W + (16u << 20));        // 1 MB
  unsigned short* B1lo = (unsigned short*)(W + (17u << 20));        // 1 MB
  unsigned short* B2hi = (unsigned short*)(W + (18u << 20));        // 0.5 MB
  float*          C1   = (float*)(W + (19u << 20));                 // 16 MB
  unsigned short* C2   = (unsigned short*)(W + (35u << 20));        // 4 MB
  float*          scores = (float*)(W + (39u << 20));               // 1 MB
  char* S = W + (40u << 20);
  float* q1b      = (float*)(S);               // 64 KB
  float* q2b      = (float*)(S + 65536);       // 32 KB
  float* s2       = (float*)(S + 98304);       // 125 KB
  int*   topk     = (int*)  (S + 354304);      // 125 KB
  float* wact_acc = (float*)(S + 482304);      // 16 KB
  float* wres_acc = (float*)(S + 498688);      // 128 B
  float* hp_acc   = (float*)(S + 498944);      // 96 KB
  float* v1h      = (float*)(S + 597248);      // 64 KB
  float* m1h      = (float*)(S + 662784);      // 64 KB

  k_prep<<<9881, 256, 0, stream>>>(memory, W1s, W1e, b1s, b1e, bv1, bm1, bp1,
                                   bp2, Ahi, B1hi, B1lo, B2hi, q1b, q2b, v1h,
                                   m1h, hp_acc, wact_acc, wres_acc, out);
  k_skinny_all<<<dim3(10, 16), 128, 0, stream>>>(features, W1s, W1e, Wv1, Wm1,
                                                 Wp1, q1b, q2b, v1h, m1h, hp_acc);
  k_gemmA<<<dim3(64, 6), 256, 0, stream>>>(Ahi, B1hi, B1lo, B2hi, C1, C2);
  k_scores2<<<1024, 256, 0, stream>>>(C1, q1b, W2s, b2s, scores);
  k_topk<<<32, 1024, 0, stream>>>(scores, topk);
  k_s2<<<8000, 256, 0, stream>>>(C2, q2b, topk, W2e, b2e, s2);
  k_weighted<<<256, 256, 0, stream>>>(topk, s2, memory, wact_acc, wres_acc);
  k_tail<<<65, 512, 0, stream>>>(wact_acc, wres_acc, v1h, m1h, Wv2, bv2, Wm2,
                                 bm2, Wp1, hp_acc, out);
  k_skinny_logits<<<dim3(19, 12), 128, 0, stream>>>(hp_acc, Wp2, out);
}

// Round 9
// 324.755 us; speedup vs baseline: 2.3173x; 1.0148x over previous
//
#include <hip/hip_runtime.h>
#include <math.h>

#define B_ 32
#define K_ 8192
#define TOPK_ 1000
#define F_ 1024
#define E_ 1153
#define H1_ 512
#define H2_ 256
#define PH_ 768
#define ADIM_ 4672

// output layout (floats): logits | board_vals | value | wact | wres
#define OFF_BV   149504
#define OFF_VAL  149536
#define OFF_WACT 149568
#define OFF_WRES 153664

typedef __attribute__((ext_vector_type(8))) short v8s;
typedef __attribute__((ext_vector_type(4))) float v4f;
typedef __attribute__((ext_vector_type(4))) unsigned short v4u16;

#define GLD16(gp, lp) __builtin_amdgcn_global_load_lds( \
    (const __attribute__((address_space(1))) void*)(gp), \
    (__attribute__((address_space(3))) void*)(lp), 16, 0, 0)

__device__ __forceinline__ float gelu_f(float x) {
  return 0.5f * x * (1.0f + erff(x * 0.70710678118654752440f));
}
__device__ __forceinline__ unsigned short f2bf(float x) {
  union { float f; unsigned u; } v; v.f = x;
  unsigned r = v.u + 0x7fffu + ((v.u >> 16) & 1u);
  return (unsigned short)(r >> 16);
}
__device__ __forceinline__ float bf2f(unsigned short h) {
  union { unsigned u; float f; } v; v.u = ((unsigned)h) << 16; return v.f;
}

// ---------- merged prep: split_mem | split_w | init (branch on blockIdx) ----------
__global__ __launch_bounds__(256) void k_prep(
    const float* __restrict__ memory, const float* __restrict__ W1s,
    const float* __restrict__ W1e, const float* __restrict__ b1s,
    const float* __restrict__ b1e, const float* __restrict__ bv1,
    const float* __restrict__ bm1, const float* __restrict__ bp1,
    const float* __restrict__ bp2, unsigned short* __restrict__ Ahi,
    unsigned short* __restrict__ B1hi, unsigned short* __restrict__ B1lo,
    unsigned short* __restrict__ B2hi, float* __restrict__ q1b,
    float* __restrict__ q2b, float* __restrict__ v1h, float* __restrict__ m1h,
    float* __restrict__ hp, float* __restrict__ wact, float* __restrict__ wres,
    float* __restrict__ out) {
  const int blk = blockIdx.x;
  const int tid = threadIdx.x;
  if (blk < 8192) {  // split_mem: row blk
    const float* src = memory + (size_t)blk * E_ + 4 * tid;
    unsigned* dst = (unsigned*)(Ahi + (size_t)blk * 1024);
    const float x0 = src[0], x1 = src[1], x2 = src[2], x3 = src[3];
    dst[2 * tid]     = (unsigned)f2bf(x0) | ((unsigned)f2bf(x1) << 16);
    dst[2 * tid + 1] = (unsigned)f2bf(x2) | ((unsigned)f2bf(x3) << 16);
  } else if (blk < 8960) {  // split_w
    __shared__ float t[32][33];
    const int blk2 = blk - 8192;
    const int x = tid & 31, y = tid >> 5;  // 32 x 8
    const int j0 = (blk2 % 24) * 32, k0 = (blk2 / 24) * 32;
#pragma unroll
    for (int i = 0; i < 4; ++i) {
      const int k = k0 + y + 8 * i;
      const int j = j0 + x;
      t[y + 8 * i][x] = (j < 512) ? W1s[(size_t)(F_ + k) * H1_ + j]
                                  : W1e[(size_t)(F_ + k) * H2_ + (j - 512)];
    }
    __syncthreads();
#pragma unroll
    for (int i = 0; i < 4; ++i) {
      const int j = j0 + y + 8 * i;
      const int k = k0 + x;
      const float v = t[x][y + 8 * i];
      const unsigned short h = f2bf(v);
      if (j < 512) {
        B1hi[(size_t)j * 1024 + k] = h;
        B1lo[(size_t)j * 1024 + k] = f2bf(v - bf2f(h));
      } else {
        B2hi[(size_t)(j - 512) * 1024 + k] = h;
      }
    }
  } else {  // init
    const int idx = (blk - 8960) * 256 + tid;
    if (idx < 32 * 2560) {
      const int b = idx / 2560, j = idx - b * 2560;
      if (j < 512) q1b[b * 512 + j] = b1s[j];
      else if (j < 768) q2b[b * 256 + (j - 512)] = b1e[j - 512];
      else if (j < 1280) v1h[b * 512 + (j - 768)] = bv1[j - 768];
      else if (j < 1792) m1h[b * 512 + (j - 1280)] = bm1[j - 1280];
      else hp[b * 768 + (j - 1792)] = bp1[j - 1792];
    } else if (idx < 32 * 2560 + 4128) {
      const int k = idx - 32 * 2560;
      if (k < 4096) wact[k] = 0.f;
      else wres[k - 4096] = 0.f;
    } else {
      const int k = idx - (32 * 2560 + 4128);
      if (k < B_ * ADIM_) out[k] = bp2[k % ADIM_];
    }
  }
}

// ---------- skinny-M fp32 GEMM core: C[32][N] += A[32][64-slice] @ W ----------
__device__ __forceinline__ void skinny32_body(
    const float* __restrict__ A, int lda, int kbase,
    const float* __restrict__ Wp, int ldw, int n0, int N,
    float* __restrict__ C, int ldc, float* __restrict__ lA) {
  const int tid = threadIdx.x;
#pragma unroll
  for (int j = 0; j < 16; ++j) {
    const int idx = j * 128 + tid;
    const int r = idx >> 6, k = idx & 63;
    lA[k * 36 + r] = A[(size_t)r * lda + kbase + k];
  }
  __syncthreads();
  const int c0 = n0 + tid * 2;
  if (c0 >= N) return;
  float acc[32][2];
#pragma unroll
  for (int r = 0; r < 32; ++r) { acc[r][0] = 0.f; acc[r][1] = 0.f; }
  const float* wp = Wp + (size_t)kbase * ldw + c0;
#pragma unroll 2
  for (int k = 0; k < 64; ++k) {
    const float2 w = *(const float2*)&wp[(size_t)k * ldw];
#pragma unroll
    for (int rq = 0; rq < 8; ++rq) {
      const float4 a = *(const float4*)&lA[k * 36 + rq * 4];
      acc[rq * 4 + 0][0] = fmaf(a.x, w.x, acc[rq * 4 + 0][0]);
      acc[rq * 4 + 0][1] = fmaf(a.x, w.y, acc[rq * 4 + 0][1]);
      acc[rq * 4 + 1][0] = fmaf(a.y, w.x, acc[rq * 4 + 1][0]);
      acc[rq * 4 + 1][1] = fmaf(a.y, w.y, acc[rq * 4 + 1][1]);
      acc[rq * 4 + 2][0] = fmaf(a.z, w.x, acc[rq * 4 + 2][0]);
      acc[rq * 4 + 2][1] = fmaf(a.z, w.y, acc[rq * 4 + 2][1]);
      acc[rq * 4 + 3][0] = fmaf(a.w, w.x, acc[rq * 4 + 3][0]);
      acc[rq * 4 + 3][1] = fmaf(a.w, w.y, acc[rq * 4 + 3][1]);
    }
  }
#pragma unroll
  for (int r = 0; r < 32; ++r) {
    atomicAdd(&C[(size_t)r * ldc + c0], acc[r][0]);
    atomicAdd(&C[(size_t)r * ldc + c0 + 1], acc[r][1]);
  }
}

// grid (10, 16): x<7 -> {q1 lo, q1 hi, q2, v1 lo, v1 hi, m1 lo, m1 hi}; x>=7 -> hp
__global__ __launch_bounds__(128) void k_skinny_all(
    const float* __restrict__ features, const float* __restrict__ W1s,
    const float* __restrict__ W1e, const float* __restrict__ Wv1,
    const float* __restrict__ Wm1, const float* __restrict__ Wp1,
    float* __restrict__ q1b, float* __restrict__ q2b, float* __restrict__ v1h,
    float* __restrict__ m1h, float* __restrict__ hp_acc) {
  __shared__ float lA[64 * 36];
  const int t = blockIdx.x;
  const float* Wp; float* Cp; int ldw, n0;
  switch (t) {
    case 0: Wp = W1s; Cp = q1b; ldw = 512; n0 = 0;   break;
    case 1: Wp = W1s; Cp = q1b; ldw = 512; n0 = 256; break;
    case 2: Wp = W1e; Cp = q2b; ldw = 256; n0 = 0;   break;
    case 3: Wp = Wv1; Cp = v1h; ldw = 512; n0 = 0;   break;
    case 4: Wp = Wv1; Cp = v1h; ldw = 512; n0 = 256; break;
    case 5: Wp = Wm1; Cp = m1h; ldw = 512; n0 = 0;   break;
    case 6: Wp = Wm1; Cp = m1h; ldw = 512; n0 = 256; break;
    default: Wp = Wp1; Cp = hp_acc; ldw = PH_; n0 = (t - 7) * 256; break;
  }
  skinny32_body(features, F_, blockIdx.y * 64, Wp, ldw, n0, ldw, Cp, ldw, lA);
}

// grid (19, 12)
__global__ __launch_bounds__(128) void k_skinny_logits(
    const float* __restrict__ hp, const float* __restrict__ Wp2,
    float* __restrict__ out) {
  __shared__ float lA[64 * 36];
  skinny32_body(hp, PH_, blockIdx.y * 64, Wp2, ADIM_, blockIdx.x * 256, ADIM_,
                out, ADIM_, lA);
}

// ---------- fused GEMM, 128x128 tiles, conflict-free XOR-8 swizzled LDS ----------
// LDS tile: 64 lines x 128B; line L holds rows L (k-half 0) and L+64 (k-half 1);
// 16B chunk index c = (half*4 + q) ^ (r&7). Stage: linear LDS dest (GLD16 rule),
// global source pre-swizzled per lane. Reads apply same XOR -> per 16-lane phase
// banks are hit exactly 2x each (2-way aliasing is free, m136).
// grid (64, 6): y<4 -> C1 fp32 (2-term B1), y in {4,5} -> C2 bf16 (1-term B2).
__global__ __launch_bounds__(256) void k_gemmA(
    const unsigned short* __restrict__ Ahi, const unsigned short* __restrict__ B1hi,
    const unsigned short* __restrict__ B1lo, const unsigned short* __restrict__ B2hi,
    float* __restrict__ C1, unsigned short* __restrict__ C2) {
  __shared__ unsigned short lds[12288];  // 24576B: A@0 Bh@8192 Bl@16384
  char* L = (char*)lds;
  const int tid = threadIdx.x;
  const int lane = tid & 63, w = tid >> 6;
  const int m0 = blockIdx.x * 128;
  const int y = blockIdx.y;
  const bool two = (y < 4);
  const int n0 = two ? y * 128 : (y - 4) * 128;
  const unsigned short* Bh = two ? B1hi : B2hi;
  const int wr = w >> 1, wc = w & 1;

  // staging geometry (2 calls of 4KB per 8KB tensor tile):
  // call i: line Li = i*32 + w*8 + (lane>>3); stored chunk = lane&7;
  // linear chunk cl = (lane&7) ^ (Li&7); source row r = Li + 64*(cl>>2), q = cl&3.
  int srow[2], soff[2], sdst[2];
#pragma unroll
  for (int i = 0; i < 2; ++i) {
    const int Li = i * 32 + w * 8 + (lane >> 3);
    const int cl = (lane & 7) ^ (lane >> 3);
    srow[i] = Li + 64 * (cl >> 2);
    soff[i] = (cl & 3) * 8;          // element offset within k-step
    sdst[i] = i * 4096 + tid * 16;   // linear LDS dest
  }
  // fragment read offsets (bytes), per mi/ni; same XOR swizzle
  int roA[4], roB[4];
#pragma unroll
  for (int i = 0; i < 4; ++i) {
    const int Lr = i * 16 + (lane & 15);
    roA[i] = Lr * 128 + (((wr * 4) + (lane >> 4)) ^ (lane & 7)) * 16;
    roB[i] = Lr * 128 + (((wc * 4) + (lane >> 4)) ^ (lane & 7)) * 16;
  }

  v4f acc[4][4];
#pragma unroll
  for (int mi = 0; mi < 4; ++mi)
#pragma unroll
    for (int ni = 0; ni < 4; ++ni) acc[mi][ni] = (v4f)(0.f);

  for (int k0 = 0; k0 < 1024; k0 += 32) {
    __syncthreads();
#pragma unroll
    for (int i = 0; i < 2; ++i) {
      GLD16(Ahi + (size_t)(m0 + srow[i]) * 1024 + k0 + soff[i], L + sdst[i]);
      GLD16(Bh + (size_t)(n0 + srow[i]) * 1024 + k0 + soff[i], L + 8192 + sdst[i]);
      if (two)
        GLD16(B1lo + (size_t)(n0 + srow[i]) * 1024 + k0 + soff[i], L + 16384 + sdst[i]);
    }
    asm volatile("s_waitcnt vmcnt(0)" ::: "memory");
    __syncthreads();
    v8s ah[4], bh[4], bl[4];
#pragma unroll
    for (int mi = 0; mi < 4; ++mi) ah[mi] = *(const v8s*)(L + roA[mi]);
#pragma unroll
    for (int ni = 0; ni < 4; ++ni) {
      bh[ni] = *(const v8s*)(L + 8192 + roB[ni]);
      if (two) bl[ni] = *(const v8s*)(L + 16384 + roB[ni]);
    }
#pragma unroll
    for (int mi = 0; mi < 4; ++mi)
#pragma unroll
      for (int ni = 0; ni < 4; ++ni) {
        acc[mi][ni] = __builtin_amdgcn_mfma_f32_16x16x32_bf16(ah[mi], bh[ni], acc[mi][ni], 0, 0, 0);
        if (two)
          acc[mi][ni] = __builtin_amdgcn_mfma_f32_16x16x32_bf16(ah[mi], bl[ni], acc[mi][ni], 0, 0, 0);
      }
  }
  if (two) {
#pragma unroll
    for (int mi = 0; mi < 4; ++mi)
#pragma unroll
      for (int ni = 0; ni < 4; ++ni)
#pragma unroll
        for (int j = 0; j < 4; ++j) {
          const int mrow = m0 + wr * 64 + mi * 16 + (lane >> 4) * 4 + j;
          const int ncol = n0 + wc * 64 + ni * 16 + (lane & 15);
          C1[(size_t)mrow * 512 + ncol] = acc[mi][ni][j];
        }
  } else {
#pragma unroll
    for (int mi = 0; mi < 4; ++mi)
#pragma unroll
      for (int ni = 0; ni < 4; ++ni)
#pragma unroll
        for (int j = 0; j < 4; ++j) {
          const int mrow = m0 + wr * 64 + mi * 16 + (lane >> 4) * 4 + j;
          const int ncol = n0 + wc * 64 + ni * 16 + (lane & 15);
          C2[(size_t)mrow * 256 + ncol] = f2bf(acc[mi][ni][j]);
        }
  }
}

// ---------- scores: 1024 blocks, 8 k-rows staged in LDS, 1 (b,k) per thread ----------
__global__ __launch_bounds__(256) void k_scores2(
    const float* __restrict__ C1, const float* __restrict__ q1b,
    const float* __restrict__ W2s, const float* __restrict__ b2s,
    float* __restrict__ scores) {
  __shared__ float4 c4[8 * 129];  // row pad 129 f4: 8 rows cover all 32 banks
  __shared__ float4 w4[128];
  const int tid = threadIdx.x;
  const int kbase = blockIdx.x * 8;
#pragma unroll
  for (int p = 0; p < 4; ++p) {
    const int idx = p * 256 + tid;
    const int row = idx >> 7, c = idx & 127;
    c4[row * 129 + c] = *(const float4*)&C1[(size_t)(kbase + row) * 512 + c * 4];
  }
  if (tid < 128) w4[tid] = *(const float4*)&W2s[tid * 4];
  __syncthreads();
  const int b = tid >> 3, ks = tid & 7;
  const float4* qrow = (const float4*)&q1b[b * 512];
  float acc = 0.f;
  for (int i = 0; i < 128; ++i) {
    const float4 c = c4[ks * 129 + i];
    const float4 q = qrow[i];
    const float4 w = w4[i];
    acc += fmaxf(q.x + c.x, 0.f) * w.x + fmaxf(q.y + c.y, 0.f) * w.y +
           fmaxf(q.z + c.z, 0.f) * w.z + fmaxf(q.w + c.w, 0.f) * w.w;
  }
  scores[(size_t)b * K_ + kbase + ks] = acc + b2s[0];
}

// ---------- exact top-1000: 2 full radix passes + candidate-list passes 3/4 ----------
__global__ __launch_bounds__(1024) void k_topk(
    const float* __restrict__ scores, int* __restrict__ topk_idx) {
  __shared__ unsigned key[K_];         // 32 KB (reused as scratch at end)
  __shared__ unsigned whist[16][256];  // 16 KB; [1..15] overlaid by cand list
  __shared__ unsigned sfx[256];
  __shared__ int eqlist[1024];
  __shared__ unsigned ctl[6];  // d, r, n_out, eq_cnt, ncand
  int* cand = (int*)&whist[1][0];      // 3840 entries
  const int NCAND = 3840;
  const int tid = threadIdx.x;
  const int wid = tid >> 6;
  const int b = blockIdx.x;
  const float* row = scores + (size_t)b * K_;

  // pass 1: fused convert + per-wave hist on byte 3
  for (int i = tid; i < 16 * 256; i += 1024) ((unsigned*)whist)[i] = 0;
  __syncthreads();
  for (int i = tid; i < K_; i += 1024) {
    const unsigned u = __float_as_uint(row[i]);
    const unsigned k = (u & 0x80000000u) ? ~u : (u | 0x80000000u);
    key[i] = k;
    atomicAdd(&whist[wid][k >> 24], 1u);
  }
  __syncthreads();
  unsigned prefix = 0;
  int r = TOPK_;
#pragma unroll
  for (int p = 0; p < 2; ++p) {  // passes 1,2 share reduce/select code
    const int shift = 24 - 8 * p;
    if (tid < 256) {
      unsigned s = 0;
#pragma unroll
      for (int ww = 0; ww < 16; ++ww) s += whist[ww][tid];
      sfx[tid] = s;
    }
    __syncthreads();
    for (int off = 1; off < 256; off <<= 1) {
      unsigned v = 0;
      if (tid < 256) { v = sfx[tid]; if (tid + off < 256) v += sfx[tid + off]; }
      __syncthreads();
      if (tid < 256) sfx[tid] = v;
      __syncthreads();
    }
    if (tid < 256) {
      const int Sge = (int)sfx[tid];
      const int Sgt = (tid < 255) ? (int)sfx[tid + 1] : 0;
      if (Sgt < r && r <= Sge) { ctl[0] = (unsigned)tid; ctl[1] = (unsigned)(r - Sgt); }
    }
    __syncthreads();
    prefix |= ctl[0] << shift;
    r = (int)ctl[1];
    __syncthreads();
    if (p == 0) {  // pass 2 hist on byte 2 (full scan)
      for (int i = tid; i < 16 * 256; i += 1024) ((unsigned*)whist)[i] = 0;
      __syncthreads();
      for (int i = tid; i < K_; i += 1024) {
        const unsigned k = key[i];
        if ((k >> 24) == prefix >> 24) atomicAdd(&whist[wid][(k >> 16) & 255u], 1u);
      }
      __syncthreads();
    }
  }
  // append candidates matching 2-byte prefix
  if (tid == 0) ctl[4] = 0;
  __syncthreads();
  for (int i = tid; i < K_; i += 1024) {
    if ((key[i] >> 16) == (prefix >> 16)) {
      const unsigned pos = atomicAdd(&ctl[4], 1u);
      if (pos < (unsigned)NCAND) cand[pos] = i;
    }
  }
  __syncthreads();
  const int ncand = (ctl[4] < (unsigned)NCAND) ? (int)ctl[4] : NCAND;
  const bool ovf = ctl[4] > (unsigned)NCAND;
  // passes 3,4 on candidates (single hist whist[0])
#pragma unroll
  for (int p = 2; p < 4; ++p) {
    const int shift = 24 - 8 * p;
    if (tid < 256) whist[0][tid] = 0;
    __syncthreads();
    if (!ovf) {
      for (int j = tid; j < ncand; j += 1024) {
        const unsigned k = key[cand[j]];
        if (p == 2 || ((k >> 8) << 8 >> 16 == (prefix >> 8) << 8 >> 16)) {
          if (p == 2) atomicAdd(&whist[0][(k >> 8) & 255u], 1u);
          else if ((k & 0xFFFFFF00u) == prefix) atomicAdd(&whist[0][k & 255u], 1u);
        }
      }
    } else {
      const unsigned pmask = 0xFFFFFFFFu << (shift + 8);
      for (int i = tid; i < K_; i += 1024) {
        const unsigned k = key[i];
        if ((k & pmask) == prefix) atomicAdd(&whist[0][(k >> shift) & 255u], 1u);
      }
    }
    __syncthreads();
    if (tid < 256) sfx[tid] = whist[0][tid];
    __syncthreads();
    for (int off = 1; off < 256; off <<= 1) {
      unsigned v = 0;
      if (tid < 256) { v = sfx[tid]; if (tid + off < 256) v += sfx[tid + off]; }
      __syncthreads();
      if (tid < 256) sfx[tid] = v;
      __syncthreads();
    }
    if (tid < 256) {
      const int Sge = (int)sfx[tid];
      const int Sgt = (tid < 255) ? (int)sfx[tid + 1] : 0;
      if (Sgt < r && r <= Sge) { ctl[0] = (unsigned)tid; ctl[1] = (unsigned)(r - Sgt); }
    }
    __syncthreads();
    prefix |= ctl[0] << shift;
    r = (int)ctl[1];
    __syncthreads();
  }
  const unsigned T = prefix;
  const int take_eq = r;
  if (tid == 0) { ctl[2] = 0; ctl[3] = 0; }
  __syncthreads();
  int* outp = topk_idx + b * TOPK_;
  for (int i = tid; i < K_; i += 1024) {
    const unsigned k = key[i];
    if (k > T) outp[atomicAdd(&ctl[2], 1u)] = i;
    else if (k == T) { const unsigned e = atomicAdd(&ctl[3], 1u); if (e < 1024) eqlist[e] = i; }
  }
  __syncthreads();
  const int m = (ctl[3] < 1024u) ? (int)ctl[3] : 1024;
  const int ngt = TOPK_ - take_eq;
  for (int sel = 0; sel < take_eq; ++sel) {
    key[tid] = (tid < m) ? (unsigned)eqlist[tid] : 0xFFFFFFFFu;
    __syncthreads();
    for (int s = 512; s > 0; s >>= 1) {
      if (tid < s) key[tid] = min(key[tid], key[tid + s]);
      __syncthreads();
    }
    const unsigned mn = key[0];
    if (tid < m && (unsigned)eqlist[tid] == mn) eqlist[tid] = 0x7FFFFFFF;
    if (tid == 0) outp[ngt + sel] = (int)mn;
    __syncthreads();
  }
}

// ---------- s2[e] = b2e + sum_j gelu(q2b[b][j] + C2[idx][j]) * W2e[j] ----------
__global__ __launch_bounds__(256) void k_s2(
    const unsigned short* __restrict__ C2, const float* __restrict__ q2b,
    const int* __restrict__ topk_idx, const float* __restrict__ W2e,
    const float* __restrict__ b2e, float* __restrict__ s2) {
  const int tid = threadIdx.x;
  const int ln = tid & 63;
  const int e = blockIdx.x * 4 + (tid >> 6);
  const int b = e / TOPK_;
  const int idx = topk_idx[e];
  const v4u16 kv = *(const v4u16*)(C2 + (size_t)idx * H2_ + ln * 4);
  const float4 qv = *(const float4*)(q2b + b * H2_ + ln * 4);
  float s = gelu_f(qv.x + bf2f(kv[0])) * W2e[ln * 4 + 0]
          + gelu_f(qv.y + bf2f(kv[1])) * W2e[ln * 4 + 1]
          + gelu_f(qv.z + bf2f(kv[2])) * W2e[ln * 4 + 2]
          + gelu_f(qv.w + bf2f(kv[3])) * W2e[ln * 4 + 3];
#pragma unroll
  for (int off = 32; off > 0; off >>= 1) s += __shfl_down(s, off);
  if (ln == 0) s2[e] = s + b2e[0];
}

// ---------- weighted actions/results with inline softmax (8 chunks per b) ----------
// Each of the 8 chunk-blocks recomputes the identical softmax denominator
// (deterministic: same code, same inputs -> bitwise-equal m, sum).
__global__ __launch_bounds__(256) void k_weighted(
    const int* __restrict__ topk_idx, const float* __restrict__ s2,
    const float* __restrict__ memory, float* __restrict__ wact_acc,
    float* __restrict__ wres_acc) {
  __shared__ float ev[TOPK_];
  __shared__ float red[256];
  const int blk = blockIdx.x;
  const int b = blk >> 3, c = blk & 7;
  const int tid = threadIdx.x;
  float m = -3.4e38f;
  for (int t = tid; t < TOPK_; t += 256) m = fmaxf(m, s2[b * TOPK_ + t]);
  red[tid] = m;
  __syncthreads();
  for (int s = 128; s > 0; s >>= 1) {
    if (tid < s) red[tid] = fmaxf(red[tid], red[tid + s]);
    __syncthreads();
  }
  m = red[0];
  __syncthreads();
  float ps = 0.f;
  for (int t = tid; t < TOPK_; t += 256) {
    const float e = expf(s2[b * TOPK_ + t] - m);
    ev[t] = e;
    ps += e;
  }
  red[tid] = ps;
  __syncthreads();
  for (int s = 128; s > 0; s >>= 1) {
    if (tid < s) red[tid] += red[tid + s];
    __syncthreads();
  }
  const float inv = 1.f / red[0];
  __syncthreads();
  const int g = tid >> 7, a = tid & 127;
  float acc = 0.f, accr = 0.f;
  for (int t = c * 125 + g; t < (c + 1) * 125; t += 2) {
    const int idx = topk_idx[b * TOPK_ + t];
    const float wv = ev[t] * inv;
    acc += truncf(memory[(size_t)idx * E_ + F_ + a]) * wv;
    if (a == 0) accr += wv * memory[(size_t)idx * E_ + (E_ - 1)];
  }
  atomicAdd(&wact_acc[b * 128 + a], acc);
  if (a == 0) atomicAdd(&wres_acc[b], accr);
}

// ---------- tail: hp_final (b<32) | value heads+finalize (32..63) | wact copy (64) ----------
__global__ __launch_bounds__(512) void k_tail(
    const float* __restrict__ wact, const float* __restrict__ wres,
    const float* __restrict__ v1h, const float* __restrict__ m1h,
    const float* __restrict__ Wv2, const float* __restrict__ bv2,
    const float* __restrict__ Wm2, const float* __restrict__ bm2,
    const float* __restrict__ Wp1, float* __restrict__ hp,
    float* __restrict__ out) {
  const int blk = blockIdx.x, tid = threadIdx.x;
  if (blk < 32) {  // hp += wact @ Wp1b, gelu
    __shared__ float lw[128];
    if (tid < 128) lw[tid] = wact[blk * 128 + tid];
    __syncthreads();
    for (int j = tid; j < PH_; j += 512) {
      float acc = hp[blk * PH_ + j];
      const float* wp = Wp1 + (size_t)F_ * PH_ + j;
#pragma unroll 4
      for (int h = 0; h < 128; ++h) acc = fmaf(lw[h], wp[(size_t)h * PH_], acc);
      hp[blk * PH_ + j] = gelu_f(acc);
    }
  } else if (blk < 64) {  // value heads + value_output
    const int b = blk - 32;
    __shared__ float red[512];
    red[tid] = gelu_f(v1h[b * 512 + tid]) * Wv2[tid];
    __syncthreads();
    for (int s = 256; s > 0; s >>= 1) {
      if (tid < s) red[tid] += red[tid + s];
      __syncthreads();
    }
    if (tid == 0) red[0] = tanhf(red[0] + bv2[0]);
    __syncthreads();
    const float bv = red[0];
    __syncthreads();
    red[tid] = gelu_f(m1h[b * 512 + tid]) * Wm2[tid];
    __syncthreads();
    for (int s = 256; s > 0; s >>= 1) {
      if (tid < s) red[tid] += red[tid + s];
      __syncthreads();
    }
    if (tid == 0) {
      const float aw = 1.f / (1.f + expf(-(red[0] + bm2[0])));
      out[OFF_BV + b] = bv;
      out[OFF_VAL + b] = aw * wres[b] + (1.f - aw) * bv;
      out[OFF_WRES + b] = wres[b];
    }
  } else {  // wact copy
#pragma unroll
    for (int i = 0; i < 8; ++i) out[OFF_WACT + i * 512 + tid] = wact[i * 512 + tid];
  }
}

extern "C" void kernel_launch(void* const* d_in, const int* in_sizes, int n_in,
                              void* d_out, int out_size, void* d_ws,
                              size_t ws_size, hipStream_t stream) {
  (void)in_sizes; (void)n_in; (void)out_size; (void)ws_size;
  const float* features = (const float*)d_in[0];
  const float* memory   = (const float*)d_in[1];
  const float* W1s = (const float*)d_in[2];
  const float* b1s = (const float*)d_in[3];
  const float* W2s = (const float*)d_in[4];
  const float* b2s = (const float*)d_in[5];
  const float* W1e = (const float*)d_in[6];
  const float* b1e = (const float*)d_in[7];
  const float* W2e = (const float*)d_in[8];
  const float* b2e = (const float*)d_in[9];
  const float* Wp1 = (const float*)d_in[10];
  const float* bp1 = (const float*)d_in[11];
  const float* Wp2 = (const float*)d_in[12];
  const float* bp2 = (const float*)d_in[13];
  const float* Wv1 = (const float*)d_in[14];
  const float* bv1 = (const float*)d_in[15];
  const float* Wv2 = (const float*)d_in[16];
  const float* bv2 = (const float*)d_in[17];
  const float* Wm1 = (const float*)d_in[18];
  const float* bm1 = (const float*)d_in[19];
  const float* Wm2 = (const float*)d_in[20];
  const float* bm2 = (const float*)d_in[21];
  float* out = (float*)d_out;

  // workspace layout (bytes)
  char* W = (char*)d_ws;
  unsigned short* Ahi  = (unsigned short*)(W);                      // 16 MB
  unsigned short* B1hi = (unsigned short*)(W + (16u << 20));        // 1 MB
  unsigned short* B1lo = (unsigned short*)(W + (17u << 20));        // 1 MB
  unsigned short* B2hi = (unsigned short*)(W + (18u << 20));        // 0.5 MB
  float*          C1   = (float*)(W + (19u << 20));                 // 16 MB
  unsigned short* C2   = (unsigned short*)(W + (35u << 20));        // 4 MB
  float*          scores = (float*)(W + (39u << 20));               // 1 MB
  char* S = W + (40u << 20);
  float* q1b      = (float*)(S);               // 64 KB
  float* q2b      = (float*)(S + 65536);       // 32 KB
  float* s2       = (float*)(S + 98304);       // 125 KB
  int*   topk     = (int*)  (S + 354304);      // 125 KB
  float* wact_acc = (float*)(S + 482304);      // 16 KB
  float* wres_acc = (float*)(S + 498688);      // 128 B
  float* hp_acc   = (float*)(S + 498944);      // 96 KB
  float* v1h      = (float*)(S + 597248);      // 64 KB
  float* m1h      = (float*)(S + 662784);      // 64 KB

  k_prep<<<9881, 256, 0, stream>>>(memory, W1s, W1e, b1s, b1e, bv1, bm1, bp1,
                                   bp2, Ahi, B1hi, B1lo, B2hi, q1b, q2b, v1h,
                                   m1h, hp_acc, wact_acc, wres_acc, out);
  k_skinny_all<<<dim3(10, 16), 128, 0, stream>>>(features, W1s, W1e, Wv1, Wm1,
                                                 Wp1, q1b, q2b, v1h, m1h, hp_acc);
  k_gemmA<<<dim3(64, 6), 256, 0, stream>>>(Ahi, B1hi, B1lo, B2hi, C1, C2);
  k_scores2<<<1024, 256, 0, stream>>>(C1, q1b, W2s, b2s, scores);
  k_topk<<<32, 1024, 0, stream>>>(scores, topk);
  k_s2<<<8000, 256, 0, stream>>>(C2, q2b, topk, W2e, b2e, s2);
  k_weighted<<<256, 256, 0, stream>>>(topk, s2, memory, wact_acc, wres_acc);
  k_tail<<<65, 512, 0, stream>>>(wact_acc, wres_acc, v1h, m1h, Wv2, bv2, Wm2,
                                 bm2, Wp1, hp_acc, out);
  k_skinny_logits<<<dim3(19, 12), 128, 0, stream>>>(hp_acc, Wp2, out);
}

// Round 10
// 318.461 us; speedup vs baseline: 2.3631x; 1.0198x over previous
//
#include <hip/hip_runtime.h>
#include <math.h>

#define B_ 32
#define K_ 8192
#define TOPK_ 1000
#define F_ 1024
#define E_ 1153
#define H1_ 512
#define H2_ 256
#define PH_ 768
#define ADIM_ 4672

// output layout (floats): logits | board_vals | value | wact | wres
#define OFF_BV   149504
#define OFF_VAL  149536
#define OFF_WACT 149568
#define OFF_WRES 153664

typedef __attribute__((ext_vector_type(8))) short v8s;
typedef __attribute__((ext_vector_type(4))) float v4f;
typedef __attribute__((ext_vector_type(4))) unsigned short v4u16;

#define GLD16(gp, lp) __builtin_amdgcn_global_load_lds( \
    (const __attribute__((address_space(1))) void*)(gp), \
    (__attribute__((address_space(3))) void*)(lp), 16, 0, 0)

__device__ __forceinline__ float gelu_f(float x) {
  return 0.5f * x * (1.0f + erff(x * 0.70710678118654752440f));
}
__device__ __forceinline__ unsigned short f2bf(float x) {
  union { float f; unsigned u; } v; v.f = x;
  unsigned r = v.u + 0x7fffu + ((v.u >> 16) & 1u);
  return (unsigned short)(r >> 16);
}
__device__ __forceinline__ float bf2f(unsigned short h) {
  union { unsigned u; float f; } v; v.u = ((unsigned)h) << 16; return v.f;
}

// ---------- merged prep: split_mem | split_w | init (branch on blockIdx) ----------
__global__ __launch_bounds__(256) void k_prep(
    const float* __restrict__ memory, const float* __restrict__ W1s,
    const float* __restrict__ W1e, const float* __restrict__ b1s,
    const float* __restrict__ b1e, const float* __restrict__ bv1,
    const float* __restrict__ bm1, const float* __restrict__ bp1,
    const float* __restrict__ bp2, unsigned short* __restrict__ Ahi,
    unsigned short* __restrict__ B1hi, unsigned short* __restrict__ B1lo,
    unsigned short* __restrict__ B2hi, float* __restrict__ q1b,
    float* __restrict__ q2b, float* __restrict__ v1h, float* __restrict__ m1h,
    float* __restrict__ hp, float* __restrict__ wact, float* __restrict__ wres,
    float* __restrict__ out) {
  const int blk = blockIdx.x;
  const int tid = threadIdx.x;
  if (blk < 8192) {  // split_mem: row blk
    const float* src = memory + (size_t)blk * E_ + 4 * tid;
    unsigned* dst = (unsigned*)(Ahi + (size_t)blk * 1024);
    const float x0 = src[0], x1 = src[1], x2 = src[2], x3 = src[3];
    dst[2 * tid]     = (unsigned)f2bf(x0) | ((unsigned)f2bf(x1) << 16);
    dst[2 * tid + 1] = (unsigned)f2bf(x2) | ((unsigned)f2bf(x3) << 16);
  } else if (blk < 8960) {  // split_w
    __shared__ float t[32][33];
    const int blk2 = blk - 8192;
    const int x = tid & 31, y = tid >> 5;  // 32 x 8
    const int j0 = (blk2 % 24) * 32, k0 = (blk2 / 24) * 32;
#pragma unroll
    for (int i = 0; i < 4; ++i) {
      const int k = k0 + y + 8 * i;
      const int j = j0 + x;
      t[y + 8 * i][x] = (j < 512) ? W1s[(size_t)(F_ + k) * H1_ + j]
                                  : W1e[(size_t)(F_ + k) * H2_ + (j - 512)];
    }
    __syncthreads();
#pragma unroll
    for (int i = 0; i < 4; ++i) {
      const int j = j0 + y + 8 * i;
      const int k = k0 + x;
      const float v = t[x][y + 8 * i];
      const unsigned short h = f2bf(v);
      if (j < 512) {
        B1hi[(size_t)j * 1024 + k] = h;
        B1lo[(size_t)j * 1024 + k] = f2bf(v - bf2f(h));
      } else {
        B2hi[(size_t)(j - 512) * 1024 + k] = h;
      }
    }
  } else {  // init
    const int idx = (blk - 8960) * 256 + tid;
    if (idx < 32 * 2560) {
      const int b = idx / 2560, j = idx - b * 2560;
      if (j < 512) q1b[b * 512 + j] = b1s[j];
      else if (j < 768) q2b[b * 256 + (j - 512)] = b1e[j - 512];
      else if (j < 1280) v1h[b * 512 + (j - 768)] = bv1[j - 768];
      else if (j < 1792) m1h[b * 512 + (j - 1280)] = bm1[j - 1280];
      else hp[b * 768 + (j - 1792)] = bp1[j - 1792];
    } else if (idx < 32 * 2560 + 4128) {
      const int k = idx - 32 * 2560;
      if (k < 4096) wact[k] = 0.f;
      else wres[k - 4096] = 0.f;
    } else {
      const int k = idx - (32 * 2560 + 4128);
      if (k < B_ * ADIM_) out[k] = bp2[k % ADIM_];
    }
  }
}

// ---------- skinny-M fp32 GEMM core: C[32][N] += A[32][64-slice] @ W ----------
__device__ __forceinline__ void skinny32_body(
    const float* __restrict__ A, int lda, int kbase,
    const float* __restrict__ Wp, int ldw, int n0, int N,
    float* __restrict__ C, int ldc, float* __restrict__ lA) {
  const int tid = threadIdx.x;
#pragma unroll
  for (int j = 0; j < 16; ++j) {
    const int idx = j * 128 + tid;
    const int r = idx >> 6, k = idx & 63;
    lA[k * 36 + r] = A[(size_t)r * lda + kbase + k];
  }
  __syncthreads();
  const int c0 = n0 + tid * 2;
  if (c0 >= N) return;
  float acc[32][2];
#pragma unroll
  for (int r = 0; r < 32; ++r) { acc[r][0] = 0.f; acc[r][1] = 0.f; }
  const float* wp = Wp + (size_t)kbase * ldw + c0;
#pragma unroll 2
  for (int k = 0; k < 64; ++k) {
    const float2 w = *(const float2*)&wp[(size_t)k * ldw];
#pragma unroll
    for (int rq = 0; rq < 8; ++rq) {
      const float4 a = *(const float4*)&lA[k * 36 + rq * 4];
      acc[rq * 4 + 0][0] = fmaf(a.x, w.x, acc[rq * 4 + 0][0]);
      acc[rq * 4 + 0][1] = fmaf(a.x, w.y, acc[rq * 4 + 0][1]);
      acc[rq * 4 + 1][0] = fmaf(a.y, w.x, acc[rq * 4 + 1][0]);
      acc[rq * 4 + 1][1] = fmaf(a.y, w.y, acc[rq * 4 + 1][1]);
      acc[rq * 4 + 2][0] = fmaf(a.z, w.x, acc[rq * 4 + 2][0]);
      acc[rq * 4 + 2][1] = fmaf(a.z, w.y, acc[rq * 4 + 2][1]);
      acc[rq * 4 + 3][0] = fmaf(a.w, w.x, acc[rq * 4 + 3][0]);
      acc[rq * 4 + 3][1] = fmaf(a.w, w.y, acc[rq * 4 + 3][1]);
    }
  }
#pragma unroll
  for (int r = 0; r < 32; ++r) {
    atomicAdd(&C[(size_t)r * ldc + c0], acc[r][0]);
    atomicAdd(&C[(size_t)r * ldc + c0 + 1], acc[r][1]);
  }
}

// grid (10, 16): x<7 -> {q1 lo, q1 hi, q2, v1 lo, v1 hi, m1 lo, m1 hi}; x>=7 -> hp
__global__ __launch_bounds__(128) void k_skinny_all(
    const float* __restrict__ features, const float* __restrict__ W1s,
    const float* __restrict__ W1e, const float* __restrict__ Wv1,
    const float* __restrict__ Wm1, const float* __restrict__ Wp1,
    float* __restrict__ q1b, float* __restrict__ q2b, float* __restrict__ v1h,
    float* __restrict__ m1h, float* __restrict__ hp_acc) {
  __shared__ float lA[64 * 36];
  const int t = blockIdx.x;
  const float* Wp; float* Cp; int ldw, n0;
  switch (t) {
    case 0: Wp = W1s; Cp = q1b; ldw = 512; n0 = 0;   break;
    case 1: Wp = W1s; Cp = q1b; ldw = 512; n0 = 256; break;
    case 2: Wp = W1e; Cp = q2b; ldw = 256; n0 = 0;   break;
    case 3: Wp = Wv1; Cp = v1h; ldw = 512; n0 = 0;   break;
    case 4: Wp = Wv1; Cp = v1h; ldw = 512; n0 = 256; break;
    case 5: Wp = Wm1; Cp = m1h; ldw = 512; n0 = 0;   break;
    case 6: Wp = Wm1; Cp = m1h; ldw = 512; n0 = 256; break;
    default: Wp = Wp1; Cp = hp_acc; ldw = PH_; n0 = (t - 7) * 256; break;
  }
  skinny32_body(features, F_, blockIdx.y * 64, Wp, ldw, n0, ldw, Cp, ldw, lA);
}

// grid (19, 12)
__global__ __launch_bounds__(128) void k_skinny_logits(
    const float* __restrict__ hp, const float* __restrict__ Wp2,
    float* __restrict__ out) {
  __shared__ float lA[64 * 36];
  skinny32_body(hp, PH_, blockIdx.y * 64, Wp2, ADIM_, blockIdx.x * 256, ADIM_,
                out, ADIM_, lA);
}

// ---------- fused GEMM, 128x128 tiles, XOR-8 swizzled LDS, 2-phase double-buffer ----------
// Per iter: STAGE(next tile into buf^1) issued FIRST, then ds_read+MFMA on buf[cur],
// then one barrier (drains the in-flight loads AFTER compute hid their latency).
// grid (64, 6): y<4 -> C1 fp32 (2-term B1), y in {4,5} -> C2 bf16 (1-term B2).
__global__ __launch_bounds__(256) void k_gemmA(
    const unsigned short* __restrict__ Ahi, const unsigned short* __restrict__ B1hi,
    const unsigned short* __restrict__ B1lo, const unsigned short* __restrict__ B2hi,
    float* __restrict__ C1, unsigned short* __restrict__ C2) {
  __shared__ unsigned short lds[24576];  // 49152B: 2 buffers x {A@0 Bh@8192 Bl@16384}
  char* L = (char*)lds;
  const int tid = threadIdx.x;
  const int lane = tid & 63, w = tid >> 6;
  const int m0 = blockIdx.x * 128;
  const int y = blockIdx.y;
  const bool two = (y < 4);
  const int n0 = two ? y * 128 : (y - 4) * 128;
  const unsigned short* Bh = two ? B1hi : B2hi;
  const int wr = w >> 1, wc = w & 1;

  // staging geometry (2 calls of 4KB per 8KB tensor tile):
  // call i: line Li = i*32 + w*8 + (lane>>3); stored chunk = lane&7;
  // linear chunk cl = (lane&7) ^ (Li&7); source row r = Li + 64*(cl>>2), q = cl&3.
  int srow[2], soff[2], sdst[2];
#pragma unroll
  for (int i = 0; i < 2; ++i) {
    const int Li = i * 32 + w * 8 + (lane >> 3);
    const int cl = (lane & 7) ^ (lane >> 3);
    srow[i] = Li + 64 * (cl >> 2);
    soff[i] = (cl & 3) * 8;          // element offset within k-step
    sdst[i] = i * 4096 + tid * 16;   // linear LDS dest
  }
  // fragment read offsets (bytes), per mi/ni; same XOR swizzle
  int roA[4], roB[4];
#pragma unroll
  for (int i = 0; i < 4; ++i) {
    const int Lr = i * 16 + (lane & 15);
    roA[i] = Lr * 128 + (((wr * 4) + (lane >> 4)) ^ (lane & 7)) * 16;
    roB[i] = Lr * 128 + (((wc * 4) + (lane >> 4)) ^ (lane & 7)) * 16;
  }

  v4f acc[4][4];
#pragma unroll
  for (int mi = 0; mi < 4; ++mi)
#pragma unroll
    for (int ni = 0; ni < 4; ++ni) acc[mi][ni] = (v4f)(0.f);

#define STAGE_T(koff, bo)                                                      \
  {                                                                            \
    _Pragma("unroll") for (int i = 0; i < 2; ++i) {                            \
      GLD16(Ahi + (size_t)(m0 + srow[i]) * 1024 + (koff) + soff[i],            \
            L + (bo) + sdst[i]);                                               \
      GLD16(Bh + (size_t)(n0 + srow[i]) * 1024 + (koff) + soff[i],             \
            L + (bo) + 8192 + sdst[i]);                                        \
      if (two)                                                                 \
        GLD16(B1lo + (size_t)(n0 + srow[i]) * 1024 + (koff) + soff[i],         \
              L + (bo) + 16384 + sdst[i]);                                     \
    }                                                                          \
  }

  // prologue: fill buffer 0
  STAGE_T(0, 0);
  asm volatile("s_waitcnt vmcnt(0)" ::: "memory");
  __syncthreads();

  int cur = 0;
  for (int k0 = 0; k0 < 1024; k0 += 32) {
    const int nxt = cur ^ 1;
    if (k0 + 32 < 1024) STAGE_T(k0 + 32, nxt * 24576);  // issue next-tile loads
    const int bo = cur * 24576;
    v8s ah[4], bh[4], bl[4];
#pragma unroll
    for (int mi = 0; mi < 4; ++mi) ah[mi] = *(const v8s*)(L + bo + roA[mi]);
#pragma unroll
    for (int ni = 0; ni < 4; ++ni) {
      bh[ni] = *(const v8s*)(L + bo + 8192 + roB[ni]);
      if (two) bl[ni] = *(const v8s*)(L + bo + 16384 + roB[ni]);
    }
#pragma unroll
    for (int mi = 0; mi < 4; ++mi)
#pragma unroll
      for (int ni = 0; ni < 4; ++ni) {
        acc[mi][ni] = __builtin_amdgcn_mfma_f32_16x16x32_bf16(ah[mi], bh[ni], acc[mi][ni], 0, 0, 0);
        if (two)
          acc[mi][ni] = __builtin_amdgcn_mfma_f32_16x16x32_bf16(ah[mi], bl[ni], acc[mi][ni], 0, 0, 0);
      }
    __syncthreads();  // drains next-tile loads (latency hidden under the MFMAs)
    cur = nxt;
  }
#undef STAGE_T

  if (two) {
#pragma unroll
    for (int mi = 0; mi < 4; ++mi)
#pragma unroll
      for (int ni = 0; ni < 4; ++ni)
#pragma unroll
        for (int j = 0; j < 4; ++j) {
          const int mrow = m0 + wr * 64 + mi * 16 + (lane >> 4) * 4 + j;
          const int ncol = n0 + wc * 64 + ni * 16 + (lane & 15);
          C1[(size_t)mrow * 512 + ncol] = acc[mi][ni][j];
        }
  } else {
#pragma unroll
    for (int mi = 0; mi < 4; ++mi)
#pragma unroll
      for (int ni = 0; ni < 4; ++ni)
#pragma unroll
        for (int j = 0; j < 4; ++j) {
          const int mrow = m0 + wr * 64 + mi * 16 + (lane >> 4) * 4 + j;
          const int ncol = n0 + wc * 64 + ni * 16 + (lane & 15);
          C2[(size_t)mrow * 256 + ncol] = f2bf(acc[mi][ni][j]);
        }
  }
}

// ---------- scores: 1024 blocks, 8 k-rows staged in LDS, 1 (b,k) per thread ----------
__global__ __launch_bounds__(256) void k_scores2(
    const float* __restrict__ C1, const float* __restrict__ q1b,
    const float* __restrict__ W2s, const float* __restrict__ b2s,
    float* __restrict__ scores) {
  __shared__ float4 c4[8 * 129];  // row pad 129 f4: 8 rows cover all 32 banks
  __shared__ float4 w4[128];
  const int tid = threadIdx.x;
  const int kbase = blockIdx.x * 8;
#pragma unroll
  for (int p = 0; p < 4; ++p) {
    const int idx = p * 256 + tid;
    const int row = idx >> 7, c = idx & 127;
    c4[row * 129 + c] = *(const float4*)&C1[(size_t)(kbase + row) * 512 + c * 4];
  }
  if (tid < 128) w4[tid] = *(const float4*)&W2s[tid * 4];
  __syncthreads();
  const int b = tid >> 3, ks = tid & 7;
  const float4* qrow = (const float4*)&q1b[b * 512];
  float acc = 0.f;
  for (int i = 0; i < 128; ++i) {
    const float4 c = c4[ks * 129 + i];
    const float4 q = qrow[i];
    const float4 w = w4[i];
    acc += fmaxf(q.x + c.x, 0.f) * w.x + fmaxf(q.y + c.y, 0.f) * w.y +
           fmaxf(q.z + c.z, 0.f) * w.z + fmaxf(q.w + c.w, 0.f) * w.w;
  }
  scores[(size_t)b * K_ + kbase + ks] = acc + b2s[0];
}

// ---------- exact top-1000: 2 full radix passes + candidate-list passes 3/4 ----------
__global__ __launch_bounds__(1024) void k_topk(
    const float* __restrict__ scores, int* __restrict__ topk_idx) {
  __shared__ unsigned key[K_];         // 32 KB (reused as scratch at end)
  __shared__ unsigned whist[16][256];  // 16 KB; [1..15] overlaid by cand list
  __shared__ unsigned sfx[256];
  __shared__ int eqlist[1024];
  __shared__ unsigned ctl[6];  // d, r, n_out, eq_cnt, ncand
  int* cand = (int*)&whist[1][0];      // 3840 entries
  const int NCAND = 3840;
  const int tid = threadIdx.x;
  const int wid = tid >> 6;
  const int b = blockIdx.x;
  const float* row = scores + (size_t)b * K_;

  // pass 1: fused convert + per-wave hist on byte 3
  for (int i = tid; i < 16 * 256; i += 1024) ((unsigned*)whist)[i] = 0;
  __syncthreads();
  for (int i = tid; i < K_; i += 1024) {
    const unsigned u = __float_as_uint(row[i]);
    const unsigned k = (u & 0x80000000u) ? ~u : (u | 0x80000000u);
    key[i] = k;
    atomicAdd(&whist[wid][k >> 24], 1u);
  }
  __syncthreads();
  unsigned prefix = 0;
  int r = TOPK_;
#pragma unroll
  for (int p = 0; p < 2; ++p) {  // passes 1,2 share reduce/select code
    const int shift = 24 - 8 * p;
    if (tid < 256) {
      unsigned s = 0;
#pragma unroll
      for (int ww = 0; ww < 16; ++ww) s += whist[ww][tid];
      sfx[tid] = s;
    }
    __syncthreads();
    for (int off = 1; off < 256; off <<= 1) {
      unsigned v = 0;
      if (tid < 256) { v = sfx[tid]; if (tid + off < 256) v += sfx[tid + off]; }
      __syncthreads();
      if (tid < 256) sfx[tid] = v;
      __syncthreads();
    }
    if (tid < 256) {
      const int Sge = (int)sfx[tid];
      const int Sgt = (tid < 255) ? (int)sfx[tid + 1] : 0;
      if (Sgt < r && r <= Sge) { ctl[0] = (unsigned)tid; ctl[1] = (unsigned)(r - Sgt); }
    }
    __syncthreads();
    prefix |= ctl[0] << shift;
    r = (int)ctl[1];
    __syncthreads();
    if (p == 0) {  // pass 2 hist on byte 2 (full scan)
      for (int i = tid; i < 16 * 256; i += 1024) ((unsigned*)whist)[i] = 0;
      __syncthreads();
      for (int i = tid; i < K_; i += 1024) {
        const unsigned k = key[i];
        if ((k >> 24) == prefix >> 24) atomicAdd(&whist[wid][(k >> 16) & 255u], 1u);
      }
      __syncthreads();
    }
  }
  // append candidates matching 2-byte prefix
  if (tid == 0) ctl[4] = 0;
  __syncthreads();
  for (int i = tid; i < K_; i += 1024) {
    if ((key[i] >> 16) == (prefix >> 16)) {
      const unsigned pos = atomicAdd(&ctl[4], 1u);
      if (pos < (unsigned)NCAND) cand[pos] = i;
    }
  }
  __syncthreads();
  const int ncand = (ctl[4] < (unsigned)NCAND) ? (int)ctl[4] : NCAND;
  const bool ovf = ctl[4] > (unsigned)NCAND;
  // passes 3,4 on candidates (single hist whist[0])
#pragma unroll
  for (int p = 2; p < 4; ++p) {
    const int shift = 24 - 8 * p;
    if (tid < 256) whist[0][tid] = 0;
    __syncthreads();
    if (!ovf) {
      for (int j = tid; j < ncand; j += 1024) {
        const unsigned k = key[cand[j]];
        if (p == 2 || ((k >> 8) << 8 >> 16 == (prefix >> 8) << 8 >> 16)) {
          if (p == 2) atomicAdd(&whist[0][(k >> 8) & 255u], 1u);
          else if ((k & 0xFFFFFF00u) == prefix) atomicAdd(&whist[0][k & 255u], 1u);
        }
      }
    } else {
      const unsigned pmask = 0xFFFFFFFFu << (shift + 8);
      for (int i = tid; i < K_; i += 1024) {
        const unsigned k = key[i];
        if ((k & pmask) == prefix) atomicAdd(&whist[0][(k >> shift) & 255u], 1u);
      }
    }
    __syncthreads();
    if (tid < 256) sfx[tid] = whist[0][tid];
    __syncthreads();
    for (int off = 1; off < 256; off <<= 1) {
      unsigned v = 0;
      if (tid < 256) { v = sfx[tid]; if (tid + off < 256) v += sfx[tid + off]; }
      __syncthreads();
      if (tid < 256) sfx[tid] = v;
      __syncthreads();
    }
    if (tid < 256) {
      const int Sge = (int)sfx[tid];
      const int Sgt = (tid < 255) ? (int)sfx[tid + 1] : 0;
      if (Sgt < r && r <= Sge) { ctl[0] = (unsigned)tid; ctl[1] = (unsigned)(r - Sgt); }
    }
    __syncthreads();
    prefix |= ctl[0] << shift;
    r = (int)ctl[1];
    __syncthreads();
  }
  const unsigned T = prefix;
  const int take_eq = r;
  if (tid == 0) { ctl[2] = 0; ctl[3] = 0; }
  __syncthreads();
  int* outp = topk_idx + b * TOPK_;
  for (int i = tid; i < K_; i += 1024) {
    const unsigned k = key[i];
    if (k > T) outp[atomicAdd(&ctl[2], 1u)] = i;
    else if (k == T) { const unsigned e = atomicAdd(&ctl[3], 1u); if (e < 1024) eqlist[e] = i; }
  }
  __syncthreads();
  const int m = (ctl[3] < 1024u) ? (int)ctl[3] : 1024;
  const int ngt = TOPK_ - take_eq;
  for (int sel = 0; sel < take_eq; ++sel) {
    key[tid] = (tid < m) ? (unsigned)eqlist[tid] : 0xFFFFFFFFu;
    __syncthreads();
    for (int s = 512; s > 0; s >>= 1) {
      if (tid < s) key[tid] = min(key[tid], key[tid + s]);
      __syncthreads();
    }
    const unsigned mn = key[0];
    if (tid < m && (unsigned)eqlist[tid] == mn) eqlist[tid] = 0x7FFFFFFF;
    if (tid == 0) outp[ngt + sel] = (int)mn;
    __syncthreads();
  }
}

// ---------- s2[e] = b2e + sum_j gelu(q2b[b][j] + C2[idx][j]) * W2e[j] ----------
__global__ __launch_bounds__(256) void k_s2(
    const unsigned short* __restrict__ C2, const float* __restrict__ q2b,
    const int* __restrict__ topk_idx, const float* __restrict__ W2e,
    const float* __restrict__ b2e, float* __restrict__ s2) {
  const int tid = threadIdx.x;
  const int ln = tid & 63;
  const int e = blockIdx.x * 4 + (tid >> 6);
  const int b = e / TOPK_;
  const int idx = topk_idx[e];
  const v4u16 kv = *(const v4u16*)(C2 + (size_t)idx * H2_ + ln * 4);
  const float4 qv = *(const float4*)(q2b + b * H2_ + ln * 4);
  float s = gelu_f(qv.x + bf2f(kv[0])) * W2e[ln * 4 + 0]
          + gelu_f(qv.y + bf2f(kv[1])) * W2e[ln * 4 + 1]
          + gelu_f(qv.z + bf2f(kv[2])) * W2e[ln * 4 + 2]
          + gelu_f(qv.w + bf2f(kv[3])) * W2e[ln * 4 + 3];
#pragma unroll
  for (int off = 32; off > 0; off >>= 1) s += __shfl_down(s, off);
  if (ln == 0) s2[e] = s + b2e[0];
}

// ---------- weighted actions/results with inline softmax (8 chunks per b) ----------
// Each of the 8 chunk-blocks recomputes the identical softmax denominator
// (deterministic: same code, same inputs -> bitwise-equal m, sum).
__global__ __launch_bounds__(256) void k_weighted(
    const int* __restrict__ topk_idx, const float* __restrict__ s2,
    const float* __restrict__ memory, float* __restrict__ wact_acc,
    float* __restrict__ wres_acc) {
  __shared__ float ev[TOPK_];
  __shared__ float red[256];
  const int blk = blockIdx.x;
  const int b = blk >> 3, c = blk & 7;
  const int tid = threadIdx.x;
  float m = -3.4e38f;
  for (int t = tid; t < TOPK_; t += 256) m = fmaxf(m, s2[b * TOPK_ + t]);
  red[tid] = m;
  __syncthreads();
  for (int s = 128; s > 0; s >>= 1) {
    if (tid < s) red[tid] = fmaxf(red[tid], red[tid + s]);
    __syncthreads();
  }
  m = red[0];
  __syncthreads();
  float ps = 0.f;
  for (int t = tid; t < TOPK_; t += 256) {
    const float e = expf(s2[b * TOPK_ + t] - m);
    ev[t] = e;
    ps += e;
  }
  red[tid] = ps;
  __syncthreads();
  for (int s = 128; s > 0; s >>= 1) {
    if (tid < s) red[tid] += red[tid + s];
    __syncthreads();
  }
  const float inv = 1.f / red[0];
  __syncthreads();
  const int g = tid >> 7, a = tid & 127;
  float acc = 0.f, accr = 0.f;
  for (int t = c * 125 + g; t < (c + 1) * 125; t += 2) {
    const int idx = topk_idx[b * TOPK_ + t];
    const float wv = ev[t] * inv;
    acc += truncf(memory[(size_t)idx * E_ + F_ + a]) * wv;
    if (a == 0) accr += wv * memory[(size_t)idx * E_ + (E_ - 1)];
  }
  atomicAdd(&wact_acc[b * 128 + a], acc);
  if (a == 0) atomicAdd(&wres_acc[b], accr);
}

// ---------- tail: hp_final (b<32) | value heads+finalize (32..63) | wact copy (64) ----------
__global__ __launch_bounds__(512) void k_tail(
    const float* __restrict__ wact, const float* __restrict__ wres,
    const float* __restrict__ v1h, const float* __restrict__ m1h,
    const float* __restrict__ Wv2, const float* __restrict__ bv2,
    const float* __restrict__ Wm2, const float* __restrict__ bm2,
    const float* __restrict__ Wp1, float* __restrict__ hp,
    float* __restrict__ out) {
  const int blk = blockIdx.x, tid = threadIdx.x;
  if (blk < 32) {  // hp += wact @ Wp1b, gelu
    __shared__ float lw[128];
    if (tid < 128) lw[tid] = wact[blk * 128 + tid];
    __syncthreads();
    for (int j = tid; j < PH_; j += 512) {
      float acc = hp[blk * PH_ + j];
      const float* wp = Wp1 + (size_t)F_ * PH_ + j;
#pragma unroll 4
      for (int h = 0; h < 128; ++h) acc = fmaf(lw[h], wp[(size_t)h * PH_], acc);
      hp[blk * PH_ + j] = gelu_f(acc);
    }
  } else if (blk < 64) {  // value heads + value_output
    const int b = blk - 32;
    __shared__ float red[512];
    red[tid] = gelu_f(v1h[b * 512 + tid]) * Wv2[tid];
    __syncthreads();
    for (int s = 256; s > 0; s >>= 1) {
      if (tid < s) red[tid] += red[tid + s];
      __syncthreads();
    }
    if (tid == 0) red[0] = tanhf(red[0] + bv2[0]);
    __syncthreads();
    const float bv = red[0];
    __syncthreads();
    red[tid] = gelu_f(m1h[b * 512 + tid]) * Wm2[tid];
    __syncthreads();
    for (int s = 256; s > 0; s >>= 1) {
      if (tid < s) red[tid] += red[tid + s];
      __syncthreads();
    }
    if (tid == 0) {
      const float aw = 1.f / (1.f + expf(-(red[0] + bm2[0])));
      out[OFF_BV + b] = bv;
      out[OFF_VAL + b] = aw * wres[b] + (1.f - aw) * bv;
      out[OFF_WRES + b] = wres[b];
    }
  } else {  // wact copy
#pragma unroll
    for (int i = 0; i < 8; ++i) out[OFF_WACT + i * 512 + tid] = wact[i * 512 + tid];
  }
}

extern "C" void kernel_launch(void* const* d_in, const int* in_sizes, int n_in,
                              void* d_out, int out_size, void* d_ws,
                              size_t ws_size, hipStream_t stream) {
  (void)in_sizes; (void)n_in; (void)out_size; (void)ws_size;
  const float* features = (const float*)d_in[0];
  const float* memory   = (const float*)d_in[1];
  const float* W1s = (const float*)d_in[2];
  const float* b1s = (const float*)d_in[3];
  const float* W2s = (const float*)d_in[4];
  const float* b2s = (const float*)d_in[5];
  const float* W1e = (const float*)d_in[6];
  const float* b1e = (const float*)d_in[7];
  const float* W2e = (const float*)d_in[8];
  const float* b2e = (const float*)d_in[9];
  const float* Wp1 = (const float*)d_in[10];
  const float* bp1 = (const float*)d_in[11];
  const float* Wp2 = (const float*)d_in[12];
  const float* bp2 = (const float*)d_in[13];
  const float* Wv1 = (const float*)d_in[14];
  const float* bv1 = (const float*)d_in[15];
  const float* Wv2 = (const float*)d_in[16];
  const float* bv2 = (const float*)d_in[17];
  const float* Wm1 = (const float*)d_in[18];
  const float* bm1 = (const float*)d_in[19];
  const float* Wm2 = (const float*)d_in[20];
  const float* bm2 = (const float*)d_in[21];
  float* out = (float*)d_out;

  // workspace layout (bytes)
  char* W = (char*)d_ws;
  unsigned short* Ahi  = (unsigned short*)(W);                      // 16 MB
  unsigned short* B1hi = (unsigned short*)(W + (16u << 20));        // 1 MB
  unsigned short* B1lo = (unsigned short*)(W + (17u << 20));        // 1 MB
  unsigned short* B2hi = (unsigned short*)(W + (18u << 20));        // 0.5 MB
  float*          C1   = (float*)(W + (19u << 20));                 // 16 MB
  unsigned short* C2   = (unsigned short*)(W + (35u << 20));        // 4 MB
  float*          scores = (float*)(W + (39u << 20));               // 1 MB
  char* S = W + (40u << 20);
  float* q1b      = (float*)(S);               // 64 KB
  float* q2b      = (float*)(S + 65536);       // 32 KB
  float* s2       = (float*)(S + 98304);       // 125 KB
  int*   topk     = (int*)  (S + 354304);      // 125 KB
  float* wact_acc = (float*)(S + 482304);      // 16 KB
  float* wres_acc = (float*)(S + 498688);      // 128 B
  float* hp_acc   = (float*)(S + 498944);      // 96 KB
  float* v1h      = (float*)(S + 597248);      // 64 KB
  float* m1h      = (float*)(S + 662784);      // 64 KB

  k_prep<<<9881, 256, 0, stream>>>(memory, W1s, W1e, b1s, b1e, bv1, bm1, bp1,
                                   bp2, Ahi, B1hi, B1lo, B2hi, q1b, q2b, v1h,
                                   m1h, hp_acc, wact_acc, wres_acc, out);
  k_skinny_all<<<dim3(10, 16), 128, 0, stream>>>(features, W1s, W1e, Wv1, Wm1,
                                                 Wp1, q1b, q2b, v1h, m1h, hp_acc);
  k_gemmA<<<dim3(64, 6), 256, 0, stream>>>(Ahi, B1hi, B1lo, B2hi, C1, C2);
  k_scores2<<<1024, 256, 0, stream>>>(C1, q1b, W2s, b2s, scores);
  k_topk<<<32, 1024, 0, stream>>>(scores, topk);
  k_s2<<<8000, 256, 0, stream>>>(C2, q2b, topk, W2e, b2e, s2);
  k_weighted<<<256, 256, 0, stream>>>(topk, s2, memory, wact_acc, wres_acc);
  k_tail<<<65, 512, 0, stream>>>(wact_acc, wres_acc, v1h, m1h, Wv2, bv2, Wm2,
                                 bm2, Wp1, hp_acc, out);
  k_skinny_logits<<<dim3(19, 12), 128, 0, stream>>>(hp_acc, Wp2, out);
}